// Round 1
// baseline (82846.039 us; speedup 1.0000x reference)
//
#include <hip/hip_runtime.h>
#include <hip/hip_cooperative_groups.h>

namespace cg = cooperative_groups;

static constexpr int G    = 100;
static constexpr int G3   = G * G * G;
static constexpr int NP   = 13500;   // 30*15*30 particles
static constexpr int NSUB = 600;     // 20 frames x 30 substeps
static constexpr int SPF  = 30;      // substeps per frame
static constexpr int NBLK = 64;
static constexpr int NTHR = 256;

__device__ __forceinline__ int clampi(int v) {
    return v < 0 ? 0 : (v > G - 1 ? G - 1 : v);
}

// Persistent cooperative kernel. Triple-buffered grid in ws:
//   bm = ws[0 .. 3*G3)            : 3 mass buffers
//   bv = ws[3*G3 .. 12*G3)        : 3 momentum/velocity buffers (3 floats/cell)
// Phase p: gather substep p-1 from buf[(p-1)%3], scatter substep p into buf[p%3],
// zero substep p-2's stencil cells in buf[(p+1)%3]. One grid sync per phase.
__launch_bounds__(NTHR)
__global__ void mpm_sim(const float* __restrict__ vscal,
                        const float* __restrict__ q0,
                        const float* __restrict__ qd0,
                        float* __restrict__ out,
                        float* __restrict__ ws)
{
    const float vs = vscal[0];
    float* const bm = ws;
    float* const bv = ws + 3 * G3;

    cg::grid_group gg = cg::this_grid();
    const int tid = blockIdx.x * NTHR + threadIdx.x;
    const int nth = NBLK * NTHR;

    const float DT      = 5e-4f;
    const float INV_DX  = 100.0f;
    const float DXc     = 0.01f;
    const float MU      = (float)(1.0e5 / (2.0 * (1.0 + 0.3)));
    const float LAM     = (float)(1.0e5 * 0.3 / ((1.0 + 0.3) * (1.0 - 0.6)));
    const float P_MASS  = (float)(0.005 * 0.005 * 0.005 * 3000.0);
    const float KS      = (float)(-5.0e-4 * (0.005 * 0.005 * 0.005) * 4.0 * 100.0 * 100.0);
    const float DTG     = (float)(5.0e-4 * (-9.8));
    const float CSC     = 4.0f * INV_DX * INV_DX;   // 40000

    // ---- init: zero all 3 grid buffers (ws is poisoned 0xAA before each launch) ----
    {
        float4 z = make_float4(0.f, 0.f, 0.f, 0.f);
        float4* p4 = reinterpret_cast<float4*>(ws);
        for (int i = tid; i < 3 * G3; i += nth) p4[i] = z;   // 12*G3 floats
    }

    // ---- particle state in registers ----
    float px = 0.f, py = 0.f, pz = 0.f, vx = 0.f, vy = 0.f, vz = 0.f;
    float C00 = 0.f, C01 = 0.f, C02 = 0.f,
          C10 = 0.f, C11 = 0.f, C12 = 0.f,
          C20 = 0.f, C21 = 0.f, C22 = 0.f;
    float F00 = 1.f, F01 = 0.f, F02 = 0.f,
          F10 = 0.f, F11 = 1.f, F12 = 0.f,
          F20 = 0.f, F21 = 0.f, F22 = 1.f;
    int pbx = 0, pby = 0, pbz = 0;   // scatter base of substep p-1
    int qbx = 0, qby = 0, qbz = 0;   // scatter base of substep p-2
    const bool act = tid < NP;
    if (act) {
        px = q0[3 * tid + 0]; py = q0[3 * tid + 1]; pz = q0[3 * tid + 2];
        vx = qd0[3 * tid + 0]; vy = qd0[3 * tid + 1]; vz = qd0[3 * tid + 2];
    }

    gg.sync();

    for (int p = 0; p < NSUB; ++p) {
        const int bS = p % 3;
        const int bG = (p + 2) % 3;   // == (p-1)%3 for p>0
        const int bZ = (p + 1) % 3;   // holds substep p-2 data
        float*       __restrict__ gmS = bm + bS * G3;
        float*       __restrict__ gvS = bv + bS * 3 * G3;
        const float* __restrict__ gmG = bm + bG * G3;
        const float* __restrict__ gvG = bv + bG * 3 * G3;
        float*       __restrict__ gmZ = bm + bZ * G3;
        float*       __restrict__ gvZ = bv + bZ * 3 * G3;

        // frame output: grid_m of substep p-1 (scatter completed last phase,
        // buffer not zeroed until phase p+1)
        if (p > 0 && ((p - 1) % SPF) == SPF - 1) {
            float* o = out + ((p - 1) / SPF) * G3;
            for (int i = tid; i < G3; i += nth) o[i] = gmG[i] + vs;
        }

        if (act) {
            // ======== G2P gather for substep p-1 (weights from current x) ========
            if (p > 0) {
                const float xs0 = px * INV_DX, xs1 = py * INV_DX, xs2 = pz * INV_DX;
                const float fb0 = floorf(xs0 - 0.5f), fb1 = floorf(xs1 - 0.5f), fb2 = floorf(xs2 - 0.5f);
                const int b0 = (int)fb0, b1 = (int)fb1, b2 = (int)fb2;
                const float fx0 = xs0 - fb0, fx1 = xs1 - fb1, fx2 = xs2 - fb2;
                float wa[3], wb[3], wc[3];
                wa[0] = 0.5f * (1.5f - fx0) * (1.5f - fx0);
                wa[1] = 0.75f - (fx0 - 1.0f) * (fx0 - 1.0f);
                wa[2] = 0.5f * (fx0 - 0.5f) * (fx0 - 0.5f);
                wb[0] = 0.5f * (1.5f - fx1) * (1.5f - fx1);
                wb[1] = 0.75f - (fx1 - 1.0f) * (fx1 - 1.0f);
                wb[2] = 0.5f * (fx1 - 0.5f) * (fx1 - 0.5f);
                wc[0] = 0.5f * (1.5f - fx2) * (1.5f - fx2);
                wc[1] = 0.75f - (fx2 - 1.0f) * (fx2 - 1.0f);
                wc[2] = 0.5f * (fx2 - 0.5f) * (fx2 - 0.5f);

                float nvx = 0.f, nvy = 0.f, nvz = 0.f;
                float nc00 = 0.f, nc01 = 0.f, nc02 = 0.f,
                      nc10 = 0.f, nc11 = 0.f, nc12 = 0.f,
                      nc20 = 0.f, nc21 = 0.f, nc22 = 0.f;
                #pragma unroll
                for (int oi = 0; oi < 3; ++oi) {
                    const int nx = clampi(b0 + oi);
                    const float dpx = ((float)oi - fx0) * DXc;
                    #pragma unroll
                    for (int oj = 0; oj < 3; ++oj) {
                        const int ny = clampi(b1 + oj);
                        const float dpy = ((float)oj - fx1) * DXc;
                        const float wab = wa[oi] * wb[oj];
                        #pragma unroll
                        for (int ok = 0; ok < 3; ++ok) {
                            const int nz = clampi(b2 + ok);
                            const float dpz = ((float)ok - fx2) * DXc;
                            const float w = wab * wc[ok];
                            const int idx = (nx * G + ny) * G + nz;
                            const float den = gmG[idx] + vs;
                            const float* gp = gvG + 3 * idx;
                            float gx = gp[0] / den;
                            float gy = gp[1] / den;
                            float gz = gp[2] / den;
                            // sticky boundary (node-local, sign-dependent)
                            if (nx < 3       && gx < 0.f) gx = 0.f;
                            if (nx >= G - 3  && gx > 0.f) gx = 0.f;
                            if (ny < 3       && gy < 0.f) gy = 0.f;
                            if (ny >= G - 3  && gy > 0.f) gy = 0.f;
                            if (nz < 3       && gz < 0.f) gz = 0.f;
                            if (nz >= G - 3  && gz > 0.f) gz = 0.f;
                            nvx += w * gx; nvy += w * gy; nvz += w * gz;
                            const float wgx = w * gx, wgy = w * gy, wgz = w * gz;
                            nc00 += wgx * dpx; nc01 += wgx * dpy; nc02 += wgx * dpz;
                            nc10 += wgy * dpx; nc11 += wgy * dpy; nc12 += wgy * dpz;
                            nc20 += wgz * dpx; nc21 += wgz * dpy; nc22 += wgz * dpz;
                        }
                    }
                }
                vx = nvx; vy = nvy; vz = nvz;
                C00 = CSC * nc00; C01 = CSC * nc01; C02 = CSC * nc02;
                C10 = CSC * nc10; C11 = CSC * nc11; C12 = CSC * nc12;
                C20 = CSC * nc20; C21 = CSC * nc21; C22 = CSC * nc22;
                px += DT * vx; py += DT * vy; pz += DT * vz;
            }

            // ======== F update: F = (I + DT*C) @ F ========
            {
                const float t00 = F00 + DT * (C00 * F00 + C01 * F10 + C02 * F20);
                const float t01 = F01 + DT * (C00 * F01 + C01 * F11 + C02 * F21);
                const float t02 = F02 + DT * (C00 * F02 + C01 * F12 + C02 * F22);
                const float t10 = F10 + DT * (C10 * F00 + C11 * F10 + C12 * F20);
                const float t11 = F11 + DT * (C10 * F01 + C11 * F11 + C12 * F21);
                const float t12 = F12 + DT * (C10 * F02 + C11 * F12 + C12 * F22);
                const float t20 = F20 + DT * (C20 * F00 + C21 * F10 + C22 * F20);
                const float t21 = F21 + DT * (C20 * F01 + C21 * F11 + C22 * F21);
                const float t22 = F22 + DT * (C20 * F02 + C21 * F12 + C22 * F22);
                F00 = t00; F01 = t01; F02 = t02;
                F10 = t10; F11 = t11; F12 = t12;
                F20 = t20; F21 = t21; F22 = t22;
            }

            // ======== neo-Hookean PK1 stress -> affine ========
            const float c00 = F11 * F22 - F12 * F21;
            const float c01 = F12 * F20 - F10 * F22;
            const float c02 = F10 * F21 - F11 * F20;
            const float det = F00 * c00 + F01 * c01 + F02 * c02;
            const float c10 = F02 * F21 - F01 * F22;
            const float c11 = F00 * F22 - F02 * F20;
            const float c12 = F01 * F20 - F00 * F21;
            const float c20 = F01 * F12 - F02 * F11;
            const float c21 = F02 * F10 - F00 * F12;
            const float c22 = F00 * F11 - F01 * F10;
            const float idet = 1.0f / det;
            const float lj = LAM * logf(fmaxf(det, 1e-6f));
            const float fit00 = c00 * idet, fit01 = c01 * idet, fit02 = c02 * idet;
            const float fit10 = c10 * idet, fit11 = c11 * idet, fit12 = c12 * idet;
            const float fit20 = c20 * idet, fit21 = c21 * idet, fit22 = c22 * idet;
            const float P00 = MU * (F00 - fit00) + lj * fit00;
            const float P01 = MU * (F01 - fit01) + lj * fit01;
            const float P02 = MU * (F02 - fit02) + lj * fit02;
            const float P10 = MU * (F10 - fit10) + lj * fit10;
            const float P11 = MU * (F11 - fit11) + lj * fit11;
            const float P12 = MU * (F12 - fit12) + lj * fit12;
            const float P20 = MU * (F20 - fit20) + lj * fit20;
            const float P21 = MU * (F21 - fit21) + lj * fit21;
            const float P22 = MU * (F22 - fit22) + lj * fit22;
            // affine[i][k] = KS * (P[i][:] . F[k][:]) + P_MASS * C[i][k]
            const float A00 = KS * (P00 * F00 + P01 * F01 + P02 * F02) + P_MASS * C00;
            const float A01 = KS * (P00 * F10 + P01 * F11 + P02 * F12) + P_MASS * C01;
            const float A02 = KS * (P00 * F20 + P01 * F21 + P02 * F22) + P_MASS * C02;
            const float A10 = KS * (P10 * F00 + P11 * F01 + P12 * F02) + P_MASS * C10;
            const float A11 = KS * (P10 * F10 + P11 * F11 + P12 * F12) + P_MASS * C11;
            const float A12 = KS * (P10 * F20 + P11 * F21 + P12 * F22) + P_MASS * C12;
            const float A20 = KS * (P20 * F00 + P21 * F01 + P22 * F02) + P_MASS * C20;
            const float A21 = KS * (P20 * F10 + P21 * F11 + P22 * F12) + P_MASS * C21;
            const float A22 = KS * (P20 * F20 + P21 * F21 + P22 * F22) + P_MASS * C22;

            // ======== P2G scatter for substep p (weights from updated x) ========
            const float xs0 = px * INV_DX, xs1 = py * INV_DX, xs2 = pz * INV_DX;
            const float fb0 = floorf(xs0 - 0.5f), fb1 = floorf(xs1 - 0.5f), fb2 = floorf(xs2 - 0.5f);
            const int sb0 = (int)fb0, sb1 = (int)fb1, sb2 = (int)fb2;
            const float fx0 = xs0 - fb0, fx1 = xs1 - fb1, fx2 = xs2 - fb2;
            float wa[3], wb[3], wc[3];
            wa[0] = 0.5f * (1.5f - fx0) * (1.5f - fx0);
            wa[1] = 0.75f - (fx0 - 1.0f) * (fx0 - 1.0f);
            wa[2] = 0.5f * (fx0 - 0.5f) * (fx0 - 0.5f);
            wb[0] = 0.5f * (1.5f - fx1) * (1.5f - fx1);
            wb[1] = 0.75f - (fx1 - 1.0f) * (fx1 - 1.0f);
            wb[2] = 0.5f * (fx1 - 0.5f) * (fx1 - 0.5f);
            wc[0] = 0.5f * (1.5f - fx2) * (1.5f - fx2);
            wc[1] = 0.75f - (fx2 - 1.0f) * (fx2 - 1.0f);
            wc[2] = 0.5f * (fx2 - 0.5f) * (fx2 - 0.5f);
            const float mvx = P_MASS * vx;
            const float mvy = P_MASS * (vy + DTG);
            const float mvz = P_MASS * vz;
            #pragma unroll
            for (int oi = 0; oi < 3; ++oi) {
                const int nx = clampi(sb0 + oi);
                const float dpx = ((float)oi - fx0) * DXc;
                #pragma unroll
                for (int oj = 0; oj < 3; ++oj) {
                    const int ny = clampi(sb1 + oj);
                    const float dpy = ((float)oj - fx1) * DXc;
                    const float wab = wa[oi] * wb[oj];
                    #pragma unroll
                    for (int ok = 0; ok < 3; ++ok) {
                        const int nz = clampi(sb2 + ok);
                        const float dpz = ((float)ok - fx2) * DXc;
                        const float w = wab * wc[ok];
                        const int idx = (nx * G + ny) * G + nz;
                        const float momx = w * (mvx + A00 * dpx + A01 * dpy + A02 * dpz);
                        const float momy = w * (mvy + A10 * dpx + A11 * dpy + A12 * dpz);
                        const float momz = w * (mvz + A20 * dpx + A21 * dpy + A22 * dpz);
                        unsafeAtomicAdd(&gmS[idx], w * P_MASS);
                        float* sp = gvS + 3 * idx;
                        unsafeAtomicAdd(sp + 0, momx);
                        unsafeAtomicAdd(sp + 1, momy);
                        unsafeAtomicAdd(sp + 2, momz);
                    }
                }
            }

            // ======== zero substep p-2's stencil cells in buf[(p+1)%3] ========
            if (p >= 2) {
                #pragma unroll
                for (int oi = 0; oi < 3; ++oi) {
                    const int nx = clampi(qbx + oi);
                    #pragma unroll
                    for (int oj = 0; oj < 3; ++oj) {
                        const int ny = clampi(qby + oj);
                        #pragma unroll
                        for (int ok = 0; ok < 3; ++ok) {
                            const int nz = clampi(qbz + ok);
                            const int idx = (nx * G + ny) * G + nz;
                            gmZ[idx] = 0.f;
                            float* zp = gvZ + 3 * idx;
                            zp[0] = 0.f; zp[1] = 0.f; zp[2] = 0.f;
                        }
                    }
                }
            }
            // shift base history
            qbx = pbx; qby = pby; qbz = pbz;
            pbx = sb0; pby = sb1; pbz = sb2;
        }

        gg.sync();
    }

    // ---- final frame output: grid_m of substep 599 ----
    {
        const float* gmL = bm + ((NSUB - 1) % 3) * G3;
        float* o = out + (NSUB / SPF - 1) * G3;
        for (int i = tid; i < G3; i += nth) o[i] = gmL[i] + vs;
    }
}

extern "C" void kernel_launch(void* const* d_in, const int* in_sizes, int n_in,
                              void* d_out, int out_size, void* d_ws, size_t ws_size,
                              hipStream_t stream) {
    const float* v  = (const float*)d_in[0];
    const float* q  = (const float*)d_in[1];
    const float* qd = (const float*)d_in[2];
    float* out = (float*)d_out;
    float* ws  = (float*)d_ws;
    void* args[] = { (void*)&v, (void*)&q, (void*)&qd, (void*)&out, (void*)&ws };
    hipLaunchCooperativeKernel(reinterpret_cast<void*>(mpm_sim),
                               dim3(NBLK), dim3(NTHR), args, 0, stream);
}

// Round 2
// 40382.346 us; speedup vs baseline: 2.0515x; 2.0515x over previous
//
#include <hip/hip_runtime.h>
#include <hip/hip_cooperative_groups.h>

namespace cg = cooperative_groups;

static constexpr int G    = 100;
static constexpr int G3   = G * G * G;
static constexpr int NP   = 13500;   // 30*15*30 particles
static constexpr int NSUB = 600;     // 20 frames x 30 substeps
static constexpr int SPF  = 30;      // substeps per frame
static constexpr int NBLK = 64;
static constexpr int NTHR = 256;
static constexpr int TC   = 4000;    // LDS tile capacity in cells (4 floats each = 64000 B)

__device__ __forceinline__ int clampi(int v) {
    return v < 0 ? 0 : (v > G - 1 ? G - 1 : v);
}

// Persistent cooperative kernel. Triple-buffered grid in ws:
//   bm = ws[0 .. 3*G3)     : 3 mass buffers
//   bv = ws[3*G3 .. 12*G3) : 3 momentum buffers (3 floats/cell)
// Phase p: gather substep p-1 from buf[(p-1)%3], scatter substep p into buf[p%3]
// (privatized through a per-workgroup LDS tile over the wg's particle bbox),
// zero substep p-2's per-wg bbox in buf[(p+1)%3]. One grid sync per phase.
__launch_bounds__(NTHR)
__global__ void mpm_sim(const float* __restrict__ vscal,
                        const float* __restrict__ q0,
                        const float* __restrict__ qd0,
                        float* __restrict__ out,
                        float* __restrict__ ws)
{
    const float vs = vscal[0];
    float* const bm = ws;
    float* const bv = ws + 3 * G3;

    cg::grid_group gg = cg::this_grid();
    const int tid = blockIdx.x * NTHR + threadIdx.x;
    const int nth = NBLK * NTHR;

    const float DT      = 5e-4f;
    const float INV_DX  = 100.0f;
    const float DXc     = 0.01f;
    const float MU      = (float)(1.0e5 / (2.0 * (1.0 + 0.3)));
    const float LAM     = (float)(1.0e5 * 0.3 / ((1.0 + 0.3) * (1.0 - 0.6)));
    const float P_MASS  = (float)(0.005 * 0.005 * 0.005 * 3000.0);
    const float KS      = (float)(-5.0e-4 * (0.005 * 0.005 * 0.005) * 4.0 * 100.0 * 100.0);
    const float DTG     = (float)(5.0e-4 * (-9.8));
    const float CSC     = 4.0f * INV_DX * INV_DX;   // 40000

    __shared__ float tile[4 * TC];   // AoS: [mx,my,mz,mass] per cell
    __shared__ int sred[6];          // bbox reduction: mn0,mn1,mn2,mx0,mx1,mx2

    // ---- init: zero all 3 grid buffers (ws is poisoned 0xAA) ----
    {
        float4 z = make_float4(0.f, 0.f, 0.f, 0.f);
        float4* p4 = reinterpret_cast<float4*>(ws);
        for (int i = tid; i < 3 * G3; i += nth) p4[i] = z;
    }

    // ---- particle state in registers ----
    float px = 0.f, py = 0.f, pz = 0.f, vx = 0.f, vy = 0.f, vz = 0.f;
    float C00 = 0.f, C01 = 0.f, C02 = 0.f,
          C10 = 0.f, C11 = 0.f, C12 = 0.f,
          C20 = 0.f, C21 = 0.f, C22 = 0.f;
    float F00 = 1.f, F01 = 0.f, F02 = 0.f,
          F10 = 0.f, F11 = 1.f, F12 = 0.f,
          F20 = 0.f, F21 = 0.f, F22 = 1.f;
    const bool act = tid < NP;
    if (act) {
        px = q0[3 * tid + 0]; py = q0[3 * tid + 1]; pz = q0[3 * tid + 2];
        vx = qd0[3 * tid + 0]; vy = qd0[3 * tid + 1]; vz = qd0[3 * tid + 2];
    }

    // per-wg bbox history (uniform across wg): p-1 and p-2 scatter bboxes
    int pmn0 = 0, pmn1 = 0, pmn2 = 0, pmx0 = -1, pmx1 = -1, pmx2 = -1; bool pvalid = false;
    int zmn0 = 0, zmn1 = 0, zmn2 = 0, zmx0 = -1, zmx1 = -1, zmx2 = -1; bool zvalid = false;

    gg.sync();

    for (int p = 0; p < NSUB; ++p) {
        const int bS = p % 3;
        const int bG = (p + 2) % 3;   // (p-1)%3 for p>0
        const int bZ = (p + 1) % 3;   // holds substep p-2 data
        float*       __restrict__ gmS = bm + bS * G3;
        float*       __restrict__ gvS = bv + bS * 3 * G3;
        const float* __restrict__ gmG = bm + bG * G3;
        const float* __restrict__ gvG = bv + bG * 3 * G3;
        float*       __restrict__ gmZ = bm + bZ * G3;
        float*       __restrict__ gvZ = bv + bZ * 3 * G3;

        // frame output: grid_m of substep p-1
        if (p > 0 && ((p - 1) % SPF) == SPF - 1) {
            float* o = out + ((p - 1) / SPF) * G3;
            for (int i = tid; i < G3; i += nth) o[i] = gmG[i] + vs;
        }

        int sb0 = 0, sb1 = 0, sb2 = 0;
        float fx0 = 0.f, fx1 = 0.f, fx2 = 0.f;
        float A00 = 0.f, A01 = 0.f, A02 = 0.f,
              A10 = 0.f, A11 = 0.f, A12 = 0.f,
              A20 = 0.f, A21 = 0.f, A22 = 0.f;
        float mvx = 0.f, mvy = 0.f, mvz = 0.f;

        if (act) {
            // ======== G2P gather for substep p-1 (weights from current x) ========
            if (p > 0) {
                const float xs0 = px * INV_DX, xs1 = py * INV_DX, xs2 = pz * INV_DX;
                const float fb0 = floorf(xs0 - 0.5f), fb1 = floorf(xs1 - 0.5f), fb2 = floorf(xs2 - 0.5f);
                const int b0 = (int)fb0, b1 = (int)fb1, b2 = (int)fb2;
                const float gx0 = xs0 - fb0, gx1 = xs1 - fb1, gx2 = xs2 - fb2;
                float wa[3], wb[3], wc[3];
                wa[0] = 0.5f * (1.5f - gx0) * (1.5f - gx0);
                wa[1] = 0.75f - (gx0 - 1.0f) * (gx0 - 1.0f);
                wa[2] = 0.5f * (gx0 - 0.5f) * (gx0 - 0.5f);
                wb[0] = 0.5f * (1.5f - gx1) * (1.5f - gx1);
                wb[1] = 0.75f - (gx1 - 1.0f) * (gx1 - 1.0f);
                wb[2] = 0.5f * (gx1 - 0.5f) * (gx1 - 0.5f);
                wc[0] = 0.5f * (1.5f - gx2) * (1.5f - gx2);
                wc[1] = 0.75f - (gx2 - 1.0f) * (gx2 - 1.0f);
                wc[2] = 0.5f * (gx2 - 0.5f) * (gx2 - 0.5f);

                float nvx = 0.f, nvy = 0.f, nvz = 0.f;
                float nc00 = 0.f, nc01 = 0.f, nc02 = 0.f,
                      nc10 = 0.f, nc11 = 0.f, nc12 = 0.f,
                      nc20 = 0.f, nc21 = 0.f, nc22 = 0.f;
                #pragma unroll
                for (int oi = 0; oi < 3; ++oi) {
                    const int nx = clampi(b0 + oi);
                    const float dpx = ((float)oi - gx0) * DXc;
                    #pragma unroll
                    for (int oj = 0; oj < 3; ++oj) {
                        const int ny = clampi(b1 + oj);
                        const float dpy = ((float)oj - gx1) * DXc;
                        const float wab = wa[oi] * wb[oj];
                        #pragma unroll
                        for (int ok = 0; ok < 3; ++ok) {
                            const int nz = clampi(b2 + ok);
                            const float dpz = ((float)ok - gx2) * DXc;
                            const float w = wab * wc[ok];
                            const int idx = (nx * G + ny) * G + nz;
                            const float den = gmG[idx] + vs;
                            const float* gp = gvG + 3 * idx;
                            float gvx = gp[0] / den;
                            float gvy = gp[1] / den;
                            float gvz = gp[2] / den;
                            if (nx < 3       && gvx < 0.f) gvx = 0.f;
                            if (nx >= G - 3  && gvx > 0.f) gvx = 0.f;
                            if (ny < 3       && gvy < 0.f) gvy = 0.f;
                            if (ny >= G - 3  && gvy > 0.f) gvy = 0.f;
                            if (nz < 3       && gvz < 0.f) gvz = 0.f;
                            if (nz >= G - 3  && gvz > 0.f) gvz = 0.f;
                            nvx += w * gvx; nvy += w * gvy; nvz += w * gvz;
                            const float wgx = w * gvx, wgy = w * gvy, wgz = w * gvz;
                            nc00 += wgx * dpx; nc01 += wgx * dpy; nc02 += wgx * dpz;
                            nc10 += wgy * dpx; nc11 += wgy * dpy; nc12 += wgy * dpz;
                            nc20 += wgz * dpx; nc21 += wgz * dpy; nc22 += wgz * dpz;
                        }
                    }
                }
                vx = nvx; vy = nvy; vz = nvz;
                C00 = CSC * nc00; C01 = CSC * nc01; C02 = CSC * nc02;
                C10 = CSC * nc10; C11 = CSC * nc11; C12 = CSC * nc12;
                C20 = CSC * nc20; C21 = CSC * nc21; C22 = CSC * nc22;
                px += DT * vx; py += DT * vy; pz += DT * vz;
            }

            // ======== F update: F = (I + DT*C) @ F ========
            {
                const float t00 = F00 + DT * (C00 * F00 + C01 * F10 + C02 * F20);
                const float t01 = F01 + DT * (C00 * F01 + C01 * F11 + C02 * F21);
                const float t02 = F02 + DT * (C00 * F02 + C01 * F12 + C02 * F22);
                const float t10 = F10 + DT * (C10 * F00 + C11 * F10 + C12 * F20);
                const float t11 = F11 + DT * (C10 * F01 + C11 * F11 + C12 * F21);
                const float t12 = F12 + DT * (C10 * F02 + C11 * F12 + C12 * F22);
                const float t20 = F20 + DT * (C20 * F00 + C21 * F10 + C22 * F20);
                const float t21 = F21 + DT * (C20 * F01 + C21 * F11 + C22 * F21);
                const float t22 = F22 + DT * (C20 * F02 + C21 * F12 + C22 * F22);
                F00 = t00; F01 = t01; F02 = t02;
                F10 = t10; F11 = t11; F12 = t12;
                F20 = t20; F21 = t21; F22 = t22;
            }

            // ======== neo-Hookean PK1 stress -> affine ========
            const float c00 = F11 * F22 - F12 * F21;
            const float c01 = F12 * F20 - F10 * F22;
            const float c02 = F10 * F21 - F11 * F20;
            const float det = F00 * c00 + F01 * c01 + F02 * c02;
            const float c10 = F02 * F21 - F01 * F22;
            const float c11 = F00 * F22 - F02 * F20;
            const float c12 = F01 * F20 - F00 * F21;
            const float c20 = F01 * F12 - F02 * F11;
            const float c21 = F02 * F10 - F00 * F12;
            const float c22 = F00 * F11 - F01 * F10;
            const float idet = 1.0f / det;
            const float lj = LAM * logf(fmaxf(det, 1e-6f));
            const float fit00 = c00 * idet, fit01 = c01 * idet, fit02 = c02 * idet;
            const float fit10 = c10 * idet, fit11 = c11 * idet, fit12 = c12 * idet;
            const float fit20 = c20 * idet, fit21 = c21 * idet, fit22 = c22 * idet;
            const float P00 = MU * (F00 - fit00) + lj * fit00;
            const float P01 = MU * (F01 - fit01) + lj * fit01;
            const float P02 = MU * (F02 - fit02) + lj * fit02;
            const float P10 = MU * (F10 - fit10) + lj * fit10;
            const float P11 = MU * (F11 - fit11) + lj * fit11;
            const float P12 = MU * (F12 - fit12) + lj * fit12;
            const float P20 = MU * (F20 - fit20) + lj * fit20;
            const float P21 = MU * (F21 - fit21) + lj * fit21;
            const float P22 = MU * (F22 - fit22) + lj * fit22;
            A00 = KS * (P00 * F00 + P01 * F01 + P02 * F02) + P_MASS * C00;
            A01 = KS * (P00 * F10 + P01 * F11 + P02 * F12) + P_MASS * C01;
            A02 = KS * (P00 * F20 + P01 * F21 + P02 * F22) + P_MASS * C02;
            A10 = KS * (P10 * F00 + P11 * F01 + P12 * F02) + P_MASS * C10;
            A11 = KS * (P10 * F10 + P11 * F11 + P12 * F12) + P_MASS * C11;
            A12 = KS * (P10 * F20 + P11 * F21 + P12 * F22) + P_MASS * C12;
            A20 = KS * (P20 * F00 + P21 * F01 + P22 * F02) + P_MASS * C20;
            A21 = KS * (P20 * F10 + P21 * F11 + P22 * F12) + P_MASS * C21;
            A22 = KS * (P20 * F20 + P21 * F21 + P22 * F22) + P_MASS * C22;

            // scatter base (from updated x)
            const float xs0 = px * INV_DX, xs1 = py * INV_DX, xs2 = pz * INV_DX;
            const float fb0 = floorf(xs0 - 0.5f), fb1 = floorf(xs1 - 0.5f), fb2 = floorf(xs2 - 0.5f);
            sb0 = (int)fb0; sb1 = (int)fb1; sb2 = (int)fb2;
            fx0 = xs0 - fb0; fx1 = xs1 - fb1; fx2 = xs2 - fb2;
            mvx = P_MASS * vx;
            mvy = P_MASS * (vy + DTG);
            mvz = P_MASS * vz;
        }

        // ======== per-wg clamped scatter bbox reduction ========
        if (threadIdx.x == 0) {
            sred[0] = INT_MAX; sred[1] = INT_MAX; sred[2] = INT_MAX;
            sred[3] = INT_MIN; sred[4] = INT_MIN; sred[5] = INT_MIN;
        }
        __syncthreads();
        if (act) {
            atomicMin(&sred[0], clampi(sb0)); atomicMax(&sred[3], clampi(sb0 + 2));
            atomicMin(&sred[1], clampi(sb1)); atomicMax(&sred[4], clampi(sb1 + 2));
            atomicMin(&sred[2], clampi(sb2)); atomicMax(&sred[5], clampi(sb2 + 2));
        }
        __syncthreads();
        const int mn0 = sred[0], mn1 = sred[1], mn2 = sred[2];
        const int mx0 = sred[3], mx1 = sred[4], mx2 = sred[5];
        const bool anyAct = (mx0 >= mn0);
        const int D0 = mx0 - mn0 + 1, D1 = mx1 - mn1 + 1, D2 = mx2 - mn2 + 1;
        const int vol = anyAct ? D0 * D1 * D2 : 0;
        const bool useLDS = anyAct && (vol <= TC);
        __syncthreads();   // tile reuse guard (also after bbox read)

        if (useLDS) {
            // zero tile portion
            for (int i = threadIdx.x; i < 4 * vol; i += NTHR) tile[i] = 0.f;
            __syncthreads();
            if (act) {
                float wa[3], wb[3], wc[3];
                wa[0] = 0.5f * (1.5f - fx0) * (1.5f - fx0);
                wa[1] = 0.75f - (fx0 - 1.0f) * (fx0 - 1.0f);
                wa[2] = 0.5f * (fx0 - 0.5f) * (fx0 - 0.5f);
                wb[0] = 0.5f * (1.5f - fx1) * (1.5f - fx1);
                wb[1] = 0.75f - (fx1 - 1.0f) * (fx1 - 1.0f);
                wb[2] = 0.5f * (fx1 - 0.5f) * (fx1 - 0.5f);
                wc[0] = 0.5f * (1.5f - fx2) * (1.5f - fx2);
                wc[1] = 0.75f - (fx2 - 1.0f) * (fx2 - 1.0f);
                wc[2] = 0.5f * (fx2 - 0.5f) * (fx2 - 0.5f);
                #pragma unroll
                for (int oi = 0; oi < 3; ++oi) {
                    const int li = clampi(sb0 + oi) - mn0;
                    const float dpx = ((float)oi - fx0) * DXc;
                    #pragma unroll
                    for (int oj = 0; oj < 3; ++oj) {
                        const int lj2 = clampi(sb1 + oj) - mn1;
                        const float dpy = ((float)oj - fx1) * DXc;
                        const float wab = wa[oi] * wb[oj];
                        #pragma unroll
                        for (int ok = 0; ok < 3; ++ok) {
                            const int lk = clampi(sb2 + ok) - mn2;
                            const float dpz = ((float)ok - fx2) * DXc;
                            const float w = wab * wc[ok];
                            const int c4 = 4 * ((li * D1 + lj2) * D2 + lk);
                            atomicAdd(&tile[c4 + 0], w * (mvx + A00 * dpx + A01 * dpy + A02 * dpz));
                            atomicAdd(&tile[c4 + 1], w * (mvy + A10 * dpx + A11 * dpy + A12 * dpz));
                            atomicAdd(&tile[c4 + 2], w * (mvz + A20 * dpx + A21 * dpy + A22 * dpz));
                            atomicAdd(&tile[c4 + 3], w * P_MASS);
                        }
                    }
                }
            }
            __syncthreads();
            // flush tile -> global (device-scope atomics), skip empty cells
            for (int c = threadIdx.x; c < vol; c += NTHR) {
                const float m = tile[4 * c + 3];
                if (m != 0.f) {
                    const int k = c % D2;
                    const int t = c / D2;
                    const int j = t % D1;
                    const int i = t / D1;
                    const int gidx = ((mn0 + i) * G + (mn1 + j)) * G + (mn2 + k);
                    unsafeAtomicAdd(&gmS[gidx], m);
                    float* sp = gvS + 3 * gidx;
                    unsafeAtomicAdd(sp + 0, tile[4 * c + 0]);
                    unsafeAtomicAdd(sp + 1, tile[4 * c + 1]);
                    unsafeAtomicAdd(sp + 2, tile[4 * c + 2]);
                }
            }
        } else if (anyAct && act) {
            // fallback: direct global atomics (bbox too large)
            float wa[3], wb[3], wc[3];
            wa[0] = 0.5f * (1.5f - fx0) * (1.5f - fx0);
            wa[1] = 0.75f - (fx0 - 1.0f) * (fx0 - 1.0f);
            wa[2] = 0.5f * (fx0 - 0.5f) * (fx0 - 0.5f);
            wb[0] = 0.5f * (1.5f - fx1) * (1.5f - fx1);
            wb[1] = 0.75f - (fx1 - 1.0f) * (fx1 - 1.0f);
            wb[2] = 0.5f * (fx1 - 0.5f) * (fx1 - 0.5f);
            wc[0] = 0.5f * (1.5f - fx2) * (1.5f - fx2);
            wc[1] = 0.75f - (fx2 - 1.0f) * (fx2 - 1.0f);
            wc[2] = 0.5f * (fx2 - 0.5f) * (fx2 - 0.5f);
            #pragma unroll
            for (int oi = 0; oi < 3; ++oi) {
                const int nx = clampi(sb0 + oi);
                const float dpx = ((float)oi - fx0) * DXc;
                #pragma unroll
                for (int oj = 0; oj < 3; ++oj) {
                    const int ny = clampi(sb1 + oj);
                    const float dpy = ((float)oj - fx1) * DXc;
                    const float wab = wa[oi] * wb[oj];
                    #pragma unroll
                    for (int ok = 0; ok < 3; ++ok) {
                        const int nz = clampi(sb2 + ok);
                        const float dpz = ((float)ok - fx2) * DXc;
                        const float w = wab * wc[ok];
                        const int gidx = (nx * G + ny) * G + nz;
                        unsafeAtomicAdd(&gmS[gidx], w * P_MASS);
                        float* sp = gvS + 3 * gidx;
                        unsafeAtomicAdd(sp + 0, w * (mvx + A00 * dpx + A01 * dpy + A02 * dpz));
                        unsafeAtomicAdd(sp + 1, w * (mvy + A10 * dpx + A11 * dpy + A12 * dpz));
                        unsafeAtomicAdd(sp + 2, w * (mvz + A20 * dpx + A21 * dpy + A22 * dpz));
                    }
                }
            }
        }

        // ======== zero substep p-2's per-wg bbox in buf[(p+1)%3] ========
        if (zvalid) {
            const int zD1 = zmx1 - zmn1 + 1, zD2 = zmx2 - zmn2 + 1;
            const int zvol = (zmx0 - zmn0 + 1) * zD1 * zD2;
            for (int c = threadIdx.x; c < zvol; c += NTHR) {
                const int k = c % zD2;
                const int t = c / zD2;
                const int j = t % zD1;
                const int i = t / zD1;
                const int gidx = ((zmn0 + i) * G + (zmn1 + j)) * G + (zmn2 + k);
                gmZ[gidx] = 0.f;
                float* zp = gvZ + 3 * gidx;
                zp[0] = 0.f; zp[1] = 0.f; zp[2] = 0.f;
            }
        }
        // shift bbox history
        zmn0 = pmn0; zmn1 = pmn1; zmn2 = pmn2;
        zmx0 = pmx0; zmx1 = pmx1; zmx2 = pmx2; zvalid = pvalid;
        pmn0 = mn0; pmn1 = mn1; pmn2 = mn2;
        pmx0 = mx0; pmx1 = mx1; pmx2 = mx2; pvalid = anyAct;

        gg.sync();
    }

    // ---- final frame output: grid_m of substep 599 ----
    {
        const float* gmL = bm + ((NSUB - 1) % 3) * G3;
        float* o = out + (NSUB / SPF - 1) * G3;
        for (int i = tid; i < G3; i += nth) o[i] = gmL[i] + vs;
    }
}

extern "C" void kernel_launch(void* const* d_in, const int* in_sizes, int n_in,
                              void* d_out, int out_size, void* d_ws, size_t ws_size,
                              hipStream_t stream) {
    const float* v  = (const float*)d_in[0];
    const float* q  = (const float*)d_in[1];
    const float* qd = (const float*)d_in[2];
    float* out = (float*)d_out;
    float* ws  = (float*)d_ws;
    void* args[] = { (void*)&v, (void*)&q, (void*)&qd, (void*)&out, (void*)&ws };
    hipLaunchCooperativeKernel(reinterpret_cast<void*>(mpm_sim),
                               dim3(NBLK), dim3(NTHR), args, 0, stream);
}

// Round 3
// 28333.926 us; speedup vs baseline: 2.9239x; 1.4252x over previous
//
#include <hip/hip_runtime.h>
#include <hip/hip_cooperative_groups.h>

namespace cg = cooperative_groups;

static constexpr int G    = 100;
static constexpr int G3   = G * G * G;
static constexpr int NP   = 13500;   // 30*15*30 particles
static constexpr int NSUB = 600;     // 20 frames x 30 substeps
static constexpr int SPF  = 30;      // substeps per frame
static constexpr int R    = 4;       // lanes per particle
static constexpr int NTHR = 256;
static constexpr int PPB  = NTHR / R;               // 64 particles per block
static constexpr int NBLK = (NP + PPB - 1) / PPB;   // 211
static constexpr int TC   = 4000;    // LDS tile capacity in cells (float4 each = 64000 B)

__device__ __forceinline__ int clampi(int v) {
    return v < 0 ? 0 : (v > G - 1 ? G - 1 : v);
}

// Persistent cooperative kernel. Triple-buffered float4 grid in ws:
//   g4[buf*G3 + idx] = (mom.x, mom.y, mom.z, mass)
// Phase p: gather substep p-1 from buf[(p-1)%3], scatter substep p into buf[p%3]
// (privatized through a per-workgroup LDS tile over the wg's particle bbox),
// zero substep p-2's per-wg bbox in buf[(p+1)%3]. One grid sync per phase.
// Each particle is handled by a 4-lane group (stencil cells split c%4); particle
// state is replicated bitwise-identically across the 4 lanes via shfl butterflies.
__launch_bounds__(NTHR)
__global__ void mpm_sim(const float* __restrict__ vscal,
                        const float* __restrict__ q0,
                        const float* __restrict__ qd0,
                        float* __restrict__ out,
                        float* __restrict__ ws)
{
    const float vs = vscal[0];
    float4* const g4 = reinterpret_cast<float4*>(ws);

    cg::grid_group gg = cg::this_grid();
    const int tid = blockIdx.x * NTHR + threadIdx.x;
    const int nth = NBLK * NTHR;
    const int pid = blockIdx.x * PPB + (threadIdx.x >> 2);
    const int sub = threadIdx.x & 3;
    const bool act = pid < NP;

    const float DT      = 5e-4f;
    const float INV_DX  = 100.0f;
    const float DXc     = 0.01f;
    const float MU      = (float)(1.0e5 / (2.0 * (1.0 + 0.3)));
    const float LAM     = (float)(1.0e5 * 0.3 / ((1.0 + 0.3) * (1.0 - 0.6)));
    const float P_MASS  = (float)(0.005 * 0.005 * 0.005 * 3000.0);
    const float KS      = (float)(-5.0e-4 * (0.005 * 0.005 * 0.005) * 4.0 * 100.0 * 100.0);
    const float DTG     = (float)(5.0e-4 * (-9.8));
    const float CSC     = 4.0f * INV_DX * INV_DX;   // 40000

    __shared__ float tile[4 * TC];   // AoS per cell: [mx,my,mz,mass]
    __shared__ int sred[6];          // bbox reduction

    // ---- init: zero all 3 grid buffers (ws is poisoned 0xAA) ----
    {
        const float4 z = make_float4(0.f, 0.f, 0.f, 0.f);
        for (int i = tid; i < 3 * G3; i += nth) g4[i] = z;
    }

    // ---- particle state, replicated across the 4 lanes of a group ----
    float px = 0.f, py = 0.f, pz = 0.f, vx = 0.f, vy = 0.f, vz = 0.f;
    float C00 = 0.f, C01 = 0.f, C02 = 0.f,
          C10 = 0.f, C11 = 0.f, C12 = 0.f,
          C20 = 0.f, C21 = 0.f, C22 = 0.f;
    float F00 = 1.f, F01 = 0.f, F02 = 0.f,
          F10 = 0.f, F11 = 1.f, F12 = 0.f,
          F20 = 0.f, F21 = 0.f, F22 = 1.f;
    if (act) {
        px = q0[3 * pid + 0]; py = q0[3 * pid + 1]; pz = q0[3 * pid + 2];
        vx = qd0[3 * pid + 0]; vy = qd0[3 * pid + 1]; vz = qd0[3 * pid + 2];
    }

    // per-wg bbox history (uniform across wg): p-1 and p-2 scatter bboxes
    int pmn0 = 0, pmn1 = 0, pmn2 = 0, pmx0 = -1, pmx1 = -1, pmx2 = -1; bool pvalid = false;
    int zmn0 = 0, zmn1 = 0, zmn2 = 0, zmx0 = -1, zmx1 = -1, zmx2 = -1; bool zvalid = false;

    gg.sync();

    for (int p = 0; p < NSUB; ++p) {
        const int bS = p % 3;
        const int bG = (p + 2) % 3;   // (p-1)%3 for p>0
        const int bZ = (p + 1) % 3;   // holds substep p-2 data
        float4*       __restrict__ gS4 = g4 + bS * G3;
        const float4* __restrict__ gG4 = g4 + bG * G3;
        float4*       __restrict__ gZ4 = g4 + bZ * G3;

        // frame output: grid_m of substep p-1
        if (p > 0 && ((p - 1) % SPF) == SPF - 1) {
            float* o = out + ((p - 1) / SPF) * G3;
            for (int i = tid; i < G3; i += nth) o[i] = gG4[i].w + vs;
        }

        int sb0 = 0, sb1 = 0, sb2 = 0;
        float fx0 = 0.f, fx1 = 0.f, fx2 = 0.f;
        float A00 = 0.f, A01 = 0.f, A02 = 0.f,
              A10 = 0.f, A11 = 0.f, A12 = 0.f,
              A20 = 0.f, A21 = 0.f, A22 = 0.f;
        float mvx = 0.f, mvy = 0.f, mvz = 0.f;

        if (act) {
            // ======== G2P gather for substep p-1 (cells c%4==sub per lane) ========
            if (p > 0) {
                const float xs0 = px * INV_DX, xs1 = py * INV_DX, xs2 = pz * INV_DX;
                const float fb0 = floorf(xs0 - 0.5f), fb1 = floorf(xs1 - 0.5f), fb2 = floorf(xs2 - 0.5f);
                const int b0 = (int)fb0, b1 = (int)fb1, b2 = (int)fb2;
                const float gx0 = xs0 - fb0, gx1 = xs1 - fb1, gx2 = xs2 - fb2;
                float wa[3], wb[3], wc[3];
                wa[0] = 0.5f * (1.5f - gx0) * (1.5f - gx0);
                wa[1] = 0.75f - (gx0 - 1.0f) * (gx0 - 1.0f);
                wa[2] = 0.5f * (gx0 - 0.5f) * (gx0 - 0.5f);
                wb[0] = 0.5f * (1.5f - gx1) * (1.5f - gx1);
                wb[1] = 0.75f - (gx1 - 1.0f) * (gx1 - 1.0f);
                wb[2] = 0.5f * (gx1 - 0.5f) * (gx1 - 0.5f);
                wc[0] = 0.5f * (1.5f - gx2) * (1.5f - gx2);
                wc[1] = 0.75f - (gx2 - 1.0f) * (gx2 - 1.0f);
                wc[2] = 0.5f * (gx2 - 0.5f) * (gx2 - 0.5f);

                float nvx = 0.f, nvy = 0.f, nvz = 0.f;
                float nc00 = 0.f, nc01 = 0.f, nc02 = 0.f,
                      nc10 = 0.f, nc11 = 0.f, nc12 = 0.f,
                      nc20 = 0.f, nc21 = 0.f, nc22 = 0.f;
                #pragma unroll
                for (int t = 0; t < 7; ++t) {
                    const int c = sub + 4 * t;
                    if (c >= 27) break;
                    const int oi = c / 9;
                    const int rem = c - 9 * oi;
                    const int oj = rem / 3;
                    const int ok = rem - 3 * oj;
                    const int nx = clampi(b0 + oi);
                    const int ny = clampi(b1 + oj);
                    const int nz = clampi(b2 + ok);
                    const float dpx = ((float)oi - gx0) * DXc;
                    const float dpy = ((float)oj - gx1) * DXc;
                    const float dpz = ((float)ok - gx2) * DXc;
                    const float w = wa[oi] * wb[oj] * wc[ok];
                    const float4 gq = gG4[(nx * G + ny) * G + nz];
                    const float den = gq.w + vs;
                    float gvx = gq.x / den;
                    float gvy = gq.y / den;
                    float gvz = gq.z / den;
                    if (nx < 3       && gvx < 0.f) gvx = 0.f;
                    if (nx >= G - 3  && gvx > 0.f) gvx = 0.f;
                    if (ny < 3       && gvy < 0.f) gvy = 0.f;
                    if (ny >= G - 3  && gvy > 0.f) gvy = 0.f;
                    if (nz < 3       && gvz < 0.f) gvz = 0.f;
                    if (nz >= G - 3  && gvz > 0.f) gvz = 0.f;
                    nvx += w * gvx; nvy += w * gvy; nvz += w * gvz;
                    const float wgx = w * gvx, wgy = w * gvy, wgz = w * gvz;
                    nc00 += wgx * dpx; nc01 += wgx * dpy; nc02 += wgx * dpz;
                    nc10 += wgy * dpx; nc11 += wgy * dpy; nc12 += wgy * dpz;
                    nc20 += wgz * dpx; nc21 += wgz * dpy; nc22 += wgz * dpz;
                }
                // 4-lane butterfly: all lanes end with identical full sums
                #define BFLY(v) { v += __shfl_xor(v, 1); v += __shfl_xor(v, 2); }
                BFLY(nvx) BFLY(nvy) BFLY(nvz)
                BFLY(nc00) BFLY(nc01) BFLY(nc02)
                BFLY(nc10) BFLY(nc11) BFLY(nc12)
                BFLY(nc20) BFLY(nc21) BFLY(nc22)
                #undef BFLY
                vx = nvx; vy = nvy; vz = nvz;
                C00 = CSC * nc00; C01 = CSC * nc01; C02 = CSC * nc02;
                C10 = CSC * nc10; C11 = CSC * nc11; C12 = CSC * nc12;
                C20 = CSC * nc20; C21 = CSC * nc21; C22 = CSC * nc22;
                px += DT * vx; py += DT * vy; pz += DT * vz;
            }

            // ======== F update: F = (I + DT*C) @ F (replicated) ========
            {
                const float t00 = F00 + DT * (C00 * F00 + C01 * F10 + C02 * F20);
                const float t01 = F01 + DT * (C00 * F01 + C01 * F11 + C02 * F21);
                const float t02 = F02 + DT * (C00 * F02 + C01 * F12 + C02 * F22);
                const float t10 = F10 + DT * (C10 * F00 + C11 * F10 + C12 * F20);
                const float t11 = F11 + DT * (C10 * F01 + C11 * F11 + C12 * F21);
                const float t12 = F12 + DT * (C10 * F02 + C11 * F12 + C12 * F22);
                const float t20 = F20 + DT * (C20 * F00 + C21 * F10 + C22 * F20);
                const float t21 = F21 + DT * (C20 * F01 + C21 * F11 + C22 * F21);
                const float t22 = F22 + DT * (C20 * F02 + C21 * F12 + C22 * F22);
                F00 = t00; F01 = t01; F02 = t02;
                F10 = t10; F11 = t11; F12 = t12;
                F20 = t20; F21 = t21; F22 = t22;
            }

            // ======== neo-Hookean PK1 stress -> affine (replicated) ========
            const float c00 = F11 * F22 - F12 * F21;
            const float c01 = F12 * F20 - F10 * F22;
            const float c02 = F10 * F21 - F11 * F20;
            const float det = F00 * c00 + F01 * c01 + F02 * c02;
            const float c10 = F02 * F21 - F01 * F22;
            const float c11 = F00 * F22 - F02 * F20;
            const float c12 = F01 * F20 - F00 * F21;
            const float c20 = F01 * F12 - F02 * F11;
            const float c21 = F02 * F10 - F00 * F12;
            const float c22 = F00 * F11 - F01 * F10;
            const float idet = 1.0f / det;
            const float lj = LAM * logf(fmaxf(det, 1e-6f));
            const float fit00 = c00 * idet, fit01 = c01 * idet, fit02 = c02 * idet;
            const float fit10 = c10 * idet, fit11 = c11 * idet, fit12 = c12 * idet;
            const float fit20 = c20 * idet, fit21 = c21 * idet, fit22 = c22 * idet;
            const float P00 = MU * (F00 - fit00) + lj * fit00;
            const float P01 = MU * (F01 - fit01) + lj * fit01;
            const float P02 = MU * (F02 - fit02) + lj * fit02;
            const float P10 = MU * (F10 - fit10) + lj * fit10;
            const float P11 = MU * (F11 - fit11) + lj * fit11;
            const float P12 = MU * (F12 - fit12) + lj * fit12;
            const float P20 = MU * (F20 - fit20) + lj * fit20;
            const float P21 = MU * (F21 - fit21) + lj * fit21;
            const float P22 = MU * (F22 - fit22) + lj * fit22;
            A00 = KS * (P00 * F00 + P01 * F01 + P02 * F02) + P_MASS * C00;
            A01 = KS * (P00 * F10 + P01 * F11 + P02 * F12) + P_MASS * C01;
            A02 = KS * (P00 * F20 + P01 * F21 + P02 * F22) + P_MASS * C02;
            A10 = KS * (P10 * F00 + P11 * F01 + P12 * F02) + P_MASS * C10;
            A11 = KS * (P10 * F10 + P11 * F11 + P12 * F12) + P_MASS * C11;
            A12 = KS * (P10 * F20 + P11 * F21 + P12 * F22) + P_MASS * C12;
            A20 = KS * (P20 * F00 + P21 * F01 + P22 * F02) + P_MASS * C20;
            A21 = KS * (P20 * F10 + P21 * F11 + P22 * F12) + P_MASS * C21;
            A22 = KS * (P20 * F20 + P21 * F21 + P22 * F22) + P_MASS * C22;

            // scatter base (from updated x)
            const float xs0 = px * INV_DX, xs1 = py * INV_DX, xs2 = pz * INV_DX;
            const float fb0 = floorf(xs0 - 0.5f), fb1 = floorf(xs1 - 0.5f), fb2 = floorf(xs2 - 0.5f);
            sb0 = (int)fb0; sb1 = (int)fb1; sb2 = (int)fb2;
            fx0 = xs0 - fb0; fx1 = xs1 - fb1; fx2 = xs2 - fb2;
            mvx = P_MASS * vx;
            mvy = P_MASS * (vy + DTG);
            mvz = P_MASS * vz;
        }

        // ======== per-wg clamped scatter bbox reduction ========
        if (threadIdx.x == 0) {
            sred[0] = INT_MAX; sred[1] = INT_MAX; sred[2] = INT_MAX;
            sred[3] = INT_MIN; sred[4] = INT_MIN; sred[5] = INT_MIN;
        }
        __syncthreads();
        if (act && sub == 0) {
            atomicMin(&sred[0], clampi(sb0)); atomicMax(&sred[3], clampi(sb0 + 2));
            atomicMin(&sred[1], clampi(sb1)); atomicMax(&sred[4], clampi(sb1 + 2));
            atomicMin(&sred[2], clampi(sb2)); atomicMax(&sred[5], clampi(sb2 + 2));
        }
        __syncthreads();
        const int mn0 = sred[0], mn1 = sred[1], mn2 = sred[2];
        const int mx0 = sred[3], mx1 = sred[4], mx2 = sred[5];
        const bool anyAct = (mx0 >= mn0);
        const int D1 = mx1 - mn1 + 1, D2 = mx2 - mn2 + 1;
        const int vol = anyAct ? (mx0 - mn0 + 1) * D1 * D2 : 0;
        const bool useLDS = anyAct && (vol <= TC);
        __syncthreads();   // tile reuse guard

        // weights for scatter (replicated per lane group)
        float wa0 = 0.f, wa1 = 0.f, wa2 = 0.f, wb0 = 0.f, wb1 = 0.f, wb2 = 0.f,
              wcc0 = 0.f, wcc1 = 0.f, wcc2 = 0.f;
        if (act) {
            wa0 = 0.5f * (1.5f - fx0) * (1.5f - fx0);
            wa1 = 0.75f - (fx0 - 1.0f) * (fx0 - 1.0f);
            wa2 = 0.5f * (fx0 - 0.5f) * (fx0 - 0.5f);
            wb0 = 0.5f * (1.5f - fx1) * (1.5f - fx1);
            wb1 = 0.75f - (fx1 - 1.0f) * (fx1 - 1.0f);
            wb2 = 0.5f * (fx1 - 0.5f) * (fx1 - 0.5f);
            wcc0 = 0.5f * (1.5f - fx2) * (1.5f - fx2);
            wcc1 = 0.75f - (fx2 - 1.0f) * (fx2 - 1.0f);
            wcc2 = 0.5f * (fx2 - 0.5f) * (fx2 - 0.5f);
        }
        const float WA[3] = { wa0, wa1, wa2 };
        const float WB[3] = { wb0, wb1, wb2 };
        const float WC[3] = { wcc0, wcc1, wcc2 };

        if (useLDS) {
            // zero tile portion (float4 stores)
            float4* t4 = reinterpret_cast<float4*>(tile);
            const float4 z = make_float4(0.f, 0.f, 0.f, 0.f);
            for (int i = threadIdx.x; i < vol; i += NTHR) t4[i] = z;
            __syncthreads();
            if (act) {
                #pragma unroll
                for (int t = 0; t < 7; ++t) {
                    const int c = sub + 4 * t;
                    if (c >= 27) break;
                    const int oi = c / 9;
                    const int rem = c - 9 * oi;
                    const int oj = rem / 3;
                    const int ok = rem - 3 * oj;
                    const int li  = clampi(sb0 + oi) - mn0;
                    const int lj2 = clampi(sb1 + oj) - mn1;
                    const int lk  = clampi(sb2 + ok) - mn2;
                    const float dpx = ((float)oi - fx0) * DXc;
                    const float dpy = ((float)oj - fx1) * DXc;
                    const float dpz = ((float)ok - fx2) * DXc;
                    const float w = WA[oi] * WB[oj] * WC[ok];
                    const int c4 = 4 * ((li * D1 + lj2) * D2 + lk);
                    atomicAdd(&tile[c4 + 0], w * (mvx + A00 * dpx + A01 * dpy + A02 * dpz));
                    atomicAdd(&tile[c4 + 1], w * (mvy + A10 * dpx + A11 * dpy + A12 * dpz));
                    atomicAdd(&tile[c4 + 2], w * (mvz + A20 * dpx + A21 * dpy + A22 * dpz));
                    atomicAdd(&tile[c4 + 3], w * P_MASS);
                }
            }
            __syncthreads();
            // flush tile -> global (device-scope atomics), skip empty cells
            for (int c = threadIdx.x; c < vol; c += NTHR) {
                const float m = tile[4 * c + 3];
                if (m != 0.f) {
                    const int k = c % D2;
                    const int t = c / D2;
                    const int j = t % D1;
                    const int i = t / D1;
                    const int gidx = ((mn0 + i) * G + (mn1 + j)) * G + (mn2 + k);
                    float* gp = reinterpret_cast<float*>(gS4 + gidx);
                    unsafeAtomicAdd(gp + 0, tile[4 * c + 0]);
                    unsafeAtomicAdd(gp + 1, tile[4 * c + 1]);
                    unsafeAtomicAdd(gp + 2, tile[4 * c + 2]);
                    unsafeAtomicAdd(gp + 3, m);
                }
            }
        } else if (anyAct && act) {
            // fallback: direct global atomics (bbox too large)
            #pragma unroll
            for (int t = 0; t < 7; ++t) {
                const int c = sub + 4 * t;
                if (c >= 27) break;
                const int oi = c / 9;
                const int rem = c - 9 * oi;
                const int oj = rem / 3;
                const int ok = rem - 3 * oj;
                const int nx = clampi(sb0 + oi);
                const int ny = clampi(sb1 + oj);
                const int nz = clampi(sb2 + ok);
                const float dpx = ((float)oi - fx0) * DXc;
                const float dpy = ((float)oj - fx1) * DXc;
                const float dpz = ((float)ok - fx2) * DXc;
                const float w = WA[oi] * WB[oj] * WC[ok];
                float* gp = reinterpret_cast<float*>(gS4 + (nx * G + ny) * G + nz);
                unsafeAtomicAdd(gp + 0, w * (mvx + A00 * dpx + A01 * dpy + A02 * dpz));
                unsafeAtomicAdd(gp + 1, w * (mvy + A10 * dpx + A11 * dpy + A12 * dpz));
                unsafeAtomicAdd(gp + 2, w * (mvz + A20 * dpx + A21 * dpy + A22 * dpz));
                unsafeAtomicAdd(gp + 3, w * P_MASS);
            }
        }

        // ======== zero substep p-2's per-wg bbox in buf[(p+1)%3] ========
        if (zvalid) {
            const int zD1 = zmx1 - zmn1 + 1, zD2 = zmx2 - zmn2 + 1;
            const int zvol = (zmx0 - zmn0 + 1) * zD1 * zD2;
            const float4 z = make_float4(0.f, 0.f, 0.f, 0.f);
            for (int c = threadIdx.x; c < zvol; c += NTHR) {
                const int k = c % zD2;
                const int t = c / zD2;
                const int j = t % zD1;
                const int i = t / zD1;
                gZ4[((zmn0 + i) * G + (zmn1 + j)) * G + (zmn2 + k)] = z;
            }
        }
        // shift bbox history
        zmn0 = pmn0; zmn1 = pmn1; zmn2 = pmn2;
        zmx0 = pmx0; zmx1 = pmx1; zmx2 = pmx2; zvalid = pvalid;
        pmn0 = mn0; pmn1 = mn1; pmn2 = mn2;
        pmx0 = mx0; pmx1 = mx1; pmx2 = mx2; pvalid = anyAct;

        gg.sync();
    }

    // ---- final frame output: grid_m of substep 599 ----
    {
        const float4* gL4 = g4 + ((NSUB - 1) % 3) * G3;
        float* o = out + (NSUB / SPF - 1) * G3;
        for (int i = tid; i < G3; i += nth) o[i] = gL4[i].w + vs;
    }
}

extern "C" void kernel_launch(void* const* d_in, const int* in_sizes, int n_in,
                              void* d_out, int out_size, void* d_ws, size_t ws_size,
                              hipStream_t stream) {
    const float* v  = (const float*)d_in[0];
    const float* q  = (const float*)d_in[1];
    const float* qd = (const float*)d_in[2];
    float* out = (float*)d_out;
    float* ws  = (float*)d_ws;
    void* args[] = { (void*)&v, (void*)&q, (void*)&qd, (void*)&out, (void*)&ws };
    hipLaunchCooperativeKernel(reinterpret_cast<void*>(mpm_sim),
                               dim3(NBLK), dim3(NTHR), args, 0, stream);
}

// Round 4
// 24106.589 us; speedup vs baseline: 3.4367x; 1.1754x over previous
//
#include <hip/hip_runtime.h>
#include <hip/hip_cooperative_groups.h>

namespace cg = cooperative_groups;

static constexpr int G    = 100;
static constexpr int G3   = G * G * G;
static constexpr int NP   = 13500;   // 30*15*30 particles
static constexpr int NSUB = 600;     // 20 frames x 30 substeps
static constexpr int SPF  = 30;      // substeps per frame
static constexpr int R    = 8;       // lanes per particle
static constexpr int NTHR = 1024;
static constexpr int NBLK = 108;     // 6x3x6 bricks of 5x5x5 particles
static constexpr int TC   = 4000;    // LDS tile capacity in cells (float4 each = 64000 B)

__device__ __forceinline__ int clampi(int v) {
    return v < 0 ? 0 : (v > G - 1 ? G - 1 : v);
}

// Persistent cooperative kernel. Triple-buffered float4 grid in ws:
//   g4[buf*G3 + idx] = (mom.x, mom.y, mom.z, mass)
// Phase p: gather substep p-1 from buf[(p-1)%3], scatter substep p into buf[p%3]
// (privatized through a per-workgroup LDS tile over the wg's particle bbox),
// zero substep p-2's per-wg bbox in buf[(p+1)%3]. One grid sync per phase.
// Particles are statically re-grouped into 5x5x5 spatial bricks (one brick per
// wg) so per-wg bboxes are compact cubes (~6^3 cells) with minimal halo overlap.
// Each particle is handled by an 8-lane group (stencil cells split c%8); state
// is replicated bitwise-identically across the 8 lanes via shfl butterflies.
__launch_bounds__(NTHR)
__global__ void mpm_sim(const float* __restrict__ vscal,
                        const float* __restrict__ q0,
                        const float* __restrict__ qd0,
                        float* __restrict__ out,
                        float* __restrict__ ws)
{
    const float vs = vscal[0];
    float4* const g4 = reinterpret_cast<float4*>(ws);

    cg::grid_group gg = cg::this_grid();
    const int tid = blockIdx.x * NTHR + threadIdx.x;
    const int nth = NBLK * NTHR;

    // brick/slot -> original particle index
    const int slot = threadIdx.x >> 3;        // 0..127
    const int sub  = threadIdx.x & 7;         // lane within particle group
    const bool act = slot < 125;
    int pid = 0;
    if (act) {
        const int b  = blockIdx.x;            // (bx*3+by)*6+bz
        const int bx = b / 18;
        const int by = (b / 6) % 3;
        const int bz = b % 6;
        const int lx = slot / 25;
        const int rem = slot % 25;
        const int ly = rem / 5;
        const int lz = rem % 5;
        const int ix = bx * 5 + lx;
        const int iy = by * 5 + ly;
        const int iz = bz * 5 + lz;
        pid = (ix * 15 + iy) * 30 + iz;
    }

    const float DT      = 5e-4f;
    const float INV_DX  = 100.0f;
    const float DXc     = 0.01f;
    const float MU      = (float)(1.0e5 / (2.0 * (1.0 + 0.3)));
    const float LAM     = (float)(1.0e5 * 0.3 / ((1.0 + 0.3) * (1.0 - 0.6)));
    const float P_MASS  = (float)(0.005 * 0.005 * 0.005 * 3000.0);
    const float KS      = (float)(-5.0e-4 * (0.005 * 0.005 * 0.005) * 4.0 * 100.0 * 100.0);
    const float DTG     = (float)(5.0e-4 * (-9.8));
    const float CSC     = 4.0f * INV_DX * INV_DX;   // 40000

    __shared__ float tile[4 * TC];   // AoS per cell: [mx,my,mz,mass]
    __shared__ int sred[6];          // bbox reduction

    // ---- init: zero all 3 grid buffers (ws is poisoned 0xAA) ----
    {
        const float4 z = make_float4(0.f, 0.f, 0.f, 0.f);
        for (int i = tid; i < 3 * G3; i += nth) g4[i] = z;
    }

    // ---- particle state, replicated across the 8 lanes of a group ----
    float px = 0.f, py = 0.f, pz = 0.f, vx = 0.f, vy = 0.f, vz = 0.f;
    float C00 = 0.f, C01 = 0.f, C02 = 0.f,
          C10 = 0.f, C11 = 0.f, C12 = 0.f,
          C20 = 0.f, C21 = 0.f, C22 = 0.f;
    float F00 = 1.f, F01 = 0.f, F02 = 0.f,
          F10 = 0.f, F11 = 1.f, F12 = 0.f,
          F20 = 0.f, F21 = 0.f, F22 = 1.f;
    if (act) {
        px = q0[3 * pid + 0]; py = q0[3 * pid + 1]; pz = q0[3 * pid + 2];
        vx = qd0[3 * pid + 0]; vy = qd0[3 * pid + 1]; vz = qd0[3 * pid + 2];
    }

    // per-wg bbox history (uniform across wg): p-1 and p-2 scatter bboxes
    int pmn0 = 0, pmn1 = 0, pmn2 = 0, pmx0 = -1, pmx1 = -1, pmx2 = -1; bool pvalid = false;
    int zmn0 = 0, zmn1 = 0, zmn2 = 0, zmx0 = -1, zmx1 = -1, zmx2 = -1; bool zvalid = false;

    gg.sync();

    for (int p = 0; p < NSUB; ++p) {
        const int bS = p % 3;
        const int bG = (p + 2) % 3;   // (p-1)%3 for p>0
        const int bZ = (p + 1) % 3;   // holds substep p-2 data
        float4*       __restrict__ gS4 = g4 + bS * G3;
        const float4* __restrict__ gG4 = g4 + bG * G3;
        float4*       __restrict__ gZ4 = g4 + bZ * G3;

        // frame output: grid_m of substep p-1
        if (p > 0 && ((p - 1) % SPF) == SPF - 1) {
            float* o = out + ((p - 1) / SPF) * G3;
            for (int i = tid; i < G3; i += nth) o[i] = gG4[i].w + vs;
        }

        int sb0 = 0, sb1 = 0, sb2 = 0;
        float fx0 = 0.f, fx1 = 0.f, fx2 = 0.f;
        float A00 = 0.f, A01 = 0.f, A02 = 0.f,
              A10 = 0.f, A11 = 0.f, A12 = 0.f,
              A20 = 0.f, A21 = 0.f, A22 = 0.f;
        float mvx = 0.f, mvy = 0.f, mvz = 0.f;

        if (act) {
            // ======== G2P gather for substep p-1 (cells c%8==sub per lane) ========
            if (p > 0) {
                const float xs0 = px * INV_DX, xs1 = py * INV_DX, xs2 = pz * INV_DX;
                const float fb0 = floorf(xs0 - 0.5f), fb1 = floorf(xs1 - 0.5f), fb2 = floorf(xs2 - 0.5f);
                const int b0 = (int)fb0, b1 = (int)fb1, b2 = (int)fb2;
                const float gx0 = xs0 - fb0, gx1 = xs1 - fb1, gx2 = xs2 - fb2;
                float wa[3], wb[3], wc[3];
                wa[0] = 0.5f * (1.5f - gx0) * (1.5f - gx0);
                wa[1] = 0.75f - (gx0 - 1.0f) * (gx0 - 1.0f);
                wa[2] = 0.5f * (gx0 - 0.5f) * (gx0 - 0.5f);
                wb[0] = 0.5f * (1.5f - gx1) * (1.5f - gx1);
                wb[1] = 0.75f - (gx1 - 1.0f) * (gx1 - 1.0f);
                wb[2] = 0.5f * (gx1 - 0.5f) * (gx1 - 0.5f);
                wc[0] = 0.5f * (1.5f - gx2) * (1.5f - gx2);
                wc[1] = 0.75f - (gx2 - 1.0f) * (gx2 - 1.0f);
                wc[2] = 0.5f * (gx2 - 0.5f) * (gx2 - 0.5f);

                float nvx = 0.f, nvy = 0.f, nvz = 0.f;
                float nc00 = 0.f, nc01 = 0.f, nc02 = 0.f,
                      nc10 = 0.f, nc11 = 0.f, nc12 = 0.f,
                      nc20 = 0.f, nc21 = 0.f, nc22 = 0.f;
                #pragma unroll
                for (int t = 0; t < 4; ++t) {
                    const int c = sub + 8 * t;
                    if (c >= 27) break;
                    const int oi = c / 9;
                    const int rem = c - 9 * oi;
                    const int oj = rem / 3;
                    const int ok = rem - 3 * oj;
                    const int nx = clampi(b0 + oi);
                    const int ny = clampi(b1 + oj);
                    const int nz = clampi(b2 + ok);
                    const float dpx = ((float)oi - gx0) * DXc;
                    const float dpy = ((float)oj - gx1) * DXc;
                    const float dpz = ((float)ok - gx2) * DXc;
                    const float w = wa[oi] * wb[oj] * wc[ok];
                    const float4 gq = gG4[(nx * G + ny) * G + nz];
                    const float den = gq.w + vs;
                    float gvx = gq.x / den;
                    float gvy = gq.y / den;
                    float gvz = gq.z / den;
                    if (nx < 3       && gvx < 0.f) gvx = 0.f;
                    if (nx >= G - 3  && gvx > 0.f) gvx = 0.f;
                    if (ny < 3       && gvy < 0.f) gvy = 0.f;
                    if (ny >= G - 3  && gvy > 0.f) gvy = 0.f;
                    if (nz < 3       && gvz < 0.f) gvz = 0.f;
                    if (nz >= G - 3  && gvz > 0.f) gvz = 0.f;
                    nvx += w * gvx; nvy += w * gvy; nvz += w * gvz;
                    const float wgx = w * gvx, wgy = w * gvy, wgz = w * gvz;
                    nc00 += wgx * dpx; nc01 += wgx * dpy; nc02 += wgx * dpz;
                    nc10 += wgy * dpx; nc11 += wgy * dpy; nc12 += wgy * dpz;
                    nc20 += wgz * dpx; nc21 += wgz * dpy; nc22 += wgz * dpz;
                }
                // 8-lane butterfly: all lanes end with identical full sums
                #define BFLY(v) { v += __shfl_xor(v, 1); v += __shfl_xor(v, 2); v += __shfl_xor(v, 4); }
                BFLY(nvx) BFLY(nvy) BFLY(nvz)
                BFLY(nc00) BFLY(nc01) BFLY(nc02)
                BFLY(nc10) BFLY(nc11) BFLY(nc12)
                BFLY(nc20) BFLY(nc21) BFLY(nc22)
                #undef BFLY
                vx = nvx; vy = nvy; vz = nvz;
                C00 = CSC * nc00; C01 = CSC * nc01; C02 = CSC * nc02;
                C10 = CSC * nc10; C11 = CSC * nc11; C12 = CSC * nc12;
                C20 = CSC * nc20; C21 = CSC * nc21; C22 = CSC * nc22;
                px += DT * vx; py += DT * vy; pz += DT * vz;
            }

            // ======== F update: F = (I + DT*C) @ F (replicated) ========
            {
                const float t00 = F00 + DT * (C00 * F00 + C01 * F10 + C02 * F20);
                const float t01 = F01 + DT * (C00 * F01 + C01 * F11 + C02 * F21);
                const float t02 = F02 + DT * (C00 * F02 + C01 * F12 + C02 * F22);
                const float t10 = F10 + DT * (C10 * F00 + C11 * F10 + C12 * F20);
                const float t11 = F11 + DT * (C10 * F01 + C11 * F11 + C12 * F21);
                const float t12 = F12 + DT * (C10 * F02 + C11 * F12 + C12 * F22);
                const float t20 = F20 + DT * (C20 * F00 + C21 * F10 + C22 * F20);
                const float t21 = F21 + DT * (C20 * F01 + C21 * F11 + C22 * F21);
                const float t22 = F22 + DT * (C20 * F02 + C21 * F12 + C22 * F22);
                F00 = t00; F01 = t01; F02 = t02;
                F10 = t10; F11 = t11; F12 = t12;
                F20 = t20; F21 = t21; F22 = t22;
            }

            // ======== neo-Hookean PK1 stress -> affine (replicated) ========
            const float c00 = F11 * F22 - F12 * F21;
            const float c01 = F12 * F20 - F10 * F22;
            const float c02 = F10 * F21 - F11 * F20;
            const float det = F00 * c00 + F01 * c01 + F02 * c02;
            const float c10 = F02 * F21 - F01 * F22;
            const float c11 = F00 * F22 - F02 * F20;
            const float c12 = F01 * F20 - F00 * F21;
            const float c20 = F01 * F12 - F02 * F11;
            const float c21 = F02 * F10 - F00 * F12;
            const float c22 = F00 * F11 - F01 * F10;
            const float idet = 1.0f / det;
            const float lj = LAM * logf(fmaxf(det, 1e-6f));
            const float fit00 = c00 * idet, fit01 = c01 * idet, fit02 = c02 * idet;
            const float fit10 = c10 * idet, fit11 = c11 * idet, fit12 = c12 * idet;
            const float fit20 = c20 * idet, fit21 = c21 * idet, fit22 = c22 * idet;
            const float P00 = MU * (F00 - fit00) + lj * fit00;
            const float P01 = MU * (F01 - fit01) + lj * fit01;
            const float P02 = MU * (F02 - fit02) + lj * fit02;
            const float P10 = MU * (F10 - fit10) + lj * fit10;
            const float P11 = MU * (F11 - fit11) + lj * fit11;
            const float P12 = MU * (F12 - fit12) + lj * fit12;
            const float P20 = MU * (F20 - fit20) + lj * fit20;
            const float P21 = MU * (F21 - fit21) + lj * fit21;
            const float P22 = MU * (F22 - fit22) + lj * fit22;
            A00 = KS * (P00 * F00 + P01 * F01 + P02 * F02) + P_MASS * C00;
            A01 = KS * (P00 * F10 + P01 * F11 + P02 * F12) + P_MASS * C01;
            A02 = KS * (P00 * F20 + P01 * F21 + P02 * F22) + P_MASS * C02;
            A10 = KS * (P10 * F00 + P11 * F01 + P12 * F02) + P_MASS * C10;
            A11 = KS * (P10 * F10 + P11 * F11 + P12 * F12) + P_MASS * C11;
            A12 = KS * (P10 * F20 + P11 * F21 + P12 * F22) + P_MASS * C12;
            A20 = KS * (P20 * F00 + P21 * F01 + P22 * F02) + P_MASS * C20;
            A21 = KS * (P20 * F10 + P21 * F11 + P22 * F12) + P_MASS * C21;
            A22 = KS * (P20 * F20 + P21 * F21 + P22 * F22) + P_MASS * C22;

            // scatter base (from updated x)
            const float xs0 = px * INV_DX, xs1 = py * INV_DX, xs2 = pz * INV_DX;
            const float fb0 = floorf(xs0 - 0.5f), fb1 = floorf(xs1 - 0.5f), fb2 = floorf(xs2 - 0.5f);
            sb0 = (int)fb0; sb1 = (int)fb1; sb2 = (int)fb2;
            fx0 = xs0 - fb0; fx1 = xs1 - fb1; fx2 = xs2 - fb2;
            mvx = P_MASS * vx;
            mvy = P_MASS * (vy + DTG);
            mvz = P_MASS * vz;
        }

        // ======== per-wg clamped scatter bbox reduction ========
        if (threadIdx.x == 0) {
            sred[0] = INT_MAX; sred[1] = INT_MAX; sred[2] = INT_MAX;
            sred[3] = INT_MIN; sred[4] = INT_MIN; sred[5] = INT_MIN;
        }
        __syncthreads();
        if (act && sub == 0) {
            atomicMin(&sred[0], clampi(sb0)); atomicMax(&sred[3], clampi(sb0 + 2));
            atomicMin(&sred[1], clampi(sb1)); atomicMax(&sred[4], clampi(sb1 + 2));
            atomicMin(&sred[2], clampi(sb2)); atomicMax(&sred[5], clampi(sb2 + 2));
        }
        __syncthreads();
        const int mn0 = sred[0], mn1 = sred[1], mn2 = sred[2];
        const int mx0 = sred[3], mx1 = sred[4], mx2 = sred[5];
        const bool anyAct = (mx0 >= mn0);
        const int D1 = mx1 - mn1 + 1, D2 = mx2 - mn2 + 1;
        const int vol = anyAct ? (mx0 - mn0 + 1) * D1 * D2 : 0;
        const bool useLDS = anyAct && (vol <= TC);
        __syncthreads();   // tile reuse guard

        // weights for scatter (replicated per lane group)
        float wa0 = 0.f, wa1 = 0.f, wa2 = 0.f, wb0 = 0.f, wb1 = 0.f, wb2 = 0.f,
              wcc0 = 0.f, wcc1 = 0.f, wcc2 = 0.f;
        if (act) {
            wa0 = 0.5f * (1.5f - fx0) * (1.5f - fx0);
            wa1 = 0.75f - (fx0 - 1.0f) * (fx0 - 1.0f);
            wa2 = 0.5f * (fx0 - 0.5f) * (fx0 - 0.5f);
            wb0 = 0.5f * (1.5f - fx1) * (1.5f - fx1);
            wb1 = 0.75f - (fx1 - 1.0f) * (fx1 - 1.0f);
            wb2 = 0.5f * (fx1 - 0.5f) * (fx1 - 0.5f);
            wcc0 = 0.5f * (1.5f - fx2) * (1.5f - fx2);
            wcc1 = 0.75f - (fx2 - 1.0f) * (fx2 - 1.0f);
            wcc2 = 0.5f * (fx2 - 0.5f) * (fx2 - 0.5f);
        }
        const float WA[3] = { wa0, wa1, wa2 };
        const float WB[3] = { wb0, wb1, wb2 };
        const float WC[3] = { wcc0, wcc1, wcc2 };

        if (useLDS) {
            // zero tile portion (float4 stores)
            float4* t4 = reinterpret_cast<float4*>(tile);
            const float4 z = make_float4(0.f, 0.f, 0.f, 0.f);
            for (int i = threadIdx.x; i < vol; i += NTHR) t4[i] = z;
            __syncthreads();
            if (act) {
                #pragma unroll
                for (int t = 0; t < 4; ++t) {
                    const int c = sub + 8 * t;
                    if (c >= 27) break;
                    const int oi = c / 9;
                    const int rem = c - 9 * oi;
                    const int oj = rem / 3;
                    const int ok = rem - 3 * oj;
                    const int li  = clampi(sb0 + oi) - mn0;
                    const int lj2 = clampi(sb1 + oj) - mn1;
                    const int lk  = clampi(sb2 + ok) - mn2;
                    const float dpx = ((float)oi - fx0) * DXc;
                    const float dpy = ((float)oj - fx1) * DXc;
                    const float dpz = ((float)ok - fx2) * DXc;
                    const float w = WA[oi] * WB[oj] * WC[ok];
                    const int c4 = 4 * ((li * D1 + lj2) * D2 + lk);
                    atomicAdd(&tile[c4 + 0], w * (mvx + A00 * dpx + A01 * dpy + A02 * dpz));
                    atomicAdd(&tile[c4 + 1], w * (mvy + A10 * dpx + A11 * dpy + A12 * dpz));
                    atomicAdd(&tile[c4 + 2], w * (mvz + A20 * dpx + A21 * dpy + A22 * dpz));
                    atomicAdd(&tile[c4 + 3], w * P_MASS);
                }
            }
            __syncthreads();
            // flush tile -> global (device-scope atomics), skip empty cells
            for (int c = threadIdx.x; c < vol; c += NTHR) {
                const float m = tile[4 * c + 3];
                if (m != 0.f) {
                    const int k = c % D2;
                    const int t = c / D2;
                    const int j = t % D1;
                    const int i = t / D1;
                    const int gidx = ((mn0 + i) * G + (mn1 + j)) * G + (mn2 + k);
                    float* gp = reinterpret_cast<float*>(gS4 + gidx);
                    unsafeAtomicAdd(gp + 0, tile[4 * c + 0]);
                    unsafeAtomicAdd(gp + 1, tile[4 * c + 1]);
                    unsafeAtomicAdd(gp + 2, tile[4 * c + 2]);
                    unsafeAtomicAdd(gp + 3, m);
                }
            }
        } else if (anyAct && act) {
            // fallback: direct global atomics (bbox too large)
            #pragma unroll
            for (int t = 0; t < 4; ++t) {
                const int c = sub + 8 * t;
                if (c >= 27) break;
                const int oi = c / 9;
                const int rem = c - 9 * oi;
                const int oj = rem / 3;
                const int ok = rem - 3 * oj;
                const int nx = clampi(sb0 + oi);
                const int ny = clampi(sb1 + oj);
                const int nz = clampi(sb2 + ok);
                const float dpx = ((float)oi - fx0) * DXc;
                const float dpy = ((float)oj - fx1) * DXc;
                const float dpz = ((float)ok - fx2) * DXc;
                const float w = WA[oi] * WB[oj] * WC[ok];
                float* gp = reinterpret_cast<float*>(gS4 + (nx * G + ny) * G + nz);
                unsafeAtomicAdd(gp + 0, w * (mvx + A00 * dpx + A01 * dpy + A02 * dpz));
                unsafeAtomicAdd(gp + 1, w * (mvy + A10 * dpx + A11 * dpy + A12 * dpz));
                unsafeAtomicAdd(gp + 2, w * (mvz + A20 * dpx + A21 * dpy + A22 * dpz));
                unsafeAtomicAdd(gp + 3, w * P_MASS);
            }
        }

        // ======== zero substep p-2's per-wg bbox in buf[(p+1)%3] ========
        if (zvalid) {
            const int zD1 = zmx1 - zmn1 + 1, zD2 = zmx2 - zmn2 + 1;
            const int zvol = (zmx0 - zmn0 + 1) * zD1 * zD2;
            const float4 z = make_float4(0.f, 0.f, 0.f, 0.f);
            for (int c = threadIdx.x; c < zvol; c += NTHR) {
                const int k = c % zD2;
                const int t = c / zD2;
                const int j = t % zD1;
                const int i = t / zD1;
                gZ4[((zmn0 + i) * G + (zmn1 + j)) * G + (zmn2 + k)] = z;
            }
        }
        // shift bbox history
        zmn0 = pmn0; zmn1 = pmn1; zmn2 = pmn2;
        zmx0 = pmx0; zmx1 = pmx1; zmx2 = pmx2; zvalid = pvalid;
        pmn0 = mn0; pmn1 = mn1; pmn2 = mn2;
        pmx0 = mx0; pmx1 = mx1; pmx2 = mx2; pvalid = anyAct;

        gg.sync();
    }

    // ---- final frame output: grid_m of substep 599 ----
    {
        const float4* gL4 = g4 + ((NSUB - 1) % 3) * G3;
        float* o = out + (NSUB / SPF - 1) * G3;
        for (int i = tid; i < G3; i += nth) o[i] = gL4[i].w + vs;
    }
}

extern "C" void kernel_launch(void* const* d_in, const int* in_sizes, int n_in,
                              void* d_out, int out_size, void* d_ws, size_t ws_size,
                              hipStream_t stream) {
    const float* v  = (const float*)d_in[0];
    const float* q  = (const float*)d_in[1];
    const float* qd = (const float*)d_in[2];
    float* out = (float*)d_out;
    float* ws  = (float*)d_ws;
    void* args[] = { (void*)&v, (void*)&q, (void*)&qd, (void*)&out, (void*)&ws };
    hipLaunchCooperativeKernel(reinterpret_cast<void*>(mpm_sim),
                               dim3(NBLK), dim3(NTHR), args, 0, stream);
}

// Round 5
// 20719.589 us; speedup vs baseline: 3.9984x; 1.1635x over previous
//
#include <hip/hip_runtime.h>
#include <hip/hip_cooperative_groups.h>

namespace cg = cooperative_groups;

static constexpr int G    = 100;
static constexpr int G3   = G * G * G;
static constexpr int NP   = 13500;   // 30*15*30 particles
static constexpr int NSUB = 600;     // 20 frames x 30 substeps
static constexpr int SPF  = 30;      // substeps per frame
static constexpr int R    = 8;       // lanes per particle
static constexpr int NTHR = 1024;
static constexpr int NBLK = 108;     // 6x3x6 bricks of 5x5x5 particles
static constexpr int TC   = 4000;    // LDS tile capacity in cells (float4 each = 64000 B)

__device__ __forceinline__ int clampi(int v) {
    return v < 0 ? 0 : (v > G - 1 ? G - 1 : v);
}

// Hand-rolled grid barrier: monotonic counter, target = gen*NBLK.
// __syncthreads() drains each wave's vmcnt (compiler emits full s_waitcnt before
// s_barrier), so all block stores/atomics are in L2/MALL; thread 0's release
// fence writes back its XCD's L2 (covers the whole block: one block = one CU =
// one XCD), the acquire fence invalidates L1/L2 before any post-barrier load.
__device__ __forceinline__ void gridbar(unsigned* __restrict__ cnt, unsigned gen) {
    __syncthreads();
    if (threadIdx.x == 0) {
        __threadfence();   // release
        __hip_atomic_fetch_add(cnt, 1u, __ATOMIC_RELAXED, __HIP_MEMORY_SCOPE_AGENT);
        const unsigned target = gen * (unsigned)NBLK;
        while (__hip_atomic_load(cnt, __ATOMIC_RELAXED, __HIP_MEMORY_SCOPE_AGENT) < target) {
            __builtin_amdgcn_s_sleep(1);
        }
        __threadfence();   // acquire
    }
    __syncthreads();
}

// Persistent cooperative kernel. Triple-buffered float4 grid in ws:
//   g4[buf*G3 + idx] = (mom.x, mom.y, mom.z, mass)
// Phase p: zero substep p-2's per-wg bbox in buf[(p+1)%3] (hoisted: overlaps the
// gather's MALL round trip), gather substep p-1 from buf[(p-1)%3], scatter
// substep p into buf[p%3] via per-wg LDS tile. One hand-rolled grid barrier per
// phase. Particles statically grouped into 5x5x5 spatial bricks (one per wg);
// each particle handled by an 8-lane group with shfl-butterfly reduction.
__launch_bounds__(NTHR)
__global__ void mpm_sim(const float* __restrict__ vscal,
                        const float* __restrict__ q0,
                        const float* __restrict__ qd0,
                        float* __restrict__ out,
                        float* __restrict__ ws,
                        unsigned* __restrict__ barcnt)
{
    const float vs = vscal[0];
    float4* const g4 = reinterpret_cast<float4*>(ws);

    cg::grid_group gg = cg::this_grid();
    const int tid = blockIdx.x * NTHR + threadIdx.x;
    const int nth = NBLK * NTHR;

    // brick/slot -> original particle index
    const int slot = threadIdx.x >> 3;        // 0..127
    const int sub  = threadIdx.x & 7;         // lane within particle group
    const bool act = slot < 125;
    int pid = 0;
    if (act) {
        const int b  = blockIdx.x;            // (bx*3+by)*6+bz
        const int bx = b / 18;
        const int by = (b / 6) % 3;
        const int bz = b % 6;
        const int lx = slot / 25;
        const int rem = slot % 25;
        const int ly = rem / 5;
        const int lz = rem % 5;
        const int ix = bx * 5 + lx;
        const int iy = by * 5 + ly;
        const int iz = bz * 5 + lz;
        pid = (ix * 15 + iy) * 30 + iz;
    }

    const float DT      = 5e-4f;
    const float INV_DX  = 100.0f;
    const float DXc     = 0.01f;
    const float MU      = (float)(1.0e5 / (2.0 * (1.0 + 0.3)));
    const float LAM     = (float)(1.0e5 * 0.3 / ((1.0 + 0.3) * (1.0 - 0.6)));
    const float P_MASS  = (float)(0.005 * 0.005 * 0.005 * 3000.0);
    const float KS      = (float)(-5.0e-4 * (0.005 * 0.005 * 0.005) * 4.0 * 100.0 * 100.0);
    const float DTG     = (float)(5.0e-4 * (-9.8));
    const float CSC     = 4.0f * INV_DX * INV_DX;   // 40000

    __shared__ float tile[4 * TC];   // AoS per cell: [mx,my,mz,mass]
    __shared__ int sred[6];          // bbox reduction

    // ---- init: zero all 3 grid buffers + barrier counter (ws poisoned 0xAA) ----
    {
        const float4 z = make_float4(0.f, 0.f, 0.f, 0.f);
        for (int i = tid; i < 3 * G3; i += nth) g4[i] = z;
        if (tid == 0)
            __hip_atomic_store(barcnt, 0u, __ATOMIC_RELAXED, __HIP_MEMORY_SCOPE_AGENT);
    }

    // ---- particle state, replicated across the 8 lanes of a group ----
    float px = 0.f, py = 0.f, pz = 0.f, vx = 0.f, vy = 0.f, vz = 0.f;
    float C00 = 0.f, C01 = 0.f, C02 = 0.f,
          C10 = 0.f, C11 = 0.f, C12 = 0.f,
          C20 = 0.f, C21 = 0.f, C22 = 0.f;
    float F00 = 1.f, F01 = 0.f, F02 = 0.f,
          F10 = 0.f, F11 = 1.f, F12 = 0.f,
          F20 = 0.f, F21 = 0.f, F22 = 1.f;
    if (act) {
        px = q0[3 * pid + 0]; py = q0[3 * pid + 1]; pz = q0[3 * pid + 2];
        vx = qd0[3 * pid + 0]; vy = qd0[3 * pid + 1]; vz = qd0[3 * pid + 2];
    }

    // per-wg bbox history (uniform across wg): p-1 and p-2 scatter bboxes
    int pmn0 = 0, pmn1 = 0, pmn2 = 0, pmx0 = -1, pmx1 = -1, pmx2 = -1; bool pvalid = false;
    int zmn0 = 0, zmn1 = 0, zmn2 = 0, zmx0 = -1, zmx1 = -1, zmx2 = -1; bool zvalid = false;

    gg.sync();   // one cooperative sync to publish init (incl. zeroed barcnt)

    unsigned gen = 0;

    for (int p = 0; p < NSUB; ++p) {
        const int bS = p % 3;
        const int bG = (p + 2) % 3;   // (p-1)%3 for p>0
        const int bZ = (p + 1) % 3;   // holds substep p-2 data
        float4*       __restrict__ gS4 = g4 + bS * G3;
        const float4* __restrict__ gG4 = g4 + bG * G3;
        float4*       __restrict__ gZ4 = g4 + bZ * G3;

        // ======== zero substep p-2's per-wg bbox in buf[(p+1)%3] (hoisted) ========
        if (zvalid) {
            const int zD1 = zmx1 - zmn1 + 1, zD2 = zmx2 - zmn2 + 1;
            const int zvol = (zmx0 - zmn0 + 1) * zD1 * zD2;
            const float4 z = make_float4(0.f, 0.f, 0.f, 0.f);
            for (int c = threadIdx.x; c < zvol; c += NTHR) {
                const int k = c % zD2;
                const int t = c / zD2;
                const int j = t % zD1;
                const int i = t / zD1;
                gZ4[((zmn0 + i) * G + (zmn1 + j)) * G + (zmn2 + k)] = z;
            }
        }

        // frame output: grid_m of substep p-1
        if (p > 0 && ((p - 1) % SPF) == SPF - 1) {
            float* o = out + ((p - 1) / SPF) * G3;
            for (int i = tid; i < G3; i += nth) o[i] = gG4[i].w + vs;
        }

        int sb0 = 0, sb1 = 0, sb2 = 0;
        float fx0 = 0.f, fx1 = 0.f, fx2 = 0.f;
        float A00 = 0.f, A01 = 0.f, A02 = 0.f,
              A10 = 0.f, A11 = 0.f, A12 = 0.f,
              A20 = 0.f, A21 = 0.f, A22 = 0.f;
        float mvx = 0.f, mvy = 0.f, mvz = 0.f;

        if (act) {
            // ======== G2P gather for substep p-1 (cells c%8==sub per lane) ========
            if (p > 0) {
                const float xs0 = px * INV_DX, xs1 = py * INV_DX, xs2 = pz * INV_DX;
                const float fb0 = floorf(xs0 - 0.5f), fb1 = floorf(xs1 - 0.5f), fb2 = floorf(xs2 - 0.5f);
                const int b0 = (int)fb0, b1 = (int)fb1, b2 = (int)fb2;
                const float gx0 = xs0 - fb0, gx1 = xs1 - fb1, gx2 = xs2 - fb2;
                float wa[3], wb[3], wc[3];
                wa[0] = 0.5f * (1.5f - gx0) * (1.5f - gx0);
                wa[1] = 0.75f - (gx0 - 1.0f) * (gx0 - 1.0f);
                wa[2] = 0.5f * (gx0 - 0.5f) * (gx0 - 0.5f);
                wb[0] = 0.5f * (1.5f - gx1) * (1.5f - gx1);
                wb[1] = 0.75f - (gx1 - 1.0f) * (gx1 - 1.0f);
                wb[2] = 0.5f * (gx1 - 0.5f) * (gx1 - 0.5f);
                wc[0] = 0.5f * (1.5f - gx2) * (1.5f - gx2);
                wc[1] = 0.75f - (gx2 - 1.0f) * (gx2 - 1.0f);
                wc[2] = 0.5f * (gx2 - 0.5f) * (gx2 - 0.5f);

                float nvx = 0.f, nvy = 0.f, nvz = 0.f;
                float nc00 = 0.f, nc01 = 0.f, nc02 = 0.f,
                      nc10 = 0.f, nc11 = 0.f, nc12 = 0.f,
                      nc20 = 0.f, nc21 = 0.f, nc22 = 0.f;
                #pragma unroll
                for (int t = 0; t < 4; ++t) {
                    const int c = sub + 8 * t;
                    if (c >= 27) break;
                    const int oi = c / 9;
                    const int rem = c - 9 * oi;
                    const int oj = rem / 3;
                    const int ok = rem - 3 * oj;
                    const int nx = clampi(b0 + oi);
                    const int ny = clampi(b1 + oj);
                    const int nz = clampi(b2 + ok);
                    const float dpx = ((float)oi - gx0) * DXc;
                    const float dpy = ((float)oj - gx1) * DXc;
                    const float dpz = ((float)ok - gx2) * DXc;
                    const float w = wa[oi] * wb[oj] * wc[ok];
                    const float4 gq = gG4[(nx * G + ny) * G + nz];
                    const float den = gq.w + vs;
                    float gvx = gq.x / den;
                    float gvy = gq.y / den;
                    float gvz = gq.z / den;
                    if (nx < 3       && gvx < 0.f) gvx = 0.f;
                    if (nx >= G - 3  && gvx > 0.f) gvx = 0.f;
                    if (ny < 3       && gvy < 0.f) gvy = 0.f;
                    if (ny >= G - 3  && gvy > 0.f) gvy = 0.f;
                    if (nz < 3       && gvz < 0.f) gvz = 0.f;
                    if (nz >= G - 3  && gvz > 0.f) gvz = 0.f;
                    nvx += w * gvx; nvy += w * gvy; nvz += w * gvz;
                    const float wgx = w * gvx, wgy = w * gvy, wgz = w * gvz;
                    nc00 += wgx * dpx; nc01 += wgx * dpy; nc02 += wgx * dpz;
                    nc10 += wgy * dpx; nc11 += wgy * dpy; nc12 += wgy * dpz;
                    nc20 += wgz * dpx; nc21 += wgz * dpy; nc22 += wgz * dpz;
                }
                // 8-lane butterfly: all lanes end with identical full sums
                #define BFLY(v) { v += __shfl_xor(v, 1); v += __shfl_xor(v, 2); v += __shfl_xor(v, 4); }
                BFLY(nvx) BFLY(nvy) BFLY(nvz)
                BFLY(nc00) BFLY(nc01) BFLY(nc02)
                BFLY(nc10) BFLY(nc11) BFLY(nc12)
                BFLY(nc20) BFLY(nc21) BFLY(nc22)
                #undef BFLY
                vx = nvx; vy = nvy; vz = nvz;
                C00 = CSC * nc00; C01 = CSC * nc01; C02 = CSC * nc02;
                C10 = CSC * nc10; C11 = CSC * nc11; C12 = CSC * nc12;
                C20 = CSC * nc20; C21 = CSC * nc21; C22 = CSC * nc22;
                px += DT * vx; py += DT * vy; pz += DT * vz;
            }

            // ======== F update: F = (I + DT*C) @ F (replicated) ========
            {
                const float t00 = F00 + DT * (C00 * F00 + C01 * F10 + C02 * F20);
                const float t01 = F01 + DT * (C00 * F01 + C01 * F11 + C02 * F21);
                const float t02 = F02 + DT * (C00 * F02 + C01 * F12 + C02 * F22);
                const float t10 = F10 + DT * (C10 * F00 + C11 * F10 + C12 * F20);
                const float t11 = F11 + DT * (C10 * F01 + C11 * F11 + C12 * F21);
                const float t12 = F12 + DT * (C10 * F02 + C11 * F12 + C12 * F22);
                const float t20 = F20 + DT * (C20 * F00 + C21 * F10 + C22 * F20);
                const float t21 = F21 + DT * (C20 * F01 + C21 * F11 + C22 * F21);
                const float t22 = F22 + DT * (C20 * F02 + C21 * F12 + C22 * F22);
                F00 = t00; F01 = t01; F02 = t02;
                F10 = t10; F11 = t11; F12 = t12;
                F20 = t20; F21 = t21; F22 = t22;
            }

            // ======== neo-Hookean PK1 stress -> affine (replicated) ========
            const float c00 = F11 * F22 - F12 * F21;
            const float c01 = F12 * F20 - F10 * F22;
            const float c02 = F10 * F21 - F11 * F20;
            const float det = F00 * c00 + F01 * c01 + F02 * c02;
            const float c10 = F02 * F21 - F01 * F22;
            const float c11 = F00 * F22 - F02 * F20;
            const float c12 = F01 * F20 - F00 * F21;
            const float c20 = F01 * F12 - F02 * F11;
            const float c21 = F02 * F10 - F00 * F12;
            const float c22 = F00 * F11 - F01 * F10;
            const float idet = 1.0f / det;
            const float lj = LAM * logf(fmaxf(det, 1e-6f));
            const float fit00 = c00 * idet, fit01 = c01 * idet, fit02 = c02 * idet;
            const float fit10 = c10 * idet, fit11 = c11 * idet, fit12 = c12 * idet;
            const float fit20 = c20 * idet, fit21 = c21 * idet, fit22 = c22 * idet;
            const float P00 = MU * (F00 - fit00) + lj * fit00;
            const float P01 = MU * (F01 - fit01) + lj * fit01;
            const float P02 = MU * (F02 - fit02) + lj * fit02;
            const float P10 = MU * (F10 - fit10) + lj * fit10;
            const float P11 = MU * (F11 - fit11) + lj * fit11;
            const float P12 = MU * (F12 - fit12) + lj * fit12;
            const float P20 = MU * (F20 - fit20) + lj * fit20;
            const float P21 = MU * (F21 - fit21) + lj * fit21;
            const float P22 = MU * (F22 - fit22) + lj * fit22;
            A00 = KS * (P00 * F00 + P01 * F01 + P02 * F02) + P_MASS * C00;
            A01 = KS * (P00 * F10 + P01 * F11 + P02 * F12) + P_MASS * C01;
            A02 = KS * (P00 * F20 + P01 * F21 + P02 * F22) + P_MASS * C02;
            A10 = KS * (P10 * F00 + P11 * F01 + P12 * F02) + P_MASS * C10;
            A11 = KS * (P10 * F10 + P11 * F11 + P12 * F12) + P_MASS * C11;
            A12 = KS * (P10 * F20 + P11 * F21 + P12 * F22) + P_MASS * C12;
            A20 = KS * (P20 * F00 + P21 * F01 + P22 * F02) + P_MASS * C20;
            A21 = KS * (P20 * F10 + P21 * F11 + P22 * F12) + P_MASS * C21;
            A22 = KS * (P20 * F20 + P21 * F21 + P22 * F22) + P_MASS * C22;

            // scatter base (from updated x)
            const float xs0 = px * INV_DX, xs1 = py * INV_DX, xs2 = pz * INV_DX;
            const float fb0 = floorf(xs0 - 0.5f), fb1 = floorf(xs1 - 0.5f), fb2 = floorf(xs2 - 0.5f);
            sb0 = (int)fb0; sb1 = (int)fb1; sb2 = (int)fb2;
            fx0 = xs0 - fb0; fx1 = xs1 - fb1; fx2 = xs2 - fb2;
            mvx = P_MASS * vx;
            mvy = P_MASS * (vy + DTG);
            mvz = P_MASS * vz;
        }

        // ======== per-wg clamped scatter bbox reduction ========
        if (threadIdx.x == 0) {
            sred[0] = INT_MAX; sred[1] = INT_MAX; sred[2] = INT_MAX;
            sred[3] = INT_MIN; sred[4] = INT_MIN; sred[5] = INT_MIN;
        }
        __syncthreads();
        if (act && sub == 0) {
            atomicMin(&sred[0], clampi(sb0)); atomicMax(&sred[3], clampi(sb0 + 2));
            atomicMin(&sred[1], clampi(sb1)); atomicMax(&sred[4], clampi(sb1 + 2));
            atomicMin(&sred[2], clampi(sb2)); atomicMax(&sred[5], clampi(sb2 + 2));
        }
        __syncthreads();
        const int mn0 = sred[0], mn1 = sred[1], mn2 = sred[2];
        const int mx0 = sred[3], mx1 = sred[4], mx2 = sred[5];
        const bool anyAct = (mx0 >= mn0);
        const int D1 = mx1 - mn1 + 1, D2 = mx2 - mn2 + 1;
        const int vol = anyAct ? (mx0 - mn0 + 1) * D1 * D2 : 0;
        const bool useLDS = anyAct && (vol <= TC);
        __syncthreads();   // tile reuse guard

        // weights for scatter (replicated per lane group)
        float wa0 = 0.f, wa1 = 0.f, wa2 = 0.f, wb0 = 0.f, wb1 = 0.f, wb2 = 0.f,
              wcc0 = 0.f, wcc1 = 0.f, wcc2 = 0.f;
        if (act) {
            wa0 = 0.5f * (1.5f - fx0) * (1.5f - fx0);
            wa1 = 0.75f - (fx0 - 1.0f) * (fx0 - 1.0f);
            wa2 = 0.5f * (fx0 - 0.5f) * (fx0 - 0.5f);
            wb0 = 0.5f * (1.5f - fx1) * (1.5f - fx1);
            wb1 = 0.75f - (fx1 - 1.0f) * (fx1 - 1.0f);
            wb2 = 0.5f * (fx1 - 0.5f) * (fx1 - 0.5f);
            wcc0 = 0.5f * (1.5f - fx2) * (1.5f - fx2);
            wcc1 = 0.75f - (fx2 - 1.0f) * (fx2 - 1.0f);
            wcc2 = 0.5f * (fx2 - 0.5f) * (fx2 - 0.5f);
        }
        const float WA[3] = { wa0, wa1, wa2 };
        const float WB[3] = { wb0, wb1, wb2 };
        const float WC[3] = { wcc0, wcc1, wcc2 };

        if (useLDS) {
            // zero tile portion (float4 stores)
            float4* t4 = reinterpret_cast<float4*>(tile);
            const float4 z = make_float4(0.f, 0.f, 0.f, 0.f);
            for (int i = threadIdx.x; i < vol; i += NTHR) t4[i] = z;
            __syncthreads();
            if (act) {
                #pragma unroll
                for (int t = 0; t < 4; ++t) {
                    const int c = sub + 8 * t;
                    if (c >= 27) break;
                    const int oi = c / 9;
                    const int rem = c - 9 * oi;
                    const int oj = rem / 3;
                    const int ok = rem - 3 * oj;
                    const int li  = clampi(sb0 + oi) - mn0;
                    const int lj2 = clampi(sb1 + oj) - mn1;
                    const int lk  = clampi(sb2 + ok) - mn2;
                    const float dpx = ((float)oi - fx0) * DXc;
                    const float dpy = ((float)oj - fx1) * DXc;
                    const float dpz = ((float)ok - fx2) * DXc;
                    const float w = WA[oi] * WB[oj] * WC[ok];
                    const int c4 = 4 * ((li * D1 + lj2) * D2 + lk);
                    atomicAdd(&tile[c4 + 0], w * (mvx + A00 * dpx + A01 * dpy + A02 * dpz));
                    atomicAdd(&tile[c4 + 1], w * (mvy + A10 * dpx + A11 * dpy + A12 * dpz));
                    atomicAdd(&tile[c4 + 2], w * (mvz + A20 * dpx + A21 * dpy + A22 * dpz));
                    atomicAdd(&tile[c4 + 3], w * P_MASS);
                }
            }
            __syncthreads();
            // flush tile -> global (device-scope atomics), skip empty cells
            for (int c = threadIdx.x; c < vol; c += NTHR) {
                const float m = tile[4 * c + 3];
                if (m != 0.f) {
                    const int k = c % D2;
                    const int t = c / D2;
                    const int j = t % D1;
                    const int i = t / D1;
                    const int gidx = ((mn0 + i) * G + (mn1 + j)) * G + (mn2 + k);
                    float* gp = reinterpret_cast<float*>(gS4 + gidx);
                    unsafeAtomicAdd(gp + 0, tile[4 * c + 0]);
                    unsafeAtomicAdd(gp + 1, tile[4 * c + 1]);
                    unsafeAtomicAdd(gp + 2, tile[4 * c + 2]);
                    unsafeAtomicAdd(gp + 3, m);
                }
            }
        } else if (anyAct && act) {
            // fallback: direct global atomics (bbox too large)
            #pragma unroll
            for (int t = 0; t < 4; ++t) {
                const int c = sub + 8 * t;
                if (c >= 27) break;
                const int oi = c / 9;
                const int rem = c - 9 * oi;
                const int oj = rem / 3;
                const int ok = rem - 3 * oj;
                const int nx = clampi(sb0 + oi);
                const int ny = clampi(sb1 + oj);
                const int nz = clampi(sb2 + ok);
                const float dpx = ((float)oi - fx0) * DXc;
                const float dpy = ((float)oj - fx1) * DXc;
                const float dpz = ((float)ok - fx2) * DXc;
                const float w = WA[oi] * WB[oj] * WC[ok];
                float* gp = reinterpret_cast<float*>(gS4 + (nx * G + ny) * G + nz);
                unsafeAtomicAdd(gp + 0, w * (mvx + A00 * dpx + A01 * dpy + A02 * dpz));
                unsafeAtomicAdd(gp + 1, w * (mvy + A10 * dpx + A11 * dpy + A12 * dpz));
                unsafeAtomicAdd(gp + 2, w * (mvz + A20 * dpx + A21 * dpy + A22 * dpz));
                unsafeAtomicAdd(gp + 3, w * P_MASS);
            }
        }

        // shift bbox history
        zmn0 = pmn0; zmn1 = pmn1; zmn2 = pmn2;
        zmx0 = pmx0; zmx1 = pmx1; zmx2 = pmx2; zvalid = pvalid;
        pmn0 = mn0; pmn1 = mn1; pmn2 = mn2;
        pmx0 = mx0; pmx1 = mx1; pmx2 = mx2; pvalid = anyAct;

        gridbar(barcnt, ++gen);
    }

    // ---- final frame output: grid_m of substep 599 ----
    {
        const float4* gL4 = g4 + ((NSUB - 1) % 3) * G3;
        float* o = out + (NSUB / SPF - 1) * G3;
        for (int i = tid; i < G3; i += nth) o[i] = gL4[i].w + vs;
    }
}

extern "C" void kernel_launch(void* const* d_in, const int* in_sizes, int n_in,
                              void* d_out, int out_size, void* d_ws, size_t ws_size,
                              hipStream_t stream) {
    const float* v  = (const float*)d_in[0];
    const float* q  = (const float*)d_in[1];
    const float* qd = (const float*)d_in[2];
    float* out = (float*)d_out;
    float* ws  = (float*)d_ws;
    // barrier counter at the tail of the workspace (grid buffers use the head)
    unsigned* barcnt = reinterpret_cast<unsigned*>((char*)d_ws + (ws_size & ~(size_t)15) - 16);
    void* args[] = { (void*)&v, (void*)&q, (void*)&qd, (void*)&out, (void*)&ws, (void*)&barcnt };
    hipLaunchCooperativeKernel(reinterpret_cast<void*>(mpm_sim),
                               dim3(NBLK), dim3(NTHR), args, 0, stream);
}

// Round 6
// 19673.860 us; speedup vs baseline: 4.2110x; 1.0532x over previous
//
#include <hip/hip_runtime.h>
#include <hip/hip_cooperative_groups.h>

namespace cg = cooperative_groups;

static constexpr int G    = 100;
static constexpr int G3   = G * G * G;
static constexpr int NP   = 13500;   // 30*15*30 particles
static constexpr int NSUB = 600;     // 20 frames x 30 substeps
static constexpr int SPF  = 30;      // substeps per frame
static constexpr int R    = 8;       // lanes per particle
static constexpr int NTHR = 1024;
static constexpr int NBLK = 108;     // 6x3x6 bricks of 5x5x5 particles
static constexpr int TC   = 4000;    // LDS tile capacity in cells (float4 each = 64000 B)

__device__ __forceinline__ int clampi(int v) {
    return v < 0 ? 0 : (v > G - 1 ? G - 1 : v);
}

// MALL-coherent (agent-scope, relaxed) 16B cell load/store helpers.
// These emit cache-bypassing loads/stores (coherent at the die-level MALL), so
// inter-block visibility needs NO cache writeback/invalidate fences anywhere.
__device__ __forceinline__ float4 cell_load(const float4* p) {
    const unsigned long long* q = reinterpret_cast<const unsigned long long*>(p);
    unsigned long long a = __hip_atomic_load(&q[0], __ATOMIC_RELAXED, __HIP_MEMORY_SCOPE_AGENT);
    unsigned long long b = __hip_atomic_load(&q[1], __ATOMIC_RELAXED, __HIP_MEMORY_SCOPE_AGENT);
    float4 r;
    r.x = __uint_as_float((unsigned)(a & 0xffffffffu));
    r.y = __uint_as_float((unsigned)(a >> 32));
    r.z = __uint_as_float((unsigned)(b & 0xffffffffu));
    r.w = __uint_as_float((unsigned)(b >> 32));
    return r;
}
__device__ __forceinline__ void cell_zero(float4* p) {
    unsigned long long* q = reinterpret_cast<unsigned long long*>(p);
    __hip_atomic_store(&q[0], 0ull, __ATOMIC_RELAXED, __HIP_MEMORY_SCOPE_AGENT);
    __hip_atomic_store(&q[1], 0ull, __ATOMIC_RELAXED, __HIP_MEMORY_SCOPE_AGENT);
}
__device__ __forceinline__ float cell_load_w(const float4* p) {
    const unsigned* q = reinterpret_cast<const unsigned*>(p);
    unsigned w = __hip_atomic_load(&q[3], __ATOMIC_RELAXED, __HIP_MEMORY_SCOPE_AGENT);
    return __uint_as_float(w);
}

// Fence-free grid barrier (monotonic counter, target = gen*NBLK).
// Sound because ALL inter-block grid traffic is MALL-coherent (see above):
// __syncthreads() makes the compiler drain vmcnt before s_barrier, so every
// MALL-bound op of this block is complete (acked at the single coherence point)
// before thread 0 issues the arrive-add; a waiter's post-spin accesses are
// issued strictly later in time and hit the same coherence point. No
// buffer_wbl2 / buffer_inv (the per-phase fixed cost this round removes).
__device__ __forceinline__ void gridbar(unsigned* __restrict__ cnt, unsigned gen) {
    __syncthreads();
    if (threadIdx.x == 0) {
        __hip_atomic_fetch_add(cnt, 1u, __ATOMIC_RELAXED, __HIP_MEMORY_SCOPE_AGENT);
        const unsigned target = gen * (unsigned)NBLK;
        while (__hip_atomic_load(cnt, __ATOMIC_RELAXED, __HIP_MEMORY_SCOPE_AGENT) < target) {
            __builtin_amdgcn_s_sleep(1);
        }
    }
    __syncthreads();
}

// Persistent cooperative kernel. Triple-buffered float4 grid in ws:
//   g4[buf*G3 + idx] = (mom.x, mom.y, mom.z, mass)
// Phase p: zero substep p-2's per-wg bbox in buf[(p+1)%3] (hoisted), gather
// substep p-1 from buf[(p-1)%3], scatter substep p into buf[p%3] via per-wg
// LDS tile. One fence-free grid barrier per phase. Particles statically
// grouped into 5x5x5 spatial bricks (one per wg); each particle handled by an
// 8-lane group with shfl-butterfly reduction.
__launch_bounds__(NTHR)
__global__ void mpm_sim(const float* __restrict__ vscal,
                        const float* __restrict__ q0,
                        const float* __restrict__ qd0,
                        float* __restrict__ out,
                        float* __restrict__ ws,
                        unsigned* __restrict__ barcnt)
{
    const float vs = vscal[0];
    float4* const g4 = reinterpret_cast<float4*>(ws);

    cg::grid_group gg = cg::this_grid();
    const int tid = blockIdx.x * NTHR + threadIdx.x;
    const int nth = NBLK * NTHR;

    // brick/slot -> original particle index
    const int slot = threadIdx.x >> 3;        // 0..127
    const int sub  = threadIdx.x & 7;         // lane within particle group
    const bool act = slot < 125;
    int pid = 0;
    if (act) {
        const int b  = blockIdx.x;            // (bx*3+by)*6+bz
        const int bx = b / 18;
        const int by = (b / 6) % 3;
        const int bz = b % 6;
        const int lx = slot / 25;
        const int rem = slot % 25;
        const int ly = rem / 5;
        const int lz = rem % 5;
        const int ix = bx * 5 + lx;
        const int iy = by * 5 + ly;
        const int iz = bz * 5 + lz;
        pid = (ix * 15 + iy) * 30 + iz;
    }

    const float DT      = 5e-4f;
    const float INV_DX  = 100.0f;
    const float DXc     = 0.01f;
    const float MU      = (float)(1.0e5 / (2.0 * (1.0 + 0.3)));
    const float LAM     = (float)(1.0e5 * 0.3 / ((1.0 + 0.3) * (1.0 - 0.6)));
    const float P_MASS  = (float)(0.005 * 0.005 * 0.005 * 3000.0);
    const float KS      = (float)(-5.0e-4 * (0.005 * 0.005 * 0.005) * 4.0 * 100.0 * 100.0);
    const float DTG     = (float)(5.0e-4 * (-9.8));
    const float CSC     = 4.0f * INV_DX * INV_DX;   // 40000

    __shared__ float tile[4 * TC];   // AoS per cell: [mx,my,mz,mass]
    __shared__ int sred[6];          // bbox reduction

    // ---- init: zero all 3 grid buffers + barrier counter (ws poisoned 0xAA) ----
    {
        const float4 z = make_float4(0.f, 0.f, 0.f, 0.f);
        for (int i = tid; i < 3 * G3; i += nth) g4[i] = z;
        if (tid == 0)
            __hip_atomic_store(barcnt, 0u, __ATOMIC_RELAXED, __HIP_MEMORY_SCOPE_AGENT);
    }

    // ---- particle state, replicated across the 8 lanes of a group ----
    float px = 0.f, py = 0.f, pz = 0.f, vx = 0.f, vy = 0.f, vz = 0.f;
    float C00 = 0.f, C01 = 0.f, C02 = 0.f,
          C10 = 0.f, C11 = 0.f, C12 = 0.f,
          C20 = 0.f, C21 = 0.f, C22 = 0.f;
    float F00 = 1.f, F01 = 0.f, F02 = 0.f,
          F10 = 0.f, F11 = 1.f, F12 = 0.f,
          F20 = 0.f, F21 = 0.f, F22 = 1.f;
    if (act) {
        px = q0[3 * pid + 0]; py = q0[3 * pid + 1]; pz = q0[3 * pid + 2];
        vx = qd0[3 * pid + 0]; vy = qd0[3 * pid + 1]; vz = qd0[3 * pid + 2];
    }

    // per-wg bbox history (uniform across wg): p-1 and p-2 scatter bboxes
    int pmn0 = 0, pmn1 = 0, pmn2 = 0, pmx0 = -1, pmx1 = -1, pmx2 = -1; bool pvalid = false;
    int zmn0 = 0, zmn1 = 0, zmn2 = 0, zmx0 = -1, zmx1 = -1, zmx2 = -1; bool zvalid = false;

    gg.sync();   // one cooperative sync to publish init (incl. zeroed barcnt)

    unsigned gen = 0;

    for (int p = 0; p < NSUB; ++p) {
        const int bS = p % 3;
        const int bG = (p + 2) % 3;   // (p-1)%3 for p>0
        const int bZ = (p + 1) % 3;   // holds substep p-2 data
        float4*       __restrict__ gS4 = g4 + bS * G3;
        const float4* __restrict__ gG4 = g4 + bG * G3;
        float4*       __restrict__ gZ4 = g4 + bZ * G3;

        // ======== zero substep p-2's per-wg bbox in buf[(p+1)%3] (hoisted) ========
        if (zvalid) {
            const int zD1 = zmx1 - zmn1 + 1, zD2 = zmx2 - zmn2 + 1;
            const int zvol = (zmx0 - zmn0 + 1) * zD1 * zD2;
            for (int c = threadIdx.x; c < zvol; c += NTHR) {
                const int k = c % zD2;
                const int t = c / zD2;
                const int j = t % zD1;
                const int i = t / zD1;
                cell_zero(&gZ4[((zmn0 + i) * G + (zmn1 + j)) * G + (zmn2 + k)]);
            }
        }

        // frame output: grid_m of substep p-1
        if (p > 0 && ((p - 1) % SPF) == SPF - 1) {
            float* o = out + ((p - 1) / SPF) * G3;
            for (int i = tid; i < G3; i += nth) o[i] = cell_load_w(&gG4[i]) + vs;
        }

        int sb0 = 0, sb1 = 0, sb2 = 0;
        float fx0 = 0.f, fx1 = 0.f, fx2 = 0.f;
        float A00 = 0.f, A01 = 0.f, A02 = 0.f,
              A10 = 0.f, A11 = 0.f, A12 = 0.f,
              A20 = 0.f, A21 = 0.f, A22 = 0.f;
        float mvx = 0.f, mvy = 0.f, mvz = 0.f;

        if (act) {
            // ======== G2P gather for substep p-1 (cells c%8==sub per lane) ========
            if (p > 0) {
                const float xs0 = px * INV_DX, xs1 = py * INV_DX, xs2 = pz * INV_DX;
                const float fb0 = floorf(xs0 - 0.5f), fb1 = floorf(xs1 - 0.5f), fb2 = floorf(xs2 - 0.5f);
                const int b0 = (int)fb0, b1 = (int)fb1, b2 = (int)fb2;
                const float gx0 = xs0 - fb0, gx1 = xs1 - fb1, gx2 = xs2 - fb2;
                float wa[3], wb[3], wc[3];
                wa[0] = 0.5f * (1.5f - gx0) * (1.5f - gx0);
                wa[1] = 0.75f - (gx0 - 1.0f) * (gx0 - 1.0f);
                wa[2] = 0.5f * (gx0 - 0.5f) * (gx0 - 0.5f);
                wb[0] = 0.5f * (1.5f - gx1) * (1.5f - gx1);
                wb[1] = 0.75f - (gx1 - 1.0f) * (gx1 - 1.0f);
                wb[2] = 0.5f * (gx1 - 0.5f) * (gx1 - 0.5f);
                wc[0] = 0.5f * (1.5f - gx2) * (1.5f - gx2);
                wc[1] = 0.75f - (gx2 - 1.0f) * (gx2 - 1.0f);
                wc[2] = 0.5f * (gx2 - 0.5f) * (gx2 - 0.5f);

                float nvx = 0.f, nvy = 0.f, nvz = 0.f;
                float nc00 = 0.f, nc01 = 0.f, nc02 = 0.f,
                      nc10 = 0.f, nc11 = 0.f, nc12 = 0.f,
                      nc20 = 0.f, nc21 = 0.f, nc22 = 0.f;
                #pragma unroll
                for (int t = 0; t < 4; ++t) {
                    const int c = sub + 8 * t;
                    if (c >= 27) break;
                    const int oi = c / 9;
                    const int rem = c - 9 * oi;
                    const int oj = rem / 3;
                    const int ok = rem - 3 * oj;
                    const int nx = clampi(b0 + oi);
                    const int ny = clampi(b1 + oj);
                    const int nz = clampi(b2 + ok);
                    const float dpx = ((float)oi - gx0) * DXc;
                    const float dpy = ((float)oj - gx1) * DXc;
                    const float dpz = ((float)ok - gx2) * DXc;
                    const float w = wa[oi] * wb[oj] * wc[ok];
                    const float4 gq = cell_load(&gG4[(nx * G + ny) * G + nz]);
                    const float den = gq.w + vs;
                    float gvx = gq.x / den;
                    float gvy = gq.y / den;
                    float gvz = gq.z / den;
                    if (nx < 3       && gvx < 0.f) gvx = 0.f;
                    if (nx >= G - 3  && gvx > 0.f) gvx = 0.f;
                    if (ny < 3       && gvy < 0.f) gvy = 0.f;
                    if (ny >= G - 3  && gvy > 0.f) gvy = 0.f;
                    if (nz < 3       && gvz < 0.f) gvz = 0.f;
                    if (nz >= G - 3  && gvz > 0.f) gvz = 0.f;
                    nvx += w * gvx; nvy += w * gvy; nvz += w * gvz;
                    const float wgx = w * gvx, wgy = w * gvy, wgz = w * gvz;
                    nc00 += wgx * dpx; nc01 += wgx * dpy; nc02 += wgx * dpz;
                    nc10 += wgy * dpx; nc11 += wgy * dpy; nc12 += wgy * dpz;
                    nc20 += wgz * dpx; nc21 += wgz * dpy; nc22 += wgz * dpz;
                }
                // 8-lane butterfly: all lanes end with identical full sums
                #define BFLY(v) { v += __shfl_xor(v, 1); v += __shfl_xor(v, 2); v += __shfl_xor(v, 4); }
                BFLY(nvx) BFLY(nvy) BFLY(nvz)
                BFLY(nc00) BFLY(nc01) BFLY(nc02)
                BFLY(nc10) BFLY(nc11) BFLY(nc12)
                BFLY(nc20) BFLY(nc21) BFLY(nc22)
                #undef BFLY
                vx = nvx; vy = nvy; vz = nvz;
                C00 = CSC * nc00; C01 = CSC * nc01; C02 = CSC * nc02;
                C10 = CSC * nc10; C11 = CSC * nc11; C12 = CSC * nc12;
                C20 = CSC * nc20; C21 = CSC * nc21; C22 = CSC * nc22;
                px += DT * vx; py += DT * vy; pz += DT * vz;
            }

            // ======== F update: F = (I + DT*C) @ F (replicated) ========
            {
                const float t00 = F00 + DT * (C00 * F00 + C01 * F10 + C02 * F20);
                const float t01 = F01 + DT * (C00 * F01 + C01 * F11 + C02 * F21);
                const float t02 = F02 + DT * (C00 * F02 + C01 * F12 + C02 * F22);
                const float t10 = F10 + DT * (C10 * F00 + C11 * F10 + C12 * F20);
                const float t11 = F11 + DT * (C10 * F01 + C11 * F11 + C12 * F21);
                const float t12 = F12 + DT * (C10 * F02 + C11 * F12 + C12 * F22);
                const float t20 = F20 + DT * (C20 * F00 + C21 * F10 + C22 * F20);
                const float t21 = F21 + DT * (C20 * F01 + C21 * F11 + C22 * F21);
                const float t22 = F22 + DT * (C20 * F02 + C21 * F12 + C22 * F22);
                F00 = t00; F01 = t01; F02 = t02;
                F10 = t10; F11 = t11; F12 = t12;
                F20 = t20; F21 = t21; F22 = t22;
            }

            // ======== neo-Hookean PK1 stress -> affine (replicated) ========
            const float c00 = F11 * F22 - F12 * F21;
            const float c01 = F12 * F20 - F10 * F22;
            const float c02 = F10 * F21 - F11 * F20;
            const float det = F00 * c00 + F01 * c01 + F02 * c02;
            const float c10 = F02 * F21 - F01 * F22;
            const float c11 = F00 * F22 - F02 * F20;
            const float c12 = F01 * F20 - F00 * F21;
            const float c20 = F01 * F12 - F02 * F11;
            const float c21 = F02 * F10 - F00 * F12;
            const float c22 = F00 * F11 - F01 * F10;
            const float idet = 1.0f / det;
            const float lj = LAM * logf(fmaxf(det, 1e-6f));
            const float fit00 = c00 * idet, fit01 = c01 * idet, fit02 = c02 * idet;
            const float fit10 = c10 * idet, fit11 = c11 * idet, fit12 = c12 * idet;
            const float fit20 = c20 * idet, fit21 = c21 * idet, fit22 = c22 * idet;
            const float P00 = MU * (F00 - fit00) + lj * fit00;
            const float P01 = MU * (F01 - fit01) + lj * fit01;
            const float P02 = MU * (F02 - fit02) + lj * fit02;
            const float P10 = MU * (F10 - fit10) + lj * fit10;
            const float P11 = MU * (F11 - fit11) + lj * fit11;
            const float P12 = MU * (F12 - fit12) + lj * fit12;
            const float P20 = MU * (F20 - fit20) + lj * fit20;
            const float P21 = MU * (F21 - fit21) + lj * fit21;
            const float P22 = MU * (F22 - fit22) + lj * fit22;
            A00 = KS * (P00 * F00 + P01 * F01 + P02 * F02) + P_MASS * C00;
            A01 = KS * (P00 * F10 + P01 * F11 + P02 * F12) + P_MASS * C01;
            A02 = KS * (P00 * F20 + P01 * F21 + P02 * F22) + P_MASS * C02;
            A10 = KS * (P10 * F00 + P11 * F01 + P12 * F02) + P_MASS * C10;
            A11 = KS * (P10 * F10 + P11 * F11 + P12 * F12) + P_MASS * C11;
            A12 = KS * (P10 * F20 + P11 * F21 + P12 * F22) + P_MASS * C12;
            A20 = KS * (P20 * F00 + P21 * F01 + P22 * F02) + P_MASS * C20;
            A21 = KS * (P20 * F10 + P21 * F11 + P22 * F12) + P_MASS * C21;
            A22 = KS * (P20 * F20 + P21 * F21 + P22 * F22) + P_MASS * C22;

            // scatter base (from updated x)
            const float xs0 = px * INV_DX, xs1 = py * INV_DX, xs2 = pz * INV_DX;
            const float fb0 = floorf(xs0 - 0.5f), fb1 = floorf(xs1 - 0.5f), fb2 = floorf(xs2 - 0.5f);
            sb0 = (int)fb0; sb1 = (int)fb1; sb2 = (int)fb2;
            fx0 = xs0 - fb0; fx1 = xs1 - fb1; fx2 = xs2 - fb2;
            mvx = P_MASS * vx;
            mvy = P_MASS * (vy + DTG);
            mvz = P_MASS * vz;
        }

        // ======== per-wg clamped scatter bbox reduction ========
        if (threadIdx.x == 0) {
            sred[0] = INT_MAX; sred[1] = INT_MAX; sred[2] = INT_MAX;
            sred[3] = INT_MIN; sred[4] = INT_MIN; sred[5] = INT_MIN;
        }
        __syncthreads();
        if (act && sub == 0) {
            atomicMin(&sred[0], clampi(sb0)); atomicMax(&sred[3], clampi(sb0 + 2));
            atomicMin(&sred[1], clampi(sb1)); atomicMax(&sred[4], clampi(sb1 + 2));
            atomicMin(&sred[2], clampi(sb2)); atomicMax(&sred[5], clampi(sb2 + 2));
        }
        __syncthreads();
        const int mn0 = sred[0], mn1 = sred[1], mn2 = sred[2];
        const int mx0 = sred[3], mx1 = sred[4], mx2 = sred[5];
        const bool anyAct = (mx0 >= mn0);
        const int D1 = mx1 - mn1 + 1, D2 = mx2 - mn2 + 1;
        const int vol = anyAct ? (mx0 - mn0 + 1) * D1 * D2 : 0;
        const bool useLDS = anyAct && (vol <= TC);
        __syncthreads();   // tile reuse guard

        // weights for scatter (replicated per lane group)
        float wa0 = 0.f, wa1 = 0.f, wa2 = 0.f, wb0 = 0.f, wb1 = 0.f, wb2 = 0.f,
              wcc0 = 0.f, wcc1 = 0.f, wcc2 = 0.f;
        if (act) {
            wa0 = 0.5f * (1.5f - fx0) * (1.5f - fx0);
            wa1 = 0.75f - (fx0 - 1.0f) * (fx0 - 1.0f);
            wa2 = 0.5f * (fx0 - 0.5f) * (fx0 - 0.5f);
            wb0 = 0.5f * (1.5f - fx1) * (1.5f - fx1);
            wb1 = 0.75f - (fx1 - 1.0f) * (fx1 - 1.0f);
            wb2 = 0.5f * (fx1 - 0.5f) * (fx1 - 0.5f);
            wcc0 = 0.5f * (1.5f - fx2) * (1.5f - fx2);
            wcc1 = 0.75f - (fx2 - 1.0f) * (fx2 - 1.0f);
            wcc2 = 0.5f * (fx2 - 0.5f) * (fx2 - 0.5f);
        }
        const float WA[3] = { wa0, wa1, wa2 };
        const float WB[3] = { wb0, wb1, wb2 };
        const float WC[3] = { wcc0, wcc1, wcc2 };

        if (useLDS) {
            // zero tile portion (float4 stores)
            float4* t4 = reinterpret_cast<float4*>(tile);
            const float4 z = make_float4(0.f, 0.f, 0.f, 0.f);
            for (int i = threadIdx.x; i < vol; i += NTHR) t4[i] = z;
            __syncthreads();
            if (act) {
                #pragma unroll
                for (int t = 0; t < 4; ++t) {
                    const int c = sub + 8 * t;
                    if (c >= 27) break;
                    const int oi = c / 9;
                    const int rem = c - 9 * oi;
                    const int oj = rem / 3;
                    const int ok = rem - 3 * oj;
                    const int li  = clampi(sb0 + oi) - mn0;
                    const int lj2 = clampi(sb1 + oj) - mn1;
                    const int lk  = clampi(sb2 + ok) - mn2;
                    const float dpx = ((float)oi - fx0) * DXc;
                    const float dpy = ((float)oj - fx1) * DXc;
                    const float dpz = ((float)ok - fx2) * DXc;
                    const float w = WA[oi] * WB[oj] * WC[ok];
                    const int c4 = 4 * ((li * D1 + lj2) * D2 + lk);
                    atomicAdd(&tile[c4 + 0], w * (mvx + A00 * dpx + A01 * dpy + A02 * dpz));
                    atomicAdd(&tile[c4 + 1], w * (mvy + A10 * dpx + A11 * dpy + A12 * dpz));
                    atomicAdd(&tile[c4 + 2], w * (mvz + A20 * dpx + A21 * dpy + A22 * dpz));
                    atomicAdd(&tile[c4 + 3], w * P_MASS);
                }
            }
            __syncthreads();
            // flush tile -> global (agent-scope atomics), skip empty cells
            for (int c = threadIdx.x; c < vol; c += NTHR) {
                const float m = tile[4 * c + 3];
                if (m != 0.f) {
                    const int k = c % D2;
                    const int t = c / D2;
                    const int j = t % D1;
                    const int i = t / D1;
                    const int gidx = ((mn0 + i) * G + (mn1 + j)) * G + (mn2 + k);
                    float* gp = reinterpret_cast<float*>(gS4 + gidx);
                    unsafeAtomicAdd(gp + 0, tile[4 * c + 0]);
                    unsafeAtomicAdd(gp + 1, tile[4 * c + 1]);
                    unsafeAtomicAdd(gp + 2, tile[4 * c + 2]);
                    unsafeAtomicAdd(gp + 3, m);
                }
            }
        } else if (anyAct && act) {
            // fallback: direct global atomics (bbox too large)
            #pragma unroll
            for (int t = 0; t < 4; ++t) {
                const int c = sub + 8 * t;
                if (c >= 27) break;
                const int oi = c / 9;
                const int rem = c - 9 * oi;
                const int oj = rem / 3;
                const int ok = rem - 3 * oj;
                const int nx = clampi(sb0 + oi);
                const int ny = clampi(sb1 + oj);
                const int nz = clampi(sb2 + ok);
                const float dpx = ((float)oi - fx0) * DXc;
                const float dpy = ((float)oj - fx1) * DXc;
                const float dpz = ((float)ok - fx2) * DXc;
                const float w = WA[oi] * WB[oj] * WC[ok];
                float* gp = reinterpret_cast<float*>(gS4 + (nx * G + ny) * G + nz);
                unsafeAtomicAdd(gp + 0, w * (mvx + A00 * dpx + A01 * dpy + A02 * dpz));
                unsafeAtomicAdd(gp + 1, w * (mvy + A10 * dpx + A11 * dpy + A12 * dpz));
                unsafeAtomicAdd(gp + 2, w * (mvz + A20 * dpx + A21 * dpy + A22 * dpz));
                unsafeAtomicAdd(gp + 3, w * P_MASS);
            }
        }

        // shift bbox history
        zmn0 = pmn0; zmn1 = pmn1; zmn2 = pmn2;
        zmx0 = pmx0; zmx1 = pmx1; zmx2 = pmx2; zvalid = pvalid;
        pmn0 = mn0; pmn1 = mn1; pmn2 = mn2;
        pmx0 = mx0; pmx1 = mx1; pmx2 = mx2; pvalid = anyAct;

        gridbar(barcnt, ++gen);
    }

    // ---- final frame output: grid_m of substep 599 ----
    {
        const float4* gL4 = g4 + ((NSUB - 1) % 3) * G3;
        float* o = out + (NSUB / SPF - 1) * G3;
        for (int i = tid; i < G3; i += nth) o[i] = cell_load_w(&gL4[i]) + vs;
    }
}

extern "C" void kernel_launch(void* const* d_in, const int* in_sizes, int n_in,
                              void* d_out, int out_size, void* d_ws, size_t ws_size,
                              hipStream_t stream) {
    const float* v  = (const float*)d_in[0];
    const float* q  = (const float*)d_in[1];
    const float* qd = (const float*)d_in[2];
    float* out = (float*)d_out;
    float* ws  = (float*)d_ws;
    // barrier counter at the tail of the workspace (grid buffers use the head)
    unsigned* barcnt = reinterpret_cast<unsigned*>((char*)d_ws + (ws_size & ~(size_t)15) - 16);
    void* args[] = { (void*)&v, (void*)&q, (void*)&qd, (void*)&out, (void*)&ws, (void*)&barcnt };
    hipLaunchCooperativeKernel(reinterpret_cast<void*>(mpm_sim),
                               dim3(NBLK), dim3(NTHR), args, 0, stream);
}

// Round 7
// 19069.019 us; speedup vs baseline: 4.3445x; 1.0317x over previous
//
#include <hip/hip_runtime.h>
#include <hip/hip_cooperative_groups.h>

namespace cg = cooperative_groups;

static constexpr int G    = 100;
static constexpr int G3   = G * G * G;
static constexpr int NP   = 13500;   // 30*15*30 particles
static constexpr int NSUB = 600;     // 20 frames x 30 substeps
static constexpr int SPF  = 30;      // substeps per frame
static constexpr int NTHR = 1024;
static constexpr int NBLK = 108;     // 6x3x6 bricks of 5x5x5 particles
static constexpr int TCIN  = 2048;   // LDS IN-tile capacity (float4/cell = 32 KB)
static constexpr int TCOUT = 2048;   // LDS OUT-tile capacity (4 floats/cell = 32 KB)

__device__ __forceinline__ int clampi(int v) {
    return v < 0 ? 0 : (v > G - 1 ? G - 1 : v);
}

// MALL-coherent (agent-scope, relaxed) zero store: grid writes never allocate
// dirty L2 lines, so plain cached READS + one acquire-invalidate per phase are
// sufficient for cross-XCD coherence.
__device__ __forceinline__ void cell_zero(float4* p) {
    unsigned long long* q = reinterpret_cast<unsigned long long*>(p);
    __hip_atomic_store(&q[0], 0ull, __ATOMIC_RELAXED, __HIP_MEMORY_SCOPE_AGENT);
    __hip_atomic_store(&q[1], 0ull, __ATOMIC_RELAXED, __HIP_MEMORY_SCOPE_AGENT);
}

// Grid barrier: monotonic counter, target = gen*NBLK. __syncthreads() drains
// vmcnt (all MALL-bound flush/zero ops acked) before the arrive-add; on exit,
// thread 0 issues an agent-acquire fence (buffer_inv: L1+L2 invalidate) so the
// block's subsequent PLAIN cached loads observe all other blocks' MALL writes.
__device__ __forceinline__ void gridbar(unsigned* __restrict__ cnt, unsigned gen) {
    __syncthreads();
    if (threadIdx.x == 0) {
        __hip_atomic_fetch_add(cnt, 1u, __ATOMIC_RELAXED, __HIP_MEMORY_SCOPE_AGENT);
        const unsigned target = gen * (unsigned)NBLK;
        while (__hip_atomic_load(cnt, __ATOMIC_RELAXED, __HIP_MEMORY_SCOPE_AGENT) < target) {
            __builtin_amdgcn_s_sleep(1);
        }
        __builtin_amdgcn_fence(__ATOMIC_ACQUIRE, "agent");   // buffer_inv
    }
    __syncthreads();
}

// Persistent cooperative kernel. Triple-buffered float4 grid in ws:
//   g4[buf*G3 + idx] = (mom.x, mom.y, mom.z, mass)
// Phase p: zero substep p-2's per-wg bbox (MALL stores), STAGE the gather
// region (== own scatter bbox of p-1) into an LDS IN-tile with normalization
// (mom/(mass+vs)) and boundary conditions applied ONCE PER CELL, per-particle
// G2P gather from LDS, compute, P2G scatter into an LDS OUT-tile, flush with
// agent-scope atomics. One grid barrier (with acquire-inv) per phase.
// Particles in 5x5x5 spatial bricks; 4 lanes per particle (stencil cells split
// c%4) with 2-level shfl-xor butterfly reduction.
__launch_bounds__(NTHR)
__global__ void mpm_sim(const float* __restrict__ vscal,
                        const float* __restrict__ q0,
                        const float* __restrict__ qd0,
                        float* __restrict__ out,
                        float* __restrict__ ws,
                        unsigned* __restrict__ barcnt)
{
    const float vs = vscal[0];
    float4* const g4 = reinterpret_cast<float4*>(ws);

    cg::grid_group gg = cg::this_grid();
    const int tid = blockIdx.x * NTHR + threadIdx.x;
    const int nth = NBLK * NTHR;

    // brick/slot -> original particle index (4 lanes per particle)
    const int slot = threadIdx.x >> 2;        // 0..255
    const int sub  = threadIdx.x & 3;         // lane within particle group
    const bool act = slot < 125;
    int pid = 0;
    if (act) {
        const int b  = blockIdx.x;            // (bx*3+by)*6+bz
        const int bx = b / 18;
        const int by = (b / 6) % 3;
        const int bz = b % 6;
        const int lx = slot / 25;
        const int rem = slot % 25;
        const int ly = rem / 5;
        const int lz = rem % 5;
        const int ix = bx * 5 + lx;
        const int iy = by * 5 + ly;
        const int iz = bz * 5 + lz;
        pid = (ix * 15 + iy) * 30 + iz;
    }

    const float DT      = 5e-4f;
    const float INV_DX  = 100.0f;
    const float DXc     = 0.01f;
    const float MU      = (float)(1.0e5 / (2.0 * (1.0 + 0.3)));
    const float LAM     = (float)(1.0e5 * 0.3 / ((1.0 + 0.3) * (1.0 - 0.6)));
    const float P_MASS  = (float)(0.005 * 0.005 * 0.005 * 3000.0);
    const float KS      = (float)(-5.0e-4 * (0.005 * 0.005 * 0.005) * 4.0 * 100.0 * 100.0);
    const float DTG     = (float)(5.0e-4 * (-9.8));
    const float CSC     = 4.0f * INV_DX * INV_DX;   // 40000

    __shared__ float4 tileIn[TCIN];     // normalized grid velocity per cell
    __shared__ float  tileOut[4 * TCOUT];  // scatter accum: [mx,my,mz,mass]
    __shared__ int sred[6];             // bbox reduction

    // ---- init: zero all 3 grid buffers + barrier counter (ws poisoned 0xAA) ----
    // Plain stores here leave dirty L2 lines; the gg.sync() below does a full
    // agent release (wbl2), publishing them before any atomics touch the grid.
    {
        const float4 z = make_float4(0.f, 0.f, 0.f, 0.f);
        for (int i = tid; i < 3 * G3; i += nth) g4[i] = z;
        if (tid == 0)
            __hip_atomic_store(barcnt, 0u, __ATOMIC_RELAXED, __HIP_MEMORY_SCOPE_AGENT);
    }

    // ---- particle state, replicated across the 4 lanes of a group ----
    float px = 0.f, py = 0.f, pz = 0.f, vx = 0.f, vy = 0.f, vz = 0.f;
    float C00 = 0.f, C01 = 0.f, C02 = 0.f,
          C10 = 0.f, C11 = 0.f, C12 = 0.f,
          C20 = 0.f, C21 = 0.f, C22 = 0.f;
    float F00 = 1.f, F01 = 0.f, F02 = 0.f,
          F10 = 0.f, F11 = 1.f, F12 = 0.f,
          F20 = 0.f, F21 = 0.f, F22 = 1.f;
    if (act) {
        px = q0[3 * pid + 0]; py = q0[3 * pid + 1]; pz = q0[3 * pid + 2];
        vx = qd0[3 * pid + 0]; vy = qd0[3 * pid + 1]; vz = qd0[3 * pid + 2];
    }

    // per-wg bbox history (uniform across wg): p-1 and p-2 scatter bboxes
    int pmn0 = 0, pmn1 = 0, pmn2 = 0, pmx0 = -1, pmx1 = -1, pmx2 = -1; bool pvalid = false;
    int zmn0 = 0, zmn1 = 0, zmn2 = 0, zmx0 = -1, zmx1 = -1, zmx2 = -1; bool zvalid = false;

    gg.sync();   // publish init (release) before first phase

    unsigned gen = 0;

    for (int p = 0; p < NSUB; ++p) {
        const int bS = p % 3;
        const int bG = (p + 2) % 3;   // (p-1)%3 for p>0
        const int bZ = (p + 1) % 3;   // holds substep p-2 data
        float4*       __restrict__ gS4 = g4 + bS * G3;
        const float4* __restrict__ gG4 = g4 + bG * G3;
        float4*       __restrict__ gZ4 = g4 + bZ * G3;

        // ======== zero substep p-2's per-wg bbox (MALL stores, overlaps stage) ========
        if (zvalid) {
            const int zD1 = zmx1 - zmn1 + 1, zD2 = zmx2 - zmn2 + 1;
            const int zvol = (zmx0 - zmn0 + 1) * zD1 * zD2;
            for (int c = threadIdx.x; c < zvol; c += NTHR) {
                const int k = c % zD2;
                const int t = c / zD2;
                const int j = t % zD1;
                const int i = t / zD1;
                cell_zero(&gZ4[((zmn0 + i) * G + (zmn1 + j)) * G + (zmn2 + k)]);
            }
        }

        // frame output: grid_m of substep p-1 (plain cached loads, post-inv)
        if (p > 0 && ((p - 1) % SPF) == SPF - 1) {
            float* o = out + ((p - 1) / SPF) * G3;
            for (int i = tid; i < G3; i += nth) o[i] = gG4[i].w + vs;
        }

        // ======== STAGE: gather region (own p-1 scatter bbox) -> LDS, normalized ========
        const int iD1 = pvalid ? (pmx1 - pmn1 + 1) : 0;
        const int iD2 = pvalid ? (pmx2 - pmn2 + 1) : 0;
        const int inVol = pvalid ? (pmx0 - pmn0 + 1) * iD1 * iD2 : 0;
        const bool staged = pvalid && (inVol <= TCIN);
        if (staged) {
            for (int c = threadIdx.x; c < inVol; c += NTHR) {
                const int k = c % iD2;
                const int t = c / iD2;
                const int j = t % iD1;
                const int i = t / iD1;
                const int nx = pmn0 + i, ny = pmn1 + j, nz = pmn2 + k;
                const float4 gq = gG4[(nx * G + ny) * G + nz];  // plain cached load
                const float den = gq.w + vs;
                float gvx = gq.x / den;
                float gvy = gq.y / den;
                float gvz = gq.z / den;
                if (nx < 3       && gvx < 0.f) gvx = 0.f;
                if (nx >= G - 3  && gvx > 0.f) gvx = 0.f;
                if (ny < 3       && gvy < 0.f) gvy = 0.f;
                if (ny >= G - 3  && gvy > 0.f) gvy = 0.f;
                if (nz < 3       && gvz < 0.f) gvz = 0.f;
                if (nz >= G - 3  && gvz > 0.f) gvz = 0.f;
                tileIn[c] = make_float4(gvx, gvy, gvz, 0.f);
            }
        }
        __syncthreads();

        int sb0 = 0, sb1 = 0, sb2 = 0;
        float fx0 = 0.f, fx1 = 0.f, fx2 = 0.f;
        float A00 = 0.f, A01 = 0.f, A02 = 0.f,
              A10 = 0.f, A11 = 0.f, A12 = 0.f,
              A20 = 0.f, A21 = 0.f, A22 = 0.f;
        float mvx = 0.f, mvy = 0.f, mvz = 0.f;

        if (act) {
            // ======== G2P gather for substep p-1 (cells c%4==sub per lane) ========
            if (p > 0) {
                const float xs0 = px * INV_DX, xs1 = py * INV_DX, xs2 = pz * INV_DX;
                const float fb0 = floorf(xs0 - 0.5f), fb1 = floorf(xs1 - 0.5f), fb2 = floorf(xs2 - 0.5f);
                const int b0 = (int)fb0, b1 = (int)fb1, b2 = (int)fb2;
                const float gx0 = xs0 - fb0, gx1 = xs1 - fb1, gx2 = xs2 - fb2;
                float wa[3], wb[3], wc[3];
                wa[0] = 0.5f * (1.5f - gx0) * (1.5f - gx0);
                wa[1] = 0.75f - (gx0 - 1.0f) * (gx0 - 1.0f);
                wa[2] = 0.5f * (gx0 - 0.5f) * (gx0 - 0.5f);
                wb[0] = 0.5f * (1.5f - gx1) * (1.5f - gx1);
                wb[1] = 0.75f - (gx1 - 1.0f) * (gx1 - 1.0f);
                wb[2] = 0.5f * (gx1 - 0.5f) * (gx1 - 0.5f);
                wc[0] = 0.5f * (1.5f - gx2) * (1.5f - gx2);
                wc[1] = 0.75f - (gx2 - 1.0f) * (gx2 - 1.0f);
                wc[2] = 0.5f * (gx2 - 0.5f) * (gx2 - 0.5f);

                float nvx = 0.f, nvy = 0.f, nvz = 0.f;
                float nc00 = 0.f, nc01 = 0.f, nc02 = 0.f,
                      nc10 = 0.f, nc11 = 0.f, nc12 = 0.f,
                      nc20 = 0.f, nc21 = 0.f, nc22 = 0.f;
                #pragma unroll
                for (int t = 0; t < 7; ++t) {
                    const int c = sub + 4 * t;
                    if (c >= 27) break;
                    const int oi = c / 9;
                    const int rem = c - 9 * oi;
                    const int oj = rem / 3;
                    const int ok = rem - 3 * oj;
                    const int nx = clampi(b0 + oi);
                    const int ny = clampi(b1 + oj);
                    const int nz = clampi(b2 + ok);
                    const float dpx = ((float)oi - gx0) * DXc;
                    const float dpy = ((float)oj - gx1) * DXc;
                    const float dpz = ((float)ok - gx2) * DXc;
                    const float w = wa[oi] * wb[oj] * wc[ok];
                    float gvx, gvy, gvz;
                    if (staged) {
                        const float4 gv4 = tileIn[((nx - pmn0) * iD1 + (ny - pmn1)) * iD2 + (nz - pmn2)];
                        gvx = gv4.x; gvy = gv4.y; gvz = gv4.z;
                    } else {
                        const float4 gq = gG4[(nx * G + ny) * G + nz];  // plain cached load
                        const float den = gq.w + vs;
                        gvx = gq.x / den;
                        gvy = gq.y / den;
                        gvz = gq.z / den;
                        if (nx < 3       && gvx < 0.f) gvx = 0.f;
                        if (nx >= G - 3  && gvx > 0.f) gvx = 0.f;
                        if (ny < 3       && gvy < 0.f) gvy = 0.f;
                        if (ny >= G - 3  && gvy > 0.f) gvy = 0.f;
                        if (nz < 3       && gvz < 0.f) gvz = 0.f;
                        if (nz >= G - 3  && gvz > 0.f) gvz = 0.f;
                    }
                    nvx += w * gvx; nvy += w * gvy; nvz += w * gvz;
                    const float wgx = w * gvx, wgy = w * gvy, wgz = w * gvz;
                    nc00 += wgx * dpx; nc01 += wgx * dpy; nc02 += wgx * dpz;
                    nc10 += wgy * dpx; nc11 += wgy * dpy; nc12 += wgy * dpz;
                    nc20 += wgz * dpx; nc21 += wgz * dpy; nc22 += wgz * dpz;
                }
                // 4-lane butterfly: all lanes end with identical full sums
                #define BFLY(v) { v += __shfl_xor(v, 1); v += __shfl_xor(v, 2); }
                BFLY(nvx) BFLY(nvy) BFLY(nvz)
                BFLY(nc00) BFLY(nc01) BFLY(nc02)
                BFLY(nc10) BFLY(nc11) BFLY(nc12)
                BFLY(nc20) BFLY(nc21) BFLY(nc22)
                #undef BFLY
                vx = nvx; vy = nvy; vz = nvz;
                C00 = CSC * nc00; C01 = CSC * nc01; C02 = CSC * nc02;
                C10 = CSC * nc10; C11 = CSC * nc11; C12 = CSC * nc12;
                C20 = CSC * nc20; C21 = CSC * nc21; C22 = CSC * nc22;
                px += DT * vx; py += DT * vy; pz += DT * vz;
            }

            // ======== F update: F = (I + DT*C) @ F (replicated) ========
            {
                const float t00 = F00 + DT * (C00 * F00 + C01 * F10 + C02 * F20);
                const float t01 = F01 + DT * (C00 * F01 + C01 * F11 + C02 * F21);
                const float t02 = F02 + DT * (C00 * F02 + C01 * F12 + C02 * F22);
                const float t10 = F10 + DT * (C10 * F00 + C11 * F10 + C12 * F20);
                const float t11 = F11 + DT * (C10 * F01 + C11 * F11 + C12 * F21);
                const float t12 = F12 + DT * (C10 * F02 + C11 * F12 + C12 * F22);
                const float t20 = F20 + DT * (C20 * F00 + C21 * F10 + C22 * F20);
                const float t21 = F21 + DT * (C20 * F01 + C21 * F11 + C22 * F21);
                const float t22 = F22 + DT * (C20 * F02 + C21 * F12 + C22 * F22);
                F00 = t00; F01 = t01; F02 = t02;
                F10 = t10; F11 = t11; F12 = t12;
                F20 = t20; F21 = t21; F22 = t22;
            }

            // ======== neo-Hookean PK1 stress -> affine (replicated) ========
            const float c00 = F11 * F22 - F12 * F21;
            const float c01 = F12 * F20 - F10 * F22;
            const float c02 = F10 * F21 - F11 * F20;
            const float det = F00 * c00 + F01 * c01 + F02 * c02;
            const float c10 = F02 * F21 - F01 * F22;
            const float c11 = F00 * F22 - F02 * F20;
            const float c12 = F01 * F20 - F00 * F21;
            const float c20 = F01 * F12 - F02 * F11;
            const float c21 = F02 * F10 - F00 * F12;
            const float c22 = F00 * F11 - F01 * F10;
            const float idet = 1.0f / det;
            const float lj = LAM * logf(fmaxf(det, 1e-6f));
            const float fit00 = c00 * idet, fit01 = c01 * idet, fit02 = c02 * idet;
            const float fit10 = c10 * idet, fit11 = c11 * idet, fit12 = c12 * idet;
            const float fit20 = c20 * idet, fit21 = c21 * idet, fit22 = c22 * idet;
            const float P00 = MU * (F00 - fit00) + lj * fit00;
            const float P01 = MU * (F01 - fit01) + lj * fit01;
            const float P02 = MU * (F02 - fit02) + lj * fit02;
            const float P10 = MU * (F10 - fit10) + lj * fit10;
            const float P11 = MU * (F11 - fit11) + lj * fit11;
            const float P12 = MU * (F12 - fit12) + lj * fit12;
            const float P20 = MU * (F20 - fit20) + lj * fit20;
            const float P21 = MU * (F21 - fit21) + lj * fit21;
            const float P22 = MU * (F22 - fit22) + lj * fit22;
            A00 = KS * (P00 * F00 + P01 * F01 + P02 * F02) + P_MASS * C00;
            A01 = KS * (P00 * F10 + P01 * F11 + P02 * F12) + P_MASS * C01;
            A02 = KS * (P00 * F20 + P01 * F21 + P02 * F22) + P_MASS * C02;
            A10 = KS * (P10 * F00 + P11 * F01 + P12 * F02) + P_MASS * C10;
            A11 = KS * (P10 * F10 + P11 * F11 + P12 * F12) + P_MASS * C11;
            A12 = KS * (P10 * F20 + P11 * F21 + P12 * F22) + P_MASS * C12;
            A20 = KS * (P20 * F00 + P21 * F01 + P22 * F02) + P_MASS * C20;
            A21 = KS * (P20 * F10 + P21 * F11 + P22 * F12) + P_MASS * C21;
            A22 = KS * (P20 * F20 + P21 * F21 + P22 * F22) + P_MASS * C22;

            // scatter base (from updated x)
            const float xs0 = px * INV_DX, xs1 = py * INV_DX, xs2 = pz * INV_DX;
            const float fb0 = floorf(xs0 - 0.5f), fb1 = floorf(xs1 - 0.5f), fb2 = floorf(xs2 - 0.5f);
            sb0 = (int)fb0; sb1 = (int)fb1; sb2 = (int)fb2;
            fx0 = xs0 - fb0; fx1 = xs1 - fb1; fx2 = xs2 - fb2;
            mvx = P_MASS * vx;
            mvy = P_MASS * (vy + DTG);
            mvz = P_MASS * vz;
        }

        // ======== per-wg clamped scatter bbox reduction ========
        if (threadIdx.x == 0) {
            sred[0] = INT_MAX; sred[1] = INT_MAX; sred[2] = INT_MAX;
            sred[3] = INT_MIN; sred[4] = INT_MIN; sred[5] = INT_MIN;
        }
        __syncthreads();
        if (act && sub == 0) {
            atomicMin(&sred[0], clampi(sb0)); atomicMax(&sred[3], clampi(sb0 + 2));
            atomicMin(&sred[1], clampi(sb1)); atomicMax(&sred[4], clampi(sb1 + 2));
            atomicMin(&sred[2], clampi(sb2)); atomicMax(&sred[5], clampi(sb2 + 2));
        }
        __syncthreads();
        const int mn0 = sred[0], mn1 = sred[1], mn2 = sred[2];
        const int mx0 = sred[3], mx1 = sred[4], mx2 = sred[5];
        const bool anyAct = (mx0 >= mn0);
        const int D1 = mx1 - mn1 + 1, D2 = mx2 - mn2 + 1;
        const int vol = anyAct ? (mx0 - mn0 + 1) * D1 * D2 : 0;
        const bool useLDS = anyAct && (vol <= TCOUT);
        __syncthreads();   // tile reuse guard

        // weights for scatter (replicated per lane group)
        float wa0 = 0.f, wa1 = 0.f, wa2 = 0.f, wb0 = 0.f, wb1 = 0.f, wb2 = 0.f,
              wcc0 = 0.f, wcc1 = 0.f, wcc2 = 0.f;
        if (act) {
            wa0 = 0.5f * (1.5f - fx0) * (1.5f - fx0);
            wa1 = 0.75f - (fx0 - 1.0f) * (fx0 - 1.0f);
            wa2 = 0.5f * (fx0 - 0.5f) * (fx0 - 0.5f);
            wb0 = 0.5f * (1.5f - fx1) * (1.5f - fx1);
            wb1 = 0.75f - (fx1 - 1.0f) * (fx1 - 1.0f);
            wb2 = 0.5f * (fx1 - 0.5f) * (fx1 - 0.5f);
            wcc0 = 0.5f * (1.5f - fx2) * (1.5f - fx2);
            wcc1 = 0.75f - (fx2 - 1.0f) * (fx2 - 1.0f);
            wcc2 = 0.5f * (fx2 - 0.5f) * (fx2 - 0.5f);
        }
        const float WA[3] = { wa0, wa1, wa2 };
        const float WB[3] = { wb0, wb1, wb2 };
        const float WC[3] = { wcc0, wcc1, wcc2 };

        if (useLDS) {
            // zero tile portion (float4 stores)
            float4* t4 = reinterpret_cast<float4*>(tileOut);
            const float4 z = make_float4(0.f, 0.f, 0.f, 0.f);
            for (int i = threadIdx.x; i < vol; i += NTHR) t4[i] = z;
            __syncthreads();
            if (act) {
                #pragma unroll
                for (int t = 0; t < 7; ++t) {
                    const int c = sub + 4 * t;
                    if (c >= 27) break;
                    const int oi = c / 9;
                    const int rem = c - 9 * oi;
                    const int oj = rem / 3;
                    const int ok = rem - 3 * oj;
                    const int li  = clampi(sb0 + oi) - mn0;
                    const int lj2 = clampi(sb1 + oj) - mn1;
                    const int lk  = clampi(sb2 + ok) - mn2;
                    const float dpx = ((float)oi - fx0) * DXc;
                    const float dpy = ((float)oj - fx1) * DXc;
                    const float dpz = ((float)ok - fx2) * DXc;
                    const float w = WA[oi] * WB[oj] * WC[ok];
                    const int c4 = 4 * ((li * D1 + lj2) * D2 + lk);
                    atomicAdd(&tileOut[c4 + 0], w * (mvx + A00 * dpx + A01 * dpy + A02 * dpz));
                    atomicAdd(&tileOut[c4 + 1], w * (mvy + A10 * dpx + A11 * dpy + A12 * dpz));
                    atomicAdd(&tileOut[c4 + 2], w * (mvz + A20 * dpx + A21 * dpy + A22 * dpz));
                    atomicAdd(&tileOut[c4 + 3], w * P_MASS);
                }
            }
            __syncthreads();
            // flush tile -> global (agent-scope atomics), skip empty cells
            for (int c = threadIdx.x; c < vol; c += NTHR) {
                const float m = tileOut[4 * c + 3];
                if (m != 0.f) {
                    const int k = c % D2;
                    const int t = c / D2;
                    const int j = t % D1;
                    const int i = t / D1;
                    const int gidx = ((mn0 + i) * G + (mn1 + j)) * G + (mn2 + k);
                    float* gp = reinterpret_cast<float*>(gS4 + gidx);
                    unsafeAtomicAdd(gp + 0, tileOut[4 * c + 0]);
                    unsafeAtomicAdd(gp + 1, tileOut[4 * c + 1]);
                    unsafeAtomicAdd(gp + 2, tileOut[4 * c + 2]);
                    unsafeAtomicAdd(gp + 3, m);
                }
            }
        } else if (anyAct && act) {
            // fallback: direct global atomics (bbox too large)
            #pragma unroll
            for (int t = 0; t < 7; ++t) {
                const int c = sub + 4 * t;
                if (c >= 27) break;
                const int oi = c / 9;
                const int rem = c - 9 * oi;
                const int oj = rem / 3;
                const int ok = rem - 3 * oj;
                const int nx = clampi(sb0 + oi);
                const int ny = clampi(sb1 + oj);
                const int nz = clampi(sb2 + ok);
                const float dpx = ((float)oi - fx0) * DXc;
                const float dpy = ((float)oj - fx1) * DXc;
                const float dpz = ((float)ok - fx2) * DXc;
                const float w = WA[oi] * WB[oj] * WC[ok];
                float* gp = reinterpret_cast<float*>(gS4 + (nx * G + ny) * G + nz);
                unsafeAtomicAdd(gp + 0, w * (mvx + A00 * dpx + A01 * dpy + A02 * dpz));
                unsafeAtomicAdd(gp + 1, w * (mvy + A10 * dpx + A11 * dpy + A12 * dpz));
                unsafeAtomicAdd(gp + 2, w * (mvz + A20 * dpx + A21 * dpy + A22 * dpz));
                unsafeAtomicAdd(gp + 3, w * P_MASS);
            }
        }

        // shift bbox history
        zmn0 = pmn0; zmn1 = pmn1; zmn2 = pmn2;
        zmx0 = pmx0; zmx1 = pmx1; zmx2 = pmx2; zvalid = pvalid;
        pmn0 = mn0; pmn1 = mn1; pmn2 = mn2;
        pmx0 = mx0; pmx1 = mx1; pmx2 = mx2; pvalid = anyAct;

        gridbar(barcnt, ++gen);
    }

    // ---- final frame output: grid_m of substep 599 (post-inv plain loads) ----
    {
        const float4* gL4 = g4 + ((NSUB - 1) % 3) * G3;
        float* o = out + (NSUB / SPF - 1) * G3;
        for (int i = tid; i < G3; i += nth) o[i] = gL4[i].w + vs;
    }
}

extern "C" void kernel_launch(void* const* d_in, const int* in_sizes, int n_in,
                              void* d_out, int out_size, void* d_ws, size_t ws_size,
                              hipStream_t stream) {
    const float* v  = (const float*)d_in[0];
    const float* q  = (const float*)d_in[1];
    const float* qd = (const float*)d_in[2];
    float* out = (float*)d_out;
    float* ws  = (float*)d_ws;
    // barrier counter at the tail of the workspace (grid buffers use the head)
    unsigned* barcnt = reinterpret_cast<unsigned*>((char*)d_ws + (ws_size & ~(size_t)15) - 16);
    void* args[] = { (void*)&v, (void*)&q, (void*)&qd, (void*)&out, (void*)&ws, (void*)&barcnt };
    hipLaunchCooperativeKernel(reinterpret_cast<void*>(mpm_sim),
                               dim3(NBLK), dim3(NTHR), args, 0, stream);
}

// Round 8
// 18158.763 us; speedup vs baseline: 4.5623x; 1.0501x over previous
//
#include <hip/hip_runtime.h>
#include <hip/hip_cooperative_groups.h>

namespace cg = cooperative_groups;

static constexpr int G    = 100;
static constexpr int G3   = G * G * G;
static constexpr int NP   = 13500;   // 30*15*30 particles
static constexpr int NSUB = 600;     // 20 frames x 30 substeps
static constexpr int SPF  = 30;      // substeps per frame
static constexpr int NTHR = 512;     // 8 waves/block (halves sync drain vs 1024)
static constexpr int NBLK = 108;     // 6x3x6 bricks of 5x5x5 particles
static constexpr int TCIN  = 2048;   // LDS IN-tile capacity (float4/cell = 32 KB)
static constexpr int TCOUT = 2048;   // LDS OUT-tile capacity (4 floats/cell = 32 KB)
static constexpr int CH   = (G3 + SPF - 2) / (SPF - 1);  // out-init chunk (34483)

__device__ __forceinline__ int clampi(int v) {
    return v < 0 ? 0 : (v > G - 1 ? G - 1 : v);
}

// MALL-coherent (agent-scope, relaxed) helpers. ALL grid traffic (and all out
// traffic) goes through these or through agent-scope atomics, so the grid is
// never cached dirty in any L2 -> the grid barrier needs NO cache maintenance.
__device__ __forceinline__ float4 cell_load(const float4* p) {
    const unsigned long long* q = reinterpret_cast<const unsigned long long*>(p);
    unsigned long long a = __hip_atomic_load(&q[0], __ATOMIC_RELAXED, __HIP_MEMORY_SCOPE_AGENT);
    unsigned long long b = __hip_atomic_load(&q[1], __ATOMIC_RELAXED, __HIP_MEMORY_SCOPE_AGENT);
    float4 r;
    r.x = __uint_as_float((unsigned)(a & 0xffffffffu));
    r.y = __uint_as_float((unsigned)(a >> 32));
    r.z = __uint_as_float((unsigned)(b & 0xffffffffu));
    r.w = __uint_as_float((unsigned)(b >> 32));
    return r;
}
__device__ __forceinline__ void cell_zero(float4* p) {
    unsigned long long* q = reinterpret_cast<unsigned long long*>(p);
    __hip_atomic_store(&q[0], 0ull, __ATOMIC_RELAXED, __HIP_MEMORY_SCOPE_AGENT);
    __hip_atomic_store(&q[1], 0ull, __ATOMIC_RELAXED, __HIP_MEMORY_SCOPE_AGENT);
}

// Fence-free grid barrier (monotonic counter, target = gen*NBLK).
// __syncthreads() drains vmcnt (all MALL-bound ops acked at the single
// coherence point) before the arrive-add; waiters' post-spin accesses are
// issued strictly later and hit the same coherence point. No wbl2/inv.
__device__ __forceinline__ void gridbar(unsigned* __restrict__ cnt, unsigned gen) {
    __syncthreads();
    if (threadIdx.x == 0) {
        __hip_atomic_fetch_add(cnt, 1u, __ATOMIC_RELAXED, __HIP_MEMORY_SCOPE_AGENT);
        const unsigned target = gen * (unsigned)NBLK;
        while (__hip_atomic_load(cnt, __ATOMIC_RELAXED, __HIP_MEMORY_SCOPE_AGENT) < target) {
            __builtin_amdgcn_s_sleep(1);
        }
    }
    __syncthreads();
}

// Persistent cooperative kernel, triple-buffered float4 grid in ws:
//   g4[buf*G3 + idx] = (mom.x, mom.y, mom.z, mass)
// Phase p (5 block syncs total incl. barrier):
//   [pre-S1]  out-init chunk (spread vs-fill of the current frame's out slab),
//             sred init, FULL tileOut zero, zero p-2 bbox (MALL), stage gather
//             region (own p-1 scatter bbox) into tileIn normalized + BC'd.
//   [S1] -> particle G2P from LDS, F/stress/affine, bbox atomics
//   [S2] -> scatter into tileOut (LDS atomics)
//   [S3] -> flush tileOut -> grid (agent atomics); on frame-end phases ALSO
//           add mass into out[frame] (out pre-filled with vs; no copy pass).
//   [barrier arrive+wait]
__launch_bounds__(NTHR)
__global__ void mpm_sim(const float* __restrict__ vscal,
                        const float* __restrict__ q0,
                        const float* __restrict__ qd0,
                        float* __restrict__ out,
                        float* __restrict__ ws,
                        unsigned* __restrict__ barcnt)
{
    const float vs = vscal[0];
    float4* const g4 = reinterpret_cast<float4*>(ws);

    cg::grid_group gg = cg::this_grid();
    const int tid = blockIdx.x * NTHR + threadIdx.x;
    const int nth = NBLK * NTHR;

    // brick/slot -> original particle index (4 lanes per particle)
    const int slot = threadIdx.x >> 2;        // 0..127
    const int sub  = threadIdx.x & 3;         // lane within particle group
    const bool act = slot < 125;
    int pid = 0;
    if (act) {
        const int b  = blockIdx.x;            // (bx*3+by)*6+bz
        const int bx = b / 18;
        const int by = (b / 6) % 3;
        const int bz = b % 6;
        const int lx = slot / 25;
        const int rem = slot % 25;
        const int ly = rem / 5;
        const int lz = rem % 5;
        const int ix = bx * 5 + lx;
        const int iy = by * 5 + ly;
        const int iz = bz * 5 + lz;
        pid = (ix * 15 + iy) * 30 + iz;
    }

    const float DT      = 5e-4f;
    const float INV_DX  = 100.0f;
    const float DXc     = 0.01f;
    const float MU      = (float)(1.0e5 / (2.0 * (1.0 + 0.3)));
    const float LAM     = (float)(1.0e5 * 0.3 / ((1.0 + 0.3) * (1.0 - 0.6)));
    const float P_MASS  = (float)(0.005 * 0.005 * 0.005 * 3000.0);
    const float KS      = (float)(-5.0e-4 * (0.005 * 0.005 * 0.005) * 4.0 * 100.0 * 100.0);
    const float DTG     = (float)(5.0e-4 * (-9.8));
    const float CSC     = 4.0f * INV_DX * INV_DX;   // 40000

    __shared__ float4 tileIn[TCIN];        // normalized grid velocity per cell
    __shared__ float  tileOut[4 * TCOUT];  // scatter accum: [mx,my,mz,mass]
    __shared__ int sred[6];                // bbox reduction

    // ---- init: zero all 3 grid buffers + barrier counter (ws poisoned 0xAA) ----
    // Plain stores leave dirty L2 lines; the gg.sync() below does a full agent
    // release (wbl2), publishing them; thereafter the grid is only ever touched
    // by MALL-coherent ops, so clean-stale L2 copies are never read or evicted
    // dirty.
    {
        const float4 z = make_float4(0.f, 0.f, 0.f, 0.f);
        for (int i = tid; i < 3 * G3; i += nth) g4[i] = z;
        if (tid == 0)
            __hip_atomic_store(barcnt, 0u, __ATOMIC_RELAXED, __HIP_MEMORY_SCOPE_AGENT);
    }

    // ---- particle state, replicated across the 4 lanes of a group ----
    float px = 0.f, py = 0.f, pz = 0.f, vx = 0.f, vy = 0.f, vz = 0.f;
    float C00 = 0.f, C01 = 0.f, C02 = 0.f,
          C10 = 0.f, C11 = 0.f, C12 = 0.f,
          C20 = 0.f, C21 = 0.f, C22 = 0.f;
    float F00 = 1.f, F01 = 0.f, F02 = 0.f,
          F10 = 0.f, F11 = 1.f, F12 = 0.f,
          F20 = 0.f, F21 = 0.f, F22 = 1.f;
    if (act) {
        px = q0[3 * pid + 0]; py = q0[3 * pid + 1]; pz = q0[3 * pid + 2];
        vx = qd0[3 * pid + 0]; vy = qd0[3 * pid + 1]; vz = qd0[3 * pid + 2];
    }

    // per-wg bbox history (uniform across wg): p-1 and p-2 scatter bboxes
    int pmn0 = 0, pmn1 = 0, pmn2 = 0, pmx0 = -1, pmx1 = -1, pmx2 = -1; bool pvalid = false;
    int zmn0 = 0, zmn1 = 0, zmn2 = 0, zmx0 = -1, zmx1 = -1, zmx2 = -1; bool zvalid = false;

    gg.sync();   // publish init (release) before first phase

    unsigned gen = 0;

    for (int p = 0; p < NSUB; ++p) {
        const int bS = p % 3;
        const int bG = (p + 2) % 3;   // (p-1)%3 for p>0
        const int bZ = (p + 1) % 3;   // holds substep p-2 data
        float4*       __restrict__ gS4 = g4 + bS * G3;
        const float4* __restrict__ gG4 = g4 + bG * G3;
        float4*       __restrict__ gZ4 = g4 + bZ * G3;
        const int fc = p % SPF;
        float* const outF = (fc == SPF - 1) ? (out + (p / SPF) * G3) : nullptr;

        // ---- [pre-S1] independent prep work ----
        if (threadIdx.x == 0) {
            sred[0] = INT_MAX; sred[1] = INT_MAX; sred[2] = INT_MAX;
            sred[3] = INT_MIN; sred[4] = INT_MIN; sred[5] = INT_MIN;
        }
        // out-init: spread vs-fill of this frame's out slab over its first 29
        // phases (chunk fc); the frame-end adds happen at phase 30f+29, after
        // the barrier ending phase 30f+28 -> all inits ordered before adds.
        if (fc < SPF - 1) {
            float* of = out + (p / SPF) * G3;
            const int beg = fc * CH;
            const int end = (beg + CH < G3) ? beg + CH : G3;
            for (int i = beg + tid; i < end; i += nth)
                __hip_atomic_store(&of[i], vs, __ATOMIC_RELAXED, __HIP_MEMORY_SCOPE_AGENT);
        }
        // full tileOut zero (position-agnostic; scatter uses only vol <= TCOUT)
        {
            float4* t4 = reinterpret_cast<float4*>(tileOut);
            const float4 z = make_float4(0.f, 0.f, 0.f, 0.f);
            for (int i = threadIdx.x; i < TCOUT; i += NTHR) t4[i] = z;
        }
        // zero substep p-2's per-wg bbox (MALL stores)
        if (zvalid) {
            const int zD1 = zmx1 - zmn1 + 1, zD2 = zmx2 - zmn2 + 1;
            const int zvol = (zmx0 - zmn0 + 1) * zD1 * zD2;
            for (int c = threadIdx.x; c < zvol; c += NTHR) {
                const int k = c % zD2;
                const int t = c / zD2;
                const int j = t % zD1;
                const int i = t / zD1;
                cell_zero(&gZ4[((zmn0 + i) * G + (zmn1 + j)) * G + (zmn2 + k)]);
            }
        }
        // stage gather region (own p-1 scatter bbox) -> tileIn, normalized + BC
        const int iD1 = pvalid ? (pmx1 - pmn1 + 1) : 0;
        const int iD2 = pvalid ? (pmx2 - pmn2 + 1) : 0;
        const int inVol = pvalid ? (pmx0 - pmn0 + 1) * iD1 * iD2 : 0;
        const bool staged = pvalid && (inVol <= TCIN);
        if (staged) {
            for (int c = threadIdx.x; c < inVol; c += NTHR) {
                const int k = c % iD2;
                const int t = c / iD2;
                const int j = t % iD1;
                const int i = t / iD1;
                const int nx = pmn0 + i, ny = pmn1 + j, nz = pmn2 + k;
                const float4 gq = cell_load(&gG4[(nx * G + ny) * G + nz]);
                const float den = gq.w + vs;
                float gvx = gq.x / den;
                float gvy = gq.y / den;
                float gvz = gq.z / den;
                if (nx < 3       && gvx < 0.f) gvx = 0.f;
                if (nx >= G - 3  && gvx > 0.f) gvx = 0.f;
                if (ny < 3       && gvy < 0.f) gvy = 0.f;
                if (ny >= G - 3  && gvy > 0.f) gvy = 0.f;
                if (nz < 3       && gvz < 0.f) gvz = 0.f;
                if (nz >= G - 3  && gvz > 0.f) gvz = 0.f;
                tileIn[c] = make_float4(gvx, gvy, gvz, 0.f);
            }
        }
        __syncthreads();   // S1

        int sb0 = 0, sb1 = 0, sb2 = 0;
        float fx0 = 0.f, fx1 = 0.f, fx2 = 0.f;
        float A00 = 0.f, A01 = 0.f, A02 = 0.f,
              A10 = 0.f, A11 = 0.f, A12 = 0.f,
              A20 = 0.f, A21 = 0.f, A22 = 0.f;
        float mvx = 0.f, mvy = 0.f, mvz = 0.f;

        if (act) {
            // ======== G2P gather for substep p-1 (cells c%4==sub per lane) ========
            if (p > 0) {
                const float xs0 = px * INV_DX, xs1 = py * INV_DX, xs2 = pz * INV_DX;
                const float fb0 = floorf(xs0 - 0.5f), fb1 = floorf(xs1 - 0.5f), fb2 = floorf(xs2 - 0.5f);
                const int b0 = (int)fb0, b1 = (int)fb1, b2 = (int)fb2;
                const float gx0 = xs0 - fb0, gx1 = xs1 - fb1, gx2 = xs2 - fb2;
                float wa[3], wb[3], wc[3];
                wa[0] = 0.5f * (1.5f - gx0) * (1.5f - gx0);
                wa[1] = 0.75f - (gx0 - 1.0f) * (gx0 - 1.0f);
                wa[2] = 0.5f * (gx0 - 0.5f) * (gx0 - 0.5f);
                wb[0] = 0.5f * (1.5f - gx1) * (1.5f - gx1);
                wb[1] = 0.75f - (gx1 - 1.0f) * (gx1 - 1.0f);
                wb[2] = 0.5f * (gx1 - 0.5f) * (gx1 - 0.5f);
                wc[0] = 0.5f * (1.5f - gx2) * (1.5f - gx2);
                wc[1] = 0.75f - (gx2 - 1.0f) * (gx2 - 1.0f);
                wc[2] = 0.5f * (gx2 - 0.5f) * (gx2 - 0.5f);

                float nvx = 0.f, nvy = 0.f, nvz = 0.f;
                float nc00 = 0.f, nc01 = 0.f, nc02 = 0.f,
                      nc10 = 0.f, nc11 = 0.f, nc12 = 0.f,
                      nc20 = 0.f, nc21 = 0.f, nc22 = 0.f;
                #pragma unroll
                for (int t = 0; t < 7; ++t) {
                    const int c = sub + 4 * t;
                    if (c >= 27) break;
                    const int oi = c / 9;
                    const int rem = c - 9 * oi;
                    const int oj = rem / 3;
                    const int ok = rem - 3 * oj;
                    const int nx = clampi(b0 + oi);
                    const int ny = clampi(b1 + oj);
                    const int nz = clampi(b2 + ok);
                    const float dpx = ((float)oi - gx0) * DXc;
                    const float dpy = ((float)oj - gx1) * DXc;
                    const float dpz = ((float)ok - gx2) * DXc;
                    const float w = wa[oi] * wb[oj] * wc[ok];
                    float gvx, gvy, gvz;
                    if (staged) {
                        const float4 gv4 = tileIn[((nx - pmn0) * iD1 + (ny - pmn1)) * iD2 + (nz - pmn2)];
                        gvx = gv4.x; gvy = gv4.y; gvz = gv4.z;
                    } else {
                        const float4 gq = cell_load(&gG4[(nx * G + ny) * G + nz]);
                        const float den = gq.w + vs;
                        gvx = gq.x / den;
                        gvy = gq.y / den;
                        gvz = gq.z / den;
                        if (nx < 3       && gvx < 0.f) gvx = 0.f;
                        if (nx >= G - 3  && gvx > 0.f) gvx = 0.f;
                        if (ny < 3       && gvy < 0.f) gvy = 0.f;
                        if (ny >= G - 3  && gvy > 0.f) gvy = 0.f;
                        if (nz < 3       && gvz < 0.f) gvz = 0.f;
                        if (nz >= G - 3  && gvz > 0.f) gvz = 0.f;
                    }
                    nvx += w * gvx; nvy += w * gvy; nvz += w * gvz;
                    const float wgx = w * gvx, wgy = w * gvy, wgz = w * gvz;
                    nc00 += wgx * dpx; nc01 += wgx * dpy; nc02 += wgx * dpz;
                    nc10 += wgy * dpx; nc11 += wgy * dpy; nc12 += wgy * dpz;
                    nc20 += wgz * dpx; nc21 += wgz * dpy; nc22 += wgz * dpz;
                }
                // 4-lane butterfly: all lanes end with identical full sums
                #define BFLY(v) { v += __shfl_xor(v, 1); v += __shfl_xor(v, 2); }
                BFLY(nvx) BFLY(nvy) BFLY(nvz)
                BFLY(nc00) BFLY(nc01) BFLY(nc02)
                BFLY(nc10) BFLY(nc11) BFLY(nc12)
                BFLY(nc20) BFLY(nc21) BFLY(nc22)
                #undef BFLY
                vx = nvx; vy = nvy; vz = nvz;
                C00 = CSC * nc00; C01 = CSC * nc01; C02 = CSC * nc02;
                C10 = CSC * nc10; C11 = CSC * nc11; C12 = CSC * nc12;
                C20 = CSC * nc20; C21 = CSC * nc21; C22 = CSC * nc22;
                px += DT * vx; py += DT * vy; pz += DT * vz;
            }

            // ======== F update: F = (I + DT*C) @ F (replicated) ========
            {
                const float t00 = F00 + DT * (C00 * F00 + C01 * F10 + C02 * F20);
                const float t01 = F01 + DT * (C00 * F01 + C01 * F11 + C02 * F21);
                const float t02 = F02 + DT * (C00 * F02 + C01 * F12 + C02 * F22);
                const float t10 = F10 + DT * (C10 * F00 + C11 * F10 + C12 * F20);
                const float t11 = F11 + DT * (C10 * F01 + C11 * F11 + C12 * F21);
                const float t12 = F12 + DT * (C10 * F02 + C11 * F12 + C12 * F22);
                const float t20 = F20 + DT * (C20 * F00 + C21 * F10 + C22 * F20);
                const float t21 = F21 + DT * (C20 * F01 + C21 * F11 + C22 * F21);
                const float t22 = F22 + DT * (C20 * F02 + C21 * F12 + C22 * F22);
                F00 = t00; F01 = t01; F02 = t02;
                F10 = t10; F11 = t11; F12 = t12;
                F20 = t20; F21 = t21; F22 = t22;
            }

            // ======== neo-Hookean PK1 stress -> affine (replicated) ========
            const float c00 = F11 * F22 - F12 * F21;
            const float c01 = F12 * F20 - F10 * F22;
            const float c02 = F10 * F21 - F11 * F20;
            const float det = F00 * c00 + F01 * c01 + F02 * c02;
            const float c10 = F02 * F21 - F01 * F22;
            const float c11 = F00 * F22 - F02 * F20;
            const float c12 = F01 * F20 - F00 * F21;
            const float c20 = F01 * F12 - F02 * F11;
            const float c21 = F02 * F10 - F00 * F12;
            const float c22 = F00 * F11 - F01 * F10;
            const float idet = 1.0f / det;
            const float lj = LAM * logf(fmaxf(det, 1e-6f));
            const float fit00 = c00 * idet, fit01 = c01 * idet, fit02 = c02 * idet;
            const float fit10 = c10 * idet, fit11 = c11 * idet, fit12 = c12 * idet;
            const float fit20 = c20 * idet, fit21 = c21 * idet, fit22 = c22 * idet;
            const float P00 = MU * (F00 - fit00) + lj * fit00;
            const float P01 = MU * (F01 - fit01) + lj * fit01;
            const float P02 = MU * (F02 - fit02) + lj * fit02;
            const float P10 = MU * (F10 - fit10) + lj * fit10;
            const float P11 = MU * (F11 - fit11) + lj * fit11;
            const float P12 = MU * (F12 - fit12) + lj * fit12;
            const float P20 = MU * (F20 - fit20) + lj * fit20;
            const float P21 = MU * (F21 - fit21) + lj * fit21;
            const float P22 = MU * (F22 - fit22) + lj * fit22;
            A00 = KS * (P00 * F00 + P01 * F01 + P02 * F02) + P_MASS * C00;
            A01 = KS * (P00 * F10 + P01 * F11 + P02 * F12) + P_MASS * C01;
            A02 = KS * (P00 * F20 + P01 * F21 + P02 * F22) + P_MASS * C02;
            A10 = KS * (P10 * F00 + P11 * F01 + P12 * F02) + P_MASS * C10;
            A11 = KS * (P10 * F10 + P11 * F11 + P12 * F12) + P_MASS * C11;
            A12 = KS * (P10 * F20 + P11 * F21 + P12 * F22) + P_MASS * C12;
            A20 = KS * (P20 * F00 + P21 * F01 + P22 * F02) + P_MASS * C20;
            A21 = KS * (P20 * F10 + P21 * F11 + P22 * F12) + P_MASS * C21;
            A22 = KS * (P20 * F20 + P21 * F21 + P22 * F22) + P_MASS * C22;

            // scatter base (from updated x)
            const float xs0 = px * INV_DX, xs1 = py * INV_DX, xs2 = pz * INV_DX;
            const float fb0 = floorf(xs0 - 0.5f), fb1 = floorf(xs1 - 0.5f), fb2 = floorf(xs2 - 0.5f);
            sb0 = (int)fb0; sb1 = (int)fb1; sb2 = (int)fb2;
            fx0 = xs0 - fb0; fx1 = xs1 - fb1; fx2 = xs2 - fb2;
            mvx = P_MASS * vx;
            mvy = P_MASS * (vy + DTG);
            mvz = P_MASS * vz;

            if (sub == 0) {
                atomicMin(&sred[0], clampi(sb0)); atomicMax(&sred[3], clampi(sb0 + 2));
                atomicMin(&sred[1], clampi(sb1)); atomicMax(&sred[4], clampi(sb1 + 2));
                atomicMin(&sred[2], clampi(sb2)); atomicMax(&sred[5], clampi(sb2 + 2));
            }
        }
        __syncthreads();   // S2: bbox ready, tileOut zeroed since S1

        const int mn0 = sred[0], mn1 = sred[1], mn2 = sred[2];
        const int mx0 = sred[3], mx1 = sred[4], mx2 = sred[5];
        const bool anyAct = (mx0 >= mn0);
        const int D1 = mx1 - mn1 + 1, D2 = mx2 - mn2 + 1;
        const int vol = anyAct ? (mx0 - mn0 + 1) * D1 * D2 : 0;
        const bool useLDS = anyAct && (vol <= TCOUT);

        // weights for scatter (replicated per lane group)
        float wa0 = 0.f, wa1 = 0.f, wa2 = 0.f, wb0 = 0.f, wb1 = 0.f, wb2 = 0.f,
              wcc0 = 0.f, wcc1 = 0.f, wcc2 = 0.f;
        if (act) {
            wa0 = 0.5f * (1.5f - fx0) * (1.5f - fx0);
            wa1 = 0.75f - (fx0 - 1.0f) * (fx0 - 1.0f);
            wa2 = 0.5f * (fx0 - 0.5f) * (fx0 - 0.5f);
            wb0 = 0.5f * (1.5f - fx1) * (1.5f - fx1);
            wb1 = 0.75f - (fx1 - 1.0f) * (fx1 - 1.0f);
            wb2 = 0.5f * (fx1 - 0.5f) * (fx1 - 0.5f);
            wcc0 = 0.5f * (1.5f - fx2) * (1.5f - fx2);
            wcc1 = 0.75f - (fx2 - 1.0f) * (fx2 - 1.0f);
            wcc2 = 0.5f * (fx2 - 0.5f) * (fx2 - 0.5f);
        }
        const float WA[3] = { wa0, wa1, wa2 };
        const float WB[3] = { wb0, wb1, wb2 };
        const float WC[3] = { wcc0, wcc1, wcc2 };

        if (useLDS) {
            if (act) {
                #pragma unroll
                for (int t = 0; t < 7; ++t) {
                    const int c = sub + 4 * t;
                    if (c >= 27) break;
                    const int oi = c / 9;
                    const int rem = c - 9 * oi;
                    const int oj = rem / 3;
                    const int ok = rem - 3 * oj;
                    const int li  = clampi(sb0 + oi) - mn0;
                    const int lj2 = clampi(sb1 + oj) - mn1;
                    const int lk  = clampi(sb2 + ok) - mn2;
                    const float dpx = ((float)oi - fx0) * DXc;
                    const float dpy = ((float)oj - fx1) * DXc;
                    const float dpz = ((float)ok - fx2) * DXc;
                    const float w = WA[oi] * WB[oj] * WC[ok];
                    const int c4 = 4 * ((li * D1 + lj2) * D2 + lk);
                    atomicAdd(&tileOut[c4 + 0], w * (mvx + A00 * dpx + A01 * dpy + A02 * dpz));
                    atomicAdd(&tileOut[c4 + 1], w * (mvy + A10 * dpx + A11 * dpy + A12 * dpz));
                    atomicAdd(&tileOut[c4 + 2], w * (mvz + A20 * dpx + A21 * dpy + A22 * dpz));
                    atomicAdd(&tileOut[c4 + 3], w * P_MASS);
                }
            }
            __syncthreads();   // S3
            // flush tile -> grid (agent atomics); frame-end: also add mass to out
            for (int c = threadIdx.x; c < vol; c += NTHR) {
                const float m = tileOut[4 * c + 3];
                if (m != 0.f) {
                    const int k = c % D2;
                    const int t = c / D2;
                    const int j = t % D1;
                    const int i = t / D1;
                    const int gidx = ((mn0 + i) * G + (mn1 + j)) * G + (mn2 + k);
                    float* gp = reinterpret_cast<float*>(gS4 + gidx);
                    unsafeAtomicAdd(gp + 0, tileOut[4 * c + 0]);
                    unsafeAtomicAdd(gp + 1, tileOut[4 * c + 1]);
                    unsafeAtomicAdd(gp + 2, tileOut[4 * c + 2]);
                    unsafeAtomicAdd(gp + 3, m);
                    if (outF) unsafeAtomicAdd(&outF[gidx], m);
                }
            }
        } else {
            if (anyAct && act) {
                // fallback: direct global atomics (bbox too large)
                #pragma unroll
                for (int t = 0; t < 7; ++t) {
                    const int c = sub + 4 * t;
                    if (c >= 27) break;
                    const int oi = c / 9;
                    const int rem = c - 9 * oi;
                    const int oj = rem / 3;
                    const int ok = rem - 3 * oj;
                    const int nx = clampi(sb0 + oi);
                    const int ny = clampi(sb1 + oj);
                    const int nz = clampi(sb2 + ok);
                    const float dpx = ((float)oi - fx0) * DXc;
                    const float dpy = ((float)oj - fx1) * DXc;
                    const float dpz = ((float)ok - fx2) * DXc;
                    const float w = WA[oi] * WB[oj] * WC[ok];
                    const int gidx = (nx * G + ny) * G + nz;
                    float* gp = reinterpret_cast<float*>(gS4 + gidx);
                    unsafeAtomicAdd(gp + 0, w * (mvx + A00 * dpx + A01 * dpy + A02 * dpz));
                    unsafeAtomicAdd(gp + 1, w * (mvy + A10 * dpx + A11 * dpy + A12 * dpz));
                    unsafeAtomicAdd(gp + 2, w * (mvz + A20 * dpx + A21 * dpy + A22 * dpz));
                    unsafeAtomicAdd(gp + 3, w * P_MASS);
                    if (outF) unsafeAtomicAdd(&outF[gidx], w * P_MASS);
                }
            }
            __syncthreads();   // S3 (keep sync count uniform)
        }

        // shift bbox history
        zmn0 = pmn0; zmn1 = pmn1; zmn2 = pmn2;
        zmx0 = pmx0; zmx1 = pmx1; zmx2 = pmx2; zvalid = pvalid;
        pmn0 = mn0; pmn1 = mn1; pmn2 = mn2;
        pmx0 = mx0; pmx1 = mx1; pmx2 = mx2; pvalid = anyAct;

        if (p < NSUB - 1) gridbar(barcnt, ++gen);
        // last phase: kernel-end implicit release publishes the final out adds
    }
}

extern "C" void kernel_launch(void* const* d_in, const int* in_sizes, int n_in,
                              void* d_out, int out_size, void* d_ws, size_t ws_size,
                              hipStream_t stream) {
    const float* v  = (const float*)d_in[0];
    const float* q  = (const float*)d_in[1];
    const float* qd = (const float*)d_in[2];
    float* out = (float*)d_out;
    float* ws  = (float*)d_ws;
    // barrier counter at the tail of the workspace (grid buffers use the head)
    unsigned* barcnt = reinterpret_cast<unsigned*>((char*)d_ws + (ws_size & ~(size_t)15) - 16);
    void* args[] = { (void*)&v, (void*)&q, (void*)&qd, (void*)&out, (void*)&ws, (void*)&barcnt };
    hipLaunchCooperativeKernel(reinterpret_cast<void*>(mpm_sim),
                               dim3(NBLK), dim3(NTHR), args, 0, stream);
}

// Round 9
// 17743.411 us; speedup vs baseline: 4.6691x; 1.0234x over previous
//
#include <hip/hip_runtime.h>
#include <hip/hip_cooperative_groups.h>

namespace cg = cooperative_groups;

static constexpr int G    = 100;
static constexpr int G3   = G * G * G;
static constexpr int NP   = 13500;   // 30*15*30 particles
static constexpr int NSUB = 600;     // 20 frames x 30 substeps
static constexpr int SPF  = 30;      // substeps per frame
static constexpr int NTHR = 512;     // 8 waves/block
static constexpr int NBLK = 108;     // 6x3x6 bricks of 5x5x5 particles
static constexpr int TCIN  = 2048;   // LDS IN-tile capacity (float4/cell = 32 KB)
static constexpr int TCOUT = 2048;   // LDS OUT-tile capacity (4 floats/cell = 32 KB)
static constexpr int CH   = (G3 + SPF - 2) / (SPF - 1);  // out-init chunk (34483)

__device__ __forceinline__ int clampi(int v) {
    return v < 0 ? 0 : (v > G - 1 ? G - 1 : v);
}

// MALL-coherent (agent-scope, relaxed) helpers. ALL grid traffic goes through
// these or agent-scope atomics, so the grid is never cached dirty in any L2 ->
// the grid barrier needs NO cache maintenance.
__device__ __forceinline__ float4 cell_load(const float4* p) {
    const unsigned long long* q = reinterpret_cast<const unsigned long long*>(p);
    unsigned long long a = __hip_atomic_load(&q[0], __ATOMIC_RELAXED, __HIP_MEMORY_SCOPE_AGENT);
    unsigned long long b = __hip_atomic_load(&q[1], __ATOMIC_RELAXED, __HIP_MEMORY_SCOPE_AGENT);
    float4 r;
    r.x = __uint_as_float((unsigned)(a & 0xffffffffu));
    r.y = __uint_as_float((unsigned)(a >> 32));
    r.z = __uint_as_float((unsigned)(b & 0xffffffffu));
    r.w = __uint_as_float((unsigned)(b >> 32));
    return r;
}
__device__ __forceinline__ void cell_zero(float4* p) {
    unsigned long long* q = reinterpret_cast<unsigned long long*>(p);
    __hip_atomic_store(&q[0], 0ull, __ATOMIC_RELAXED, __HIP_MEMORY_SCOPE_AGENT);
    __hip_atomic_store(&q[1], 0ull, __ATOMIC_RELAXED, __HIP_MEMORY_SCOPE_AGENT);
}

// Split arrive/broadcast grid barrier.
// Arrivals fetch_add line A (cnt); pollers spin-read ONLY line B (flag, 256B
// away) so the polling load stream never contests ownership of the arrival
// line (the R4-R8 ~25us/phase pathology). Last arriver (old == gen*NBLK-1)
// release-stores gen to the flag. __syncthreads() before arrival drains vmcnt,
// so all MALL-bound ops of the block are complete at the single coherence
// point before the add; pollers' post-spin accesses are issued strictly later.
__device__ __forceinline__ void gridbar(unsigned* __restrict__ cnt,
                                        unsigned* __restrict__ flag,
                                        unsigned gen) {
    __syncthreads();
    if (threadIdx.x == 0) {
        const unsigned old = __hip_atomic_fetch_add(cnt, 1u, __ATOMIC_RELAXED, __HIP_MEMORY_SCOPE_AGENT);
        if (old == gen * (unsigned)NBLK - 1u) {
            __hip_atomic_store(flag, gen, __ATOMIC_RELEASE, __HIP_MEMORY_SCOPE_AGENT);
        } else {
            while (__hip_atomic_load(flag, __ATOMIC_RELAXED, __HIP_MEMORY_SCOPE_AGENT) < gen) {
                __builtin_amdgcn_s_sleep(2);
            }
        }
    }
    __syncthreads();
}

// Persistent cooperative kernel, triple-buffered float4 grid in ws:
//   g4[buf*G3 + idx] = (mom.x, mom.y, mom.z, mass)
// Phase p: [pre-S1] out-init chunk + sred init + tileOut zero + zero p-2 bbox
// (MALL) + stage gather region into tileIn (normalized + BC once per cell);
// [S1] G2P from LDS, F/stress/affine, bbox atomics; [S2] scatter into tileOut
// (LDS atomics); [S3] flush -> grid (agent atomics), frame-end also adds mass
// into out (pre-filled with vs). One split-line grid barrier per phase.
__launch_bounds__(NTHR)
__global__ void mpm_sim(const float* __restrict__ vscal,
                        const float* __restrict__ q0,
                        const float* __restrict__ qd0,
                        float* __restrict__ out,
                        float* __restrict__ ws,
                        unsigned* __restrict__ barcnt,
                        unsigned* __restrict__ barflag)
{
    const float vs = vscal[0];
    float4* const g4 = reinterpret_cast<float4*>(ws);

    cg::grid_group gg = cg::this_grid();
    const int tid = blockIdx.x * NTHR + threadIdx.x;
    const int nth = NBLK * NTHR;

    // brick/slot -> original particle index (4 lanes per particle)
    const int slot = threadIdx.x >> 2;        // 0..127
    const int sub  = threadIdx.x & 3;         // lane within particle group
    const bool act = slot < 125;
    int pid = 0;
    if (act) {
        const int b  = blockIdx.x;            // (bx*3+by)*6+bz
        const int bx = b / 18;
        const int by = (b / 6) % 3;
        const int bz = b % 6;
        const int lx = slot / 25;
        const int rem = slot % 25;
        const int ly = rem / 5;
        const int lz = rem % 5;
        const int ix = bx * 5 + lx;
        const int iy = by * 5 + ly;
        const int iz = bz * 5 + lz;
        pid = (ix * 15 + iy) * 30 + iz;
    }

    const float DT      = 5e-4f;
    const float INV_DX  = 100.0f;
    const float DXc     = 0.01f;
    const float MU      = (float)(1.0e5 / (2.0 * (1.0 + 0.3)));
    const float LAM     = (float)(1.0e5 * 0.3 / ((1.0 + 0.3) * (1.0 - 0.6)));
    const float P_MASS  = (float)(0.005 * 0.005 * 0.005 * 3000.0);
    const float KS      = (float)(-5.0e-4 * (0.005 * 0.005 * 0.005) * 4.0 * 100.0 * 100.0);
    const float DTG     = (float)(5.0e-4 * (-9.8));
    const float CSC     = 4.0f * INV_DX * INV_DX;   // 40000

    __shared__ float4 tileIn[TCIN];        // normalized grid velocity per cell
    __shared__ float  tileOut[4 * TCOUT];  // scatter accum: [mx,my,mz,mass]
    __shared__ int sred[6];                // bbox reduction

    // ---- init: zero all 3 grid buffers + barrier lines (ws poisoned 0xAA) ----
    {
        const float4 z = make_float4(0.f, 0.f, 0.f, 0.f);
        for (int i = tid; i < 3 * G3; i += nth) g4[i] = z;
        if (tid == 0) {
            __hip_atomic_store(barcnt,  0u, __ATOMIC_RELAXED, __HIP_MEMORY_SCOPE_AGENT);
            __hip_atomic_store(barflag, 0u, __ATOMIC_RELAXED, __HIP_MEMORY_SCOPE_AGENT);
        }
    }

    // ---- particle state, replicated across the 4 lanes of a group ----
    float px = 0.f, py = 0.f, pz = 0.f, vx = 0.f, vy = 0.f, vz = 0.f;
    float C00 = 0.f, C01 = 0.f, C02 = 0.f,
          C10 = 0.f, C11 = 0.f, C12 = 0.f,
          C20 = 0.f, C21 = 0.f, C22 = 0.f;
    float F00 = 1.f, F01 = 0.f, F02 = 0.f,
          F10 = 0.f, F11 = 1.f, F12 = 0.f,
          F20 = 0.f, F21 = 0.f, F22 = 1.f;
    if (act) {
        px = q0[3 * pid + 0]; py = q0[3 * pid + 1]; pz = q0[3 * pid + 2];
        vx = qd0[3 * pid + 0]; vy = qd0[3 * pid + 1]; vz = qd0[3 * pid + 2];
    }

    // per-wg bbox history (uniform across wg): p-1 and p-2 scatter bboxes
    int pmn0 = 0, pmn1 = 0, pmn2 = 0, pmx0 = -1, pmx1 = -1, pmx2 = -1; bool pvalid = false;
    int zmn0 = 0, zmn1 = 0, zmn2 = 0, zmx0 = -1, zmx1 = -1, zmx2 = -1; bool zvalid = false;

    gg.sync();   // publish init (release) before first phase

    unsigned gen = 0;

    for (int p = 0; p < NSUB; ++p) {
        const int bS = p % 3;
        const int bG = (p + 2) % 3;   // (p-1)%3 for p>0
        const int bZ = (p + 1) % 3;   // holds substep p-2 data
        float4*       __restrict__ gS4 = g4 + bS * G3;
        const float4* __restrict__ gG4 = g4 + bG * G3;
        float4*       __restrict__ gZ4 = g4 + bZ * G3;
        const int fc = p % SPF;
        float* const outF = (fc == SPF - 1) ? (out + (p / SPF) * G3) : nullptr;

        // ---- [pre-S1] independent prep work ----
        if (threadIdx.x == 0) {
            sred[0] = INT_MAX; sred[1] = INT_MAX; sred[2] = INT_MAX;
            sred[3] = INT_MIN; sred[4] = INT_MIN; sred[5] = INT_MIN;
        }
        // out-init: spread vs-fill of this frame's out slab over its first 29
        // phases; the frame-end adds happen at phase 30f+29, after the barrier
        // ending phase 30f+28 -> all inits ordered before adds.
        if (fc < SPF - 1) {
            float* of = out + (p / SPF) * G3;
            const int beg = fc * CH;
            const int end = (beg + CH < G3) ? beg + CH : G3;
            for (int i = beg + tid; i < end; i += nth)
                __hip_atomic_store(&of[i], vs, __ATOMIC_RELAXED, __HIP_MEMORY_SCOPE_AGENT);
        }
        // full tileOut zero (position-agnostic; scatter uses only vol <= TCOUT)
        {
            float4* t4 = reinterpret_cast<float4*>(tileOut);
            const float4 z = make_float4(0.f, 0.f, 0.f, 0.f);
            for (int i = threadIdx.x; i < TCOUT; i += NTHR) t4[i] = z;
        }
        // zero substep p-2's per-wg bbox (MALL stores)
        if (zvalid) {
            const int zD1 = zmx1 - zmn1 + 1, zD2 = zmx2 - zmn2 + 1;
            const int zvol = (zmx0 - zmn0 + 1) * zD1 * zD2;
            for (int c = threadIdx.x; c < zvol; c += NTHR) {
                const int k = c % zD2;
                const int t = c / zD2;
                const int j = t % zD1;
                const int i = t / zD1;
                cell_zero(&gZ4[((zmn0 + i) * G + (zmn1 + j)) * G + (zmn2 + k)]);
            }
        }
        // stage gather region (own p-1 scatter bbox) -> tileIn, normalized + BC
        const int iD1 = pvalid ? (pmx1 - pmn1 + 1) : 0;
        const int iD2 = pvalid ? (pmx2 - pmn2 + 1) : 0;
        const int inVol = pvalid ? (pmx0 - pmn0 + 1) * iD1 * iD2 : 0;
        const bool staged = pvalid && (inVol <= TCIN);
        if (staged) {
            for (int c = threadIdx.x; c < inVol; c += NTHR) {
                const int k = c % iD2;
                const int t = c / iD2;
                const int j = t % iD1;
                const int i = t / iD1;
                const int nx = pmn0 + i, ny = pmn1 + j, nz = pmn2 + k;
                const float4 gq = cell_load(&gG4[(nx * G + ny) * G + nz]);
                const float den = gq.w + vs;
                float gvx = gq.x / den;
                float gvy = gq.y / den;
                float gvz = gq.z / den;
                if (nx < 3       && gvx < 0.f) gvx = 0.f;
                if (nx >= G - 3  && gvx > 0.f) gvx = 0.f;
                if (ny < 3       && gvy < 0.f) gvy = 0.f;
                if (ny >= G - 3  && gvy > 0.f) gvy = 0.f;
                if (nz < 3       && gvz < 0.f) gvz = 0.f;
                if (nz >= G - 3  && gvz > 0.f) gvz = 0.f;
                tileIn[c] = make_float4(gvx, gvy, gvz, 0.f);
            }
        }
        __syncthreads();   // S1

        int sb0 = 0, sb1 = 0, sb2 = 0;
        float fx0 = 0.f, fx1 = 0.f, fx2 = 0.f;
        float A00 = 0.f, A01 = 0.f, A02 = 0.f,
              A10 = 0.f, A11 = 0.f, A12 = 0.f,
              A20 = 0.f, A21 = 0.f, A22 = 0.f;
        float mvx = 0.f, mvy = 0.f, mvz = 0.f;

        if (act) {
            // ======== G2P gather for substep p-1 (cells c%4==sub per lane) ========
            if (p > 0) {
                const float xs0 = px * INV_DX, xs1 = py * INV_DX, xs2 = pz * INV_DX;
                const float fb0 = floorf(xs0 - 0.5f), fb1 = floorf(xs1 - 0.5f), fb2 = floorf(xs2 - 0.5f);
                const int b0 = (int)fb0, b1 = (int)fb1, b2 = (int)fb2;
                const float gx0 = xs0 - fb0, gx1 = xs1 - fb1, gx2 = xs2 - fb2;
                float wa[3], wb[3], wc[3];
                wa[0] = 0.5f * (1.5f - gx0) * (1.5f - gx0);
                wa[1] = 0.75f - (gx0 - 1.0f) * (gx0 - 1.0f);
                wa[2] = 0.5f * (gx0 - 0.5f) * (gx0 - 0.5f);
                wb[0] = 0.5f * (1.5f - gx1) * (1.5f - gx1);
                wb[1] = 0.75f - (gx1 - 1.0f) * (gx1 - 1.0f);
                wb[2] = 0.5f * (gx1 - 0.5f) * (gx1 - 0.5f);
                wc[0] = 0.5f * (1.5f - gx2) * (1.5f - gx2);
                wc[1] = 0.75f - (gx2 - 1.0f) * (gx2 - 1.0f);
                wc[2] = 0.5f * (gx2 - 0.5f) * (gx2 - 0.5f);

                float nvx = 0.f, nvy = 0.f, nvz = 0.f;
                float nc00 = 0.f, nc01 = 0.f, nc02 = 0.f,
                      nc10 = 0.f, nc11 = 0.f, nc12 = 0.f,
                      nc20 = 0.f, nc21 = 0.f, nc22 = 0.f;
                #pragma unroll
                for (int t = 0; t < 7; ++t) {
                    const int c = sub + 4 * t;
                    if (c >= 27) break;
                    const int oi = c / 9;
                    const int rem = c - 9 * oi;
                    const int oj = rem / 3;
                    const int ok = rem - 3 * oj;
                    const int nx = clampi(b0 + oi);
                    const int ny = clampi(b1 + oj);
                    const int nz = clampi(b2 + ok);
                    const float dpx = ((float)oi - gx0) * DXc;
                    const float dpy = ((float)oj - gx1) * DXc;
                    const float dpz = ((float)ok - gx2) * DXc;
                    const float w = wa[oi] * wb[oj] * wc[ok];
                    float gvx, gvy, gvz;
                    if (staged) {
                        const float4 gv4 = tileIn[((nx - pmn0) * iD1 + (ny - pmn1)) * iD2 + (nz - pmn2)];
                        gvx = gv4.x; gvy = gv4.y; gvz = gv4.z;
                    } else {
                        const float4 gq = cell_load(&gG4[(nx * G + ny) * G + nz]);
                        const float den = gq.w + vs;
                        gvx = gq.x / den;
                        gvy = gq.y / den;
                        gvz = gq.z / den;
                        if (nx < 3       && gvx < 0.f) gvx = 0.f;
                        if (nx >= G - 3  && gvx > 0.f) gvx = 0.f;
                        if (ny < 3       && gvy < 0.f) gvy = 0.f;
                        if (ny >= G - 3  && gvy > 0.f) gvy = 0.f;
                        if (nz < 3       && gvz < 0.f) gvz = 0.f;
                        if (nz >= G - 3  && gvz > 0.f) gvz = 0.f;
                    }
                    nvx += w * gvx; nvy += w * gvy; nvz += w * gvz;
                    const float wgx = w * gvx, wgy = w * gvy, wgz = w * gvz;
                    nc00 += wgx * dpx; nc01 += wgx * dpy; nc02 += wgx * dpz;
                    nc10 += wgy * dpx; nc11 += wgy * dpy; nc12 += wgy * dpz;
                    nc20 += wgz * dpx; nc21 += wgz * dpy; nc22 += wgz * dpz;
                }
                // 4-lane butterfly: all lanes end with identical full sums
                #define BFLY(v) { v += __shfl_xor(v, 1); v += __shfl_xor(v, 2); }
                BFLY(nvx) BFLY(nvy) BFLY(nvz)
                BFLY(nc00) BFLY(nc01) BFLY(nc02)
                BFLY(nc10) BFLY(nc11) BFLY(nc12)
                BFLY(nc20) BFLY(nc21) BFLY(nc22)
                #undef BFLY
                vx = nvx; vy = nvy; vz = nvz;
                C00 = CSC * nc00; C01 = CSC * nc01; C02 = CSC * nc02;
                C10 = CSC * nc10; C11 = CSC * nc11; C12 = CSC * nc12;
                C20 = CSC * nc20; C21 = CSC * nc21; C22 = CSC * nc22;
                px += DT * vx; py += DT * vy; pz += DT * vz;
            }

            // ======== F update: F = (I + DT*C) @ F (replicated) ========
            {
                const float t00 = F00 + DT * (C00 * F00 + C01 * F10 + C02 * F20);
                const float t01 = F01 + DT * (C00 * F01 + C01 * F11 + C02 * F21);
                const float t02 = F02 + DT * (C00 * F02 + C01 * F12 + C02 * F22);
                const float t10 = F10 + DT * (C10 * F00 + C11 * F10 + C12 * F20);
                const float t11 = F11 + DT * (C10 * F01 + C11 * F11 + C12 * F21);
                const float t12 = F12 + DT * (C10 * F02 + C11 * F12 + C12 * F22);
                const float t20 = F20 + DT * (C20 * F00 + C21 * F10 + C22 * F20);
                const float t21 = F21 + DT * (C20 * F01 + C21 * F11 + C22 * F21);
                const float t22 = F22 + DT * (C20 * F02 + C21 * F12 + C22 * F22);
                F00 = t00; F01 = t01; F02 = t02;
                F10 = t10; F11 = t11; F12 = t12;
                F20 = t20; F21 = t21; F22 = t22;
            }

            // ======== neo-Hookean PK1 stress -> affine (replicated) ========
            const float c00 = F11 * F22 - F12 * F21;
            const float c01 = F12 * F20 - F10 * F22;
            const float c02 = F10 * F21 - F11 * F20;
            const float det = F00 * c00 + F01 * c01 + F02 * c02;
            const float c10 = F02 * F21 - F01 * F22;
            const float c11 = F00 * F22 - F02 * F20;
            const float c12 = F01 * F20 - F00 * F21;
            const float c20 = F01 * F12 - F02 * F11;
            const float c21 = F02 * F10 - F00 * F12;
            const float c22 = F00 * F11 - F01 * F10;
            const float idet = 1.0f / det;
            const float lj = LAM * logf(fmaxf(det, 1e-6f));
            const float fit00 = c00 * idet, fit01 = c01 * idet, fit02 = c02 * idet;
            const float fit10 = c10 * idet, fit11 = c11 * idet, fit12 = c12 * idet;
            const float fit20 = c20 * idet, fit21 = c21 * idet, fit22 = c22 * idet;
            const float P00 = MU * (F00 - fit00) + lj * fit00;
            const float P01 = MU * (F01 - fit01) + lj * fit01;
            const float P02 = MU * (F02 - fit02) + lj * fit02;
            const float P10 = MU * (F10 - fit10) + lj * fit10;
            const float P11 = MU * (F11 - fit11) + lj * fit11;
            const float P12 = MU * (F12 - fit12) + lj * fit12;
            const float P20 = MU * (F20 - fit20) + lj * fit20;
            const float P21 = MU * (F21 - fit21) + lj * fit21;
            const float P22 = MU * (F22 - fit22) + lj * fit22;
            A00 = KS * (P00 * F00 + P01 * F01 + P02 * F02) + P_MASS * C00;
            A01 = KS * (P00 * F10 + P01 * F11 + P02 * F12) + P_MASS * C01;
            A02 = KS * (P00 * F20 + P01 * F21 + P02 * F22) + P_MASS * C02;
            A10 = KS * (P10 * F00 + P11 * F01 + P12 * F02) + P_MASS * C10;
            A11 = KS * (P10 * F10 + P11 * F11 + P12 * F12) + P_MASS * C11;
            A12 = KS * (P10 * F20 + P11 * F21 + P12 * F22) + P_MASS * C12;
            A20 = KS * (P20 * F00 + P21 * F01 + P22 * F02) + P_MASS * C20;
            A21 = KS * (P20 * F10 + P21 * F11 + P22 * F12) + P_MASS * C21;
            A22 = KS * (P20 * F20 + P21 * F21 + P22 * F22) + P_MASS * C22;

            // scatter base (from updated x)
            const float xs0 = px * INV_DX, xs1 = py * INV_DX, xs2 = pz * INV_DX;
            const float fb0 = floorf(xs0 - 0.5f), fb1 = floorf(xs1 - 0.5f), fb2 = floorf(xs2 - 0.5f);
            sb0 = (int)fb0; sb1 = (int)fb1; sb2 = (int)fb2;
            fx0 = xs0 - fb0; fx1 = xs1 - fb1; fx2 = xs2 - fb2;
            mvx = P_MASS * vx;
            mvy = P_MASS * (vy + DTG);
            mvz = P_MASS * vz;

            if (sub == 0) {
                atomicMin(&sred[0], clampi(sb0)); atomicMax(&sred[3], clampi(sb0 + 2));
                atomicMin(&sred[1], clampi(sb1)); atomicMax(&sred[4], clampi(sb1 + 2));
                atomicMin(&sred[2], clampi(sb2)); atomicMax(&sred[5], clampi(sb2 + 2));
            }
        }
        __syncthreads();   // S2: bbox ready, tileOut zeroed since S1

        const int mn0 = sred[0], mn1 = sred[1], mn2 = sred[2];
        const int mx0 = sred[3], mx1 = sred[4], mx2 = sred[5];
        const bool anyAct = (mx0 >= mn0);
        const int D1 = mx1 - mn1 + 1, D2 = mx2 - mn2 + 1;
        const int vol = anyAct ? (mx0 - mn0 + 1) * D1 * D2 : 0;
        const bool useLDS = anyAct && (vol <= TCOUT);

        // weights for scatter (replicated per lane group)
        float wa0 = 0.f, wa1 = 0.f, wa2 = 0.f, wb0 = 0.f, wb1 = 0.f, wb2 = 0.f,
              wcc0 = 0.f, wcc1 = 0.f, wcc2 = 0.f;
        if (act) {
            wa0 = 0.5f * (1.5f - fx0) * (1.5f - fx0);
            wa1 = 0.75f - (fx0 - 1.0f) * (fx0 - 1.0f);
            wa2 = 0.5f * (fx0 - 0.5f) * (fx0 - 0.5f);
            wb0 = 0.5f * (1.5f - fx1) * (1.5f - fx1);
            wb1 = 0.75f - (fx1 - 1.0f) * (fx1 - 1.0f);
            wb2 = 0.5f * (fx1 - 0.5f) * (fx1 - 0.5f);
            wcc0 = 0.5f * (1.5f - fx2) * (1.5f - fx2);
            wcc1 = 0.75f - (fx2 - 1.0f) * (fx2 - 1.0f);
            wcc2 = 0.5f * (fx2 - 0.5f) * (fx2 - 0.5f);
        }
        const float WA[3] = { wa0, wa1, wa2 };
        const float WB[3] = { wb0, wb1, wb2 };
        const float WC[3] = { wcc0, wcc1, wcc2 };

        if (useLDS) {
            if (act) {
                #pragma unroll
                for (int t = 0; t < 7; ++t) {
                    const int c = sub + 4 * t;
                    if (c >= 27) break;
                    const int oi = c / 9;
                    const int rem = c - 9 * oi;
                    const int oj = rem / 3;
                    const int ok = rem - 3 * oj;
                    const int li  = clampi(sb0 + oi) - mn0;
                    const int lj2 = clampi(sb1 + oj) - mn1;
                    const int lk  = clampi(sb2 + ok) - mn2;
                    const float dpx = ((float)oi - fx0) * DXc;
                    const float dpy = ((float)oj - fx1) * DXc;
                    const float dpz = ((float)ok - fx2) * DXc;
                    const float w = WA[oi] * WB[oj] * WC[ok];
                    const int c4 = 4 * ((li * D1 + lj2) * D2 + lk);
                    atomicAdd(&tileOut[c4 + 0], w * (mvx + A00 * dpx + A01 * dpy + A02 * dpz));
                    atomicAdd(&tileOut[c4 + 1], w * (mvy + A10 * dpx + A11 * dpy + A12 * dpz));
                    atomicAdd(&tileOut[c4 + 2], w * (mvz + A20 * dpx + A21 * dpy + A22 * dpz));
                    atomicAdd(&tileOut[c4 + 3], w * P_MASS);
                }
            }
            __syncthreads();   // S3
            // flush tile -> grid (agent atomics); frame-end: also add mass to out
            for (int c = threadIdx.x; c < vol; c += NTHR) {
                const float m = tileOut[4 * c + 3];
                if (m != 0.f) {
                    const int k = c % D2;
                    const int t = c / D2;
                    const int j = t % D1;
                    const int i = t / D1;
                    const int gidx = ((mn0 + i) * G + (mn1 + j)) * G + (mn2 + k);
                    float* gp = reinterpret_cast<float*>(gS4 + gidx);
                    unsafeAtomicAdd(gp + 0, tileOut[4 * c + 0]);
                    unsafeAtomicAdd(gp + 1, tileOut[4 * c + 1]);
                    unsafeAtomicAdd(gp + 2, tileOut[4 * c + 2]);
                    unsafeAtomicAdd(gp + 3, m);
                    if (outF) unsafeAtomicAdd(&outF[gidx], m);
                }
            }
        } else {
            if (anyAct && act) {
                // fallback: direct global atomics (bbox too large)
                #pragma unroll
                for (int t = 0; t < 7; ++t) {
                    const int c = sub + 4 * t;
                    if (c >= 27) break;
                    const int oi = c / 9;
                    const int rem = c - 9 * oi;
                    const int oj = rem / 3;
                    const int ok = rem - 3 * oj;
                    const int nx = clampi(sb0 + oi);
                    const int ny = clampi(sb1 + oj);
                    const int nz = clampi(sb2 + ok);
                    const float dpx = ((float)oi - fx0) * DXc;
                    const float dpy = ((float)oj - fx1) * DXc;
                    const float dpz = ((float)ok - fx2) * DXc;
                    const float w = WA[oi] * WB[oj] * WC[ok];
                    const int gidx = (nx * G + ny) * G + nz;
                    float* gp = reinterpret_cast<float*>(gS4 + gidx);
                    unsafeAtomicAdd(gp + 0, w * (mvx + A00 * dpx + A01 * dpy + A02 * dpz));
                    unsafeAtomicAdd(gp + 1, w * (mvy + A10 * dpx + A11 * dpy + A12 * dpz));
                    unsafeAtomicAdd(gp + 2, w * (mvz + A20 * dpx + A21 * dpy + A22 * dpz));
                    unsafeAtomicAdd(gp + 3, w * P_MASS);
                    if (outF) unsafeAtomicAdd(&outF[gidx], w * P_MASS);
                }
            }
            __syncthreads();   // S3 (keep sync count uniform)
        }

        // shift bbox history
        zmn0 = pmn0; zmn1 = pmn1; zmn2 = pmn2;
        zmx0 = pmx0; zmx1 = pmx1; zmx2 = pmx2; zvalid = pvalid;
        pmn0 = mn0; pmn1 = mn1; pmn2 = mn2;
        pmx0 = mx0; pmx1 = mx1; pmx2 = mx2; pvalid = anyAct;

        if (p < NSUB - 1) gridbar(barcnt, barflag, ++gen);
        // last phase: kernel-end implicit release publishes the final out adds
    }
}

extern "C" void kernel_launch(void* const* d_in, const int* in_sizes, int n_in,
                              void* d_out, int out_size, void* d_ws, size_t ws_size,
                              hipStream_t stream) {
    const float* v  = (const float*)d_in[0];
    const float* q  = (const float*)d_in[1];
    const float* qd = (const float*)d_in[2];
    float* out = (float*)d_out;
    float* ws  = (float*)d_ws;
    // barrier lines at the tail of the workspace, 256B apart (different MALL
    // lines so the poll stream never contests the arrival line)
    char* tail = (char*)d_ws + (ws_size & ~(size_t)255);
    unsigned* barcnt  = reinterpret_cast<unsigned*>(tail - 256);
    unsigned* barflag = reinterpret_cast<unsigned*>(tail - 512);
    void* args[] = { (void*)&v, (void*)&q, (void*)&qd, (void*)&out, (void*)&ws,
                     (void*)&barcnt, (void*)&barflag };
    hipLaunchCooperativeKernel(reinterpret_cast<void*>(mpm_sim),
                               dim3(NBLK), dim3(NTHR), args, 0, stream);
}

// Round 10
// 17386.565 us; speedup vs baseline: 4.7649x; 1.0205x over previous
//
#include <hip/hip_runtime.h>
#include <hip/hip_cooperative_groups.h>

namespace cg = cooperative_groups;

static constexpr int G    = 100;
static constexpr int G3   = G * G * G;
static constexpr int NP   = 13500;   // 30*15*30 particles
static constexpr int NSUB = 600;     // 20 frames x 30 substeps
static constexpr int SPF  = 30;      // substeps per frame
static constexpr int NTHR = 512;     // 8 waves/block
static constexpr int NBLK = 108;     // 6x3x6 bricks of 5x5x5 particles
static constexpr int TCIN  = 2048;   // LDS IN-tile capacity (float4/cell = 32 KB)
static constexpr int TCOUT = 2048;   // LDS OUT-tile capacity (4 floats/cell = 32 KB)
static constexpr int CH   = (G3 + SPF - 2) / (SPF - 1);  // out-init chunk (34483)

__device__ __forceinline__ int clampi(int v) {
    return v < 0 ? 0 : (v > G - 1 ? G - 1 : v);
}
__device__ __forceinline__ int maxi(int a, int b) { return a > b ? a : b; }
__device__ __forceinline__ int mini(int a, int b) { return a < b ? a : b; }

// MALL-coherent (agent-scope, relaxed) helpers. ALL grid traffic goes through
// these or agent-scope atomics, so the grid is never cached dirty in any L2 ->
// the grid barrier needs NO cache maintenance.
__device__ __forceinline__ float4 cell_load(const float4* p) {
    const unsigned long long* q = reinterpret_cast<const unsigned long long*>(p);
    unsigned long long a = __hip_atomic_load(&q[0], __ATOMIC_RELAXED, __HIP_MEMORY_SCOPE_AGENT);
    unsigned long long b = __hip_atomic_load(&q[1], __ATOMIC_RELAXED, __HIP_MEMORY_SCOPE_AGENT);
    float4 r;
    r.x = __uint_as_float((unsigned)(a & 0xffffffffu));
    r.y = __uint_as_float((unsigned)(a >> 32));
    r.z = __uint_as_float((unsigned)(b & 0xffffffffu));
    r.w = __uint_as_float((unsigned)(b >> 32));
    return r;
}
__device__ __forceinline__ void cell_zero(float4* p) {
    unsigned long long* q = reinterpret_cast<unsigned long long*>(p);
    __hip_atomic_store(&q[0], 0ull, __ATOMIC_RELAXED, __HIP_MEMORY_SCOPE_AGENT);
    __hip_atomic_store(&q[1], 0ull, __ATOMIC_RELAXED, __HIP_MEMORY_SCOPE_AGENT);
}

// Hot split arrive/broadcast grid barrier.
// __syncthreads() drains vmcnt (all block MALL ops acked at the single
// coherence point); thread 0 arrives on line A; last arriver release-stores
// gen to line B; then ALL waves hot-spin on line B (one coalesced same-address
// request per wave, no s_sleep) and self-gate -- no trailing __syncthreads.
// Keeps waves actively issuing through the wait (clock-residency experiment)
// and removes one block-wide sync from the phase.
__device__ __forceinline__ void gridbar(unsigned* __restrict__ cnt,
                                        unsigned* __restrict__ flag,
                                        unsigned gen) {
    __syncthreads();
    if (threadIdx.x == 0) {
        const unsigned old = __hip_atomic_fetch_add(cnt, 1u, __ATOMIC_RELAXED, __HIP_MEMORY_SCOPE_AGENT);
        if (old == gen * (unsigned)NBLK - 1u) {
            __hip_atomic_store(flag, gen, __ATOMIC_RELEASE, __HIP_MEMORY_SCOPE_AGENT);
        }
    }
    while (__hip_atomic_load(flag, __ATOMIC_RELAXED, __HIP_MEMORY_SCOPE_AGENT) < gen) { }
    asm volatile("" ::: "memory");
}

// Persistent cooperative kernel, triple-buffered float4 grid in ws:
//   g4[buf*G3 + idx] = (mom.x, mom.y, mom.z, mass)
// Phase p (3 block syncs): [pre-S1] out-init chunk, sred init, tile zeroing,
// zero p-2 bbox (MALL), stage gather region into tileIn (normalized + BC once
// per cell); [S1] G2P from LDS + physics + scatter into a GROWN tile (prev
// true bbox +1 cell -- per-substep motion < 0.15 cells, so no bbox sync needed
// before scatter) + true-bbox LDS atomics; [S3] flush grown tile -> grid
// (agent atomics, m==0 skipped), frame-end also adds mass into out (pre-filled
// with vs). One hot split-line grid barrier per phase.
__launch_bounds__(NTHR)
__global__ void mpm_sim(const float* __restrict__ vscal,
                        const float* __restrict__ q0,
                        const float* __restrict__ qd0,
                        float* __restrict__ out,
                        float* __restrict__ ws,
                        unsigned* __restrict__ barcnt,
                        unsigned* __restrict__ barflag)
{
    const float vs = vscal[0];
    float4* const g4 = reinterpret_cast<float4*>(ws);

    cg::grid_group gg = cg::this_grid();
    const int tid = blockIdx.x * NTHR + threadIdx.x;
    const int nth = NBLK * NTHR;

    // brick/slot -> original particle index (4 lanes per particle)
    const int slot = threadIdx.x >> 2;        // 0..127
    const int sub  = threadIdx.x & 3;         // lane within particle group
    const bool act = slot < 125;
    int pid = 0;
    if (act) {
        const int b  = blockIdx.x;            // (bx*3+by)*6+bz
        const int bx = b / 18;
        const int by = (b / 6) % 3;
        const int bz = b % 6;
        const int lx = slot / 25;
        const int rem = slot % 25;
        const int ly = rem / 5;
        const int lz = rem % 5;
        const int ix = bx * 5 + lx;
        const int iy = by * 5 + ly;
        const int iz = bz * 5 + lz;
        pid = (ix * 15 + iy) * 30 + iz;
    }

    const float DT      = 5e-4f;
    const float INV_DX  = 100.0f;
    const float DXc     = 0.01f;
    const float MU      = (float)(1.0e5 / (2.0 * (1.0 + 0.3)));
    const float LAM     = (float)(1.0e5 * 0.3 / ((1.0 + 0.3) * (1.0 - 0.6)));
    const float P_MASS  = (float)(0.005 * 0.005 * 0.005 * 3000.0);
    const float KS      = (float)(-5.0e-4 * (0.005 * 0.005 * 0.005) * 4.0 * 100.0 * 100.0);
    const float DTG     = (float)(5.0e-4 * (-9.8));
    const float CSC     = 4.0f * INV_DX * INV_DX;   // 40000

    __shared__ float4 tileIn[TCIN];        // normalized grid velocity per cell
    __shared__ float  tileOut[4 * TCOUT];  // scatter accum: [mx,my,mz,mass]
    __shared__ int sred[6];                // true-bbox reduction

    // ---- init: zero all 3 grid buffers + barrier lines (ws poisoned 0xAA) ----
    {
        const float4 z = make_float4(0.f, 0.f, 0.f, 0.f);
        for (int i = tid; i < 3 * G3; i += nth) g4[i] = z;
        if (tid == 0) {
            __hip_atomic_store(barcnt,  0u, __ATOMIC_RELAXED, __HIP_MEMORY_SCOPE_AGENT);
            __hip_atomic_store(barflag, 0u, __ATOMIC_RELAXED, __HIP_MEMORY_SCOPE_AGENT);
        }
    }

    // ---- particle state, replicated across the 4 lanes of a group ----
    float px = 0.f, py = 0.f, pz = 0.f, vx = 0.f, vy = 0.f, vz = 0.f;
    float C00 = 0.f, C01 = 0.f, C02 = 0.f,
          C10 = 0.f, C11 = 0.f, C12 = 0.f,
          C20 = 0.f, C21 = 0.f, C22 = 0.f;
    float F00 = 1.f, F01 = 0.f, F02 = 0.f,
          F10 = 0.f, F11 = 1.f, F12 = 0.f,
          F20 = 0.f, F21 = 0.f, F22 = 1.f;
    if (act) {
        px = q0[3 * pid + 0]; py = q0[3 * pid + 1]; pz = q0[3 * pid + 2];
        vx = qd0[3 * pid + 0]; vy = qd0[3 * pid + 1]; vz = qd0[3 * pid + 2];
    }

    // per-wg TRUE bbox history (uniform across wg): p-1 and p-2 scatter bboxes
    int pmn0 = 0, pmn1 = 0, pmn2 = 0, pmx0 = -1, pmx1 = -1, pmx2 = -1; bool pvalid = false;
    int zmn0 = 0, zmn1 = 0, zmn2 = 0, zmx0 = -1, zmx1 = -1, zmx2 = -1; bool zvalid = false;

    gg.sync();   // publish init (release) before first phase

    unsigned gen = 0;

    for (int p = 0; p < NSUB; ++p) {
        const int bS = p % 3;
        const int bG = (p + 2) % 3;   // (p-1)%3 for p>0
        const int bZ = (p + 1) % 3;   // holds substep p-2 data
        float4*       __restrict__ gS4 = g4 + bS * G3;
        const float4* __restrict__ gG4 = g4 + bG * G3;
        float4*       __restrict__ gZ4 = g4 + bZ * G3;
        const int fc = p % SPF;
        float* const outF = (fc == SPF - 1) ? (out + (p / SPF) * G3) : nullptr;

        // grown scatter tile = prev true bbox +1 cell each side (fast path)
        const int tmn0 = pvalid ? maxi(pmn0 - 1, 0) : 0;
        const int tmn1 = pvalid ? maxi(pmn1 - 1, 0) : 0;
        const int tmn2 = pvalid ? maxi(pmn2 - 1, 0) : 0;
        const int tD0  = pvalid ? (mini(pmx0 + 1, G - 1) - tmn0 + 1) : 0;
        const int tD1  = pvalid ? (mini(pmx1 + 1, G - 1) - tmn1 + 1) : 0;
        const int tD2  = pvalid ? (mini(pmx2 + 1, G - 1) - tmn2 + 1) : 0;
        const int tvol = pvalid ? tD0 * tD1 * tD2 : 0;
        const bool fast = pvalid && (tvol <= TCOUT);

        // ---- [pre-S1] independent prep work ----
        if (threadIdx.x == 0) {
            sred[0] = INT_MAX; sred[1] = INT_MAX; sred[2] = INT_MAX;
            sred[3] = INT_MIN; sred[4] = INT_MIN; sred[5] = INT_MIN;
        }
        // out-init: spread vs-fill of this frame's out slab over its first 29
        // phases; frame-end adds happen at phase 30f+29, after the barrier
        // ending phase 30f+28 -> all inits ordered before adds.
        if (fc < SPF - 1) {
            float* of = out + (p / SPF) * G3;
            const int beg = fc * CH;
            const int end = (beg + CH < G3) ? beg + CH : G3;
            for (int i = beg + tid; i < end; i += nth)
                __hip_atomic_store(&of[i], vs, __ATOMIC_RELAXED, __HIP_MEMORY_SCOPE_AGENT);
        }
        // tileOut zero (grown tile in fast path, full capacity in fallback)
        {
            float4* t4 = reinterpret_cast<float4*>(tileOut);
            const float4 z = make_float4(0.f, 0.f, 0.f, 0.f);
            const int zn = fast ? tvol : TCOUT;
            for (int i = threadIdx.x; i < zn; i += NTHR) t4[i] = z;
        }
        // zero substep p-2's per-wg TRUE bbox (MALL stores)
        if (zvalid) {
            const int zD1 = zmx1 - zmn1 + 1, zD2 = zmx2 - zmn2 + 1;
            const int zvol = (zmx0 - zmn0 + 1) * zD1 * zD2;
            for (int c = threadIdx.x; c < zvol; c += NTHR) {
                const int k = c % zD2;
                const int t = c / zD2;
                const int j = t % zD1;
                const int i = t / zD1;
                cell_zero(&gZ4[((zmn0 + i) * G + (zmn1 + j)) * G + (zmn2 + k)]);
            }
        }
        // stage gather region (own p-1 TRUE scatter bbox) -> tileIn, norm + BC
        const int iD1 = pvalid ? (pmx1 - pmn1 + 1) : 0;
        const int iD2 = pvalid ? (pmx2 - pmn2 + 1) : 0;
        const int inVol = pvalid ? (pmx0 - pmn0 + 1) * iD1 * iD2 : 0;
        const bool staged = pvalid && (inVol <= TCIN);
        if (staged) {
            for (int c = threadIdx.x; c < inVol; c += NTHR) {
                const int k = c % iD2;
                const int t = c / iD2;
                const int j = t % iD1;
                const int i = t / iD1;
                const int nx = pmn0 + i, ny = pmn1 + j, nz = pmn2 + k;
                const float4 gq = cell_load(&gG4[(nx * G + ny) * G + nz]);
                const float den = gq.w + vs;
                float gvx = gq.x / den;
                float gvy = gq.y / den;
                float gvz = gq.z / den;
                if (nx < 3       && gvx < 0.f) gvx = 0.f;
                if (nx >= G - 3  && gvx > 0.f) gvx = 0.f;
                if (ny < 3       && gvy < 0.f) gvy = 0.f;
                if (ny >= G - 3  && gvy > 0.f) gvy = 0.f;
                if (nz < 3       && gvz < 0.f) gvz = 0.f;
                if (nz >= G - 3  && gvz > 0.f) gvz = 0.f;
                tileIn[c] = make_float4(gvx, gvy, gvz, 0.f);
            }
        }
        __syncthreads();   // S1

        int sb0 = 0, sb1 = 0, sb2 = 0;
        float fx0 = 0.f, fx1 = 0.f, fx2 = 0.f;
        float A00 = 0.f, A01 = 0.f, A02 = 0.f,
              A10 = 0.f, A11 = 0.f, A12 = 0.f,
              A20 = 0.f, A21 = 0.f, A22 = 0.f;
        float mvx = 0.f, mvy = 0.f, mvz = 0.f;

        if (act) {
            // ======== G2P gather for substep p-1 (cells c%4==sub per lane) ========
            if (p > 0) {
                const float xs0 = px * INV_DX, xs1 = py * INV_DX, xs2 = pz * INV_DX;
                const float fb0 = floorf(xs0 - 0.5f), fb1 = floorf(xs1 - 0.5f), fb2 = floorf(xs2 - 0.5f);
                const int b0 = (int)fb0, b1 = (int)fb1, b2 = (int)fb2;
                const float gx0 = xs0 - fb0, gx1 = xs1 - fb1, gx2 = xs2 - fb2;
                float wa[3], wb[3], wc[3];
                wa[0] = 0.5f * (1.5f - gx0) * (1.5f - gx0);
                wa[1] = 0.75f - (gx0 - 1.0f) * (gx0 - 1.0f);
                wa[2] = 0.5f * (gx0 - 0.5f) * (gx0 - 0.5f);
                wb[0] = 0.5f * (1.5f - gx1) * (1.5f - gx1);
                wb[1] = 0.75f - (gx1 - 1.0f) * (gx1 - 1.0f);
                wb[2] = 0.5f * (gx1 - 0.5f) * (gx1 - 0.5f);
                wc[0] = 0.5f * (1.5f - gx2) * (1.5f - gx2);
                wc[1] = 0.75f - (gx2 - 1.0f) * (gx2 - 1.0f);
                wc[2] = 0.5f * (gx2 - 0.5f) * (gx2 - 0.5f);

                float nvx = 0.f, nvy = 0.f, nvz = 0.f;
                float nc00 = 0.f, nc01 = 0.f, nc02 = 0.f,
                      nc10 = 0.f, nc11 = 0.f, nc12 = 0.f,
                      nc20 = 0.f, nc21 = 0.f, nc22 = 0.f;
                #pragma unroll
                for (int t = 0; t < 7; ++t) {
                    const int c = sub + 4 * t;
                    if (c >= 27) break;
                    const int oi = c / 9;
                    const int rem = c - 9 * oi;
                    const int oj = rem / 3;
                    const int ok = rem - 3 * oj;
                    const int nx = clampi(b0 + oi);
                    const int ny = clampi(b1 + oj);
                    const int nz = clampi(b2 + ok);
                    const float dpx = ((float)oi - gx0) * DXc;
                    const float dpy = ((float)oj - gx1) * DXc;
                    const float dpz = ((float)ok - gx2) * DXc;
                    const float w = wa[oi] * wb[oj] * wc[ok];
                    float gvx, gvy, gvz;
                    if (staged) {
                        const float4 gv4 = tileIn[((nx - pmn0) * iD1 + (ny - pmn1)) * iD2 + (nz - pmn2)];
                        gvx = gv4.x; gvy = gv4.y; gvz = gv4.z;
                    } else {
                        const float4 gq = cell_load(&gG4[(nx * G + ny) * G + nz]);
                        const float den = gq.w + vs;
                        gvx = gq.x / den;
                        gvy = gq.y / den;
                        gvz = gq.z / den;
                        if (nx < 3       && gvx < 0.f) gvx = 0.f;
                        if (nx >= G - 3  && gvx > 0.f) gvx = 0.f;
                        if (ny < 3       && gvy < 0.f) gvy = 0.f;
                        if (ny >= G - 3  && gvy > 0.f) gvy = 0.f;
                        if (nz < 3       && gvz < 0.f) gvz = 0.f;
                        if (nz >= G - 3  && gvz > 0.f) gvz = 0.f;
                    }
                    nvx += w * gvx; nvy += w * gvy; nvz += w * gvz;
                    const float wgx = w * gvx, wgy = w * gvy, wgz = w * gvz;
                    nc00 += wgx * dpx; nc01 += wgx * dpy; nc02 += wgx * dpz;
                    nc10 += wgy * dpx; nc11 += wgy * dpy; nc12 += wgy * dpz;
                    nc20 += wgz * dpx; nc21 += wgz * dpy; nc22 += wgz * dpz;
                }
                // 4-lane butterfly: all lanes end with identical full sums
                #define BFLY(v) { v += __shfl_xor(v, 1); v += __shfl_xor(v, 2); }
                BFLY(nvx) BFLY(nvy) BFLY(nvz)
                BFLY(nc00) BFLY(nc01) BFLY(nc02)
                BFLY(nc10) BFLY(nc11) BFLY(nc12)
                BFLY(nc20) BFLY(nc21) BFLY(nc22)
                #undef BFLY
                vx = nvx; vy = nvy; vz = nvz;
                C00 = CSC * nc00; C01 = CSC * nc01; C02 = CSC * nc02;
                C10 = CSC * nc10; C11 = CSC * nc11; C12 = CSC * nc12;
                C20 = CSC * nc20; C21 = CSC * nc21; C22 = CSC * nc22;
                px += DT * vx; py += DT * vy; pz += DT * vz;
            }

            // ======== F update: F = (I + DT*C) @ F (replicated) ========
            {
                const float t00 = F00 + DT * (C00 * F00 + C01 * F10 + C02 * F20);
                const float t01 = F01 + DT * (C00 * F01 + C01 * F11 + C02 * F21);
                const float t02 = F02 + DT * (C00 * F02 + C01 * F12 + C02 * F22);
                const float t10 = F10 + DT * (C10 * F00 + C11 * F10 + C12 * F20);
                const float t11 = F11 + DT * (C10 * F01 + C11 * F11 + C12 * F21);
                const float t12 = F12 + DT * (C10 * F02 + C11 * F12 + C12 * F22);
                const float t20 = F20 + DT * (C20 * F00 + C21 * F10 + C22 * F20);
                const float t21 = F21 + DT * (C20 * F01 + C21 * F11 + C22 * F21);
                const float t22 = F22 + DT * (C20 * F02 + C21 * F12 + C22 * F22);
                F00 = t00; F01 = t01; F02 = t02;
                F10 = t10; F11 = t11; F12 = t12;
                F20 = t20; F21 = t21; F22 = t22;
            }

            // ======== neo-Hookean PK1 stress -> affine (replicated) ========
            const float c00 = F11 * F22 - F12 * F21;
            const float c01 = F12 * F20 - F10 * F22;
            const float c02 = F10 * F21 - F11 * F20;
            const float det = F00 * c00 + F01 * c01 + F02 * c02;
            const float c10 = F02 * F21 - F01 * F22;
            const float c11 = F00 * F22 - F02 * F20;
            const float c12 = F01 * F20 - F00 * F21;
            const float c20 = F01 * F12 - F02 * F11;
            const float c21 = F02 * F10 - F00 * F12;
            const float c22 = F00 * F11 - F01 * F10;
            const float idet = 1.0f / det;
            const float lj = LAM * logf(fmaxf(det, 1e-6f));
            const float fit00 = c00 * idet, fit01 = c01 * idet, fit02 = c02 * idet;
            const float fit10 = c10 * idet, fit11 = c11 * idet, fit12 = c12 * idet;
            const float fit20 = c20 * idet, fit21 = c21 * idet, fit22 = c22 * idet;
            const float P00 = MU * (F00 - fit00) + lj * fit00;
            const float P01 = MU * (F01 - fit01) + lj * fit01;
            const float P02 = MU * (F02 - fit02) + lj * fit02;
            const float P10 = MU * (F10 - fit10) + lj * fit10;
            const float P11 = MU * (F11 - fit11) + lj * fit11;
            const float P12 = MU * (F12 - fit12) + lj * fit12;
            const float P20 = MU * (F20 - fit20) + lj * fit20;
            const float P21 = MU * (F21 - fit21) + lj * fit21;
            const float P22 = MU * (F22 - fit22) + lj * fit22;
            A00 = KS * (P00 * F00 + P01 * F01 + P02 * F02) + P_MASS * C00;
            A01 = KS * (P00 * F10 + P01 * F11 + P02 * F12) + P_MASS * C01;
            A02 = KS * (P00 * F20 + P01 * F21 + P02 * F22) + P_MASS * C02;
            A10 = KS * (P10 * F00 + P11 * F01 + P12 * F02) + P_MASS * C10;
            A11 = KS * (P10 * F10 + P11 * F11 + P12 * F12) + P_MASS * C11;
            A12 = KS * (P10 * F20 + P11 * F21 + P12 * F22) + P_MASS * C12;
            A20 = KS * (P20 * F00 + P21 * F01 + P22 * F02) + P_MASS * C20;
            A21 = KS * (P20 * F10 + P21 * F11 + P22 * F12) + P_MASS * C21;
            A22 = KS * (P20 * F20 + P21 * F21 + P22 * F22) + P_MASS * C22;

            // scatter base (from updated x)
            const float xs0 = px * INV_DX, xs1 = py * INV_DX, xs2 = pz * INV_DX;
            const float fb0 = floorf(xs0 - 0.5f), fb1 = floorf(xs1 - 0.5f), fb2 = floorf(xs2 - 0.5f);
            sb0 = (int)fb0; sb1 = (int)fb1; sb2 = (int)fb2;
            fx0 = xs0 - fb0; fx1 = xs1 - fb1; fx2 = xs2 - fb2;
            mvx = P_MASS * vx;
            mvy = P_MASS * (vy + DTG);
            mvz = P_MASS * vz;

            if (sub == 0) {   // true-bbox reduction (read only after S3)
                atomicMin(&sred[0], clampi(sb0)); atomicMax(&sred[3], clampi(sb0 + 2));
                atomicMin(&sred[1], clampi(sb1)); atomicMax(&sred[4], clampi(sb1 + 2));
                atomicMin(&sred[2], clampi(sb2)); atomicMax(&sred[5], clampi(sb2 + 2));
            }
        }

        // weights for scatter (replicated per lane group)
        float wa0 = 0.f, wa1 = 0.f, wa2 = 0.f, wb0 = 0.f, wb1 = 0.f, wb2 = 0.f,
              wcc0 = 0.f, wcc1 = 0.f, wcc2 = 0.f;
        if (act) {
            wa0 = 0.5f * (1.5f - fx0) * (1.5f - fx0);
            wa1 = 0.75f - (fx0 - 1.0f) * (fx0 - 1.0f);
            wa2 = 0.5f * (fx0 - 0.5f) * (fx0 - 0.5f);
            wb0 = 0.5f * (1.5f - fx1) * (1.5f - fx1);
            wb1 = 0.75f - (fx1 - 1.0f) * (fx1 - 1.0f);
            wb2 = 0.5f * (fx1 - 0.5f) * (fx1 - 0.5f);
            wcc0 = 0.5f * (1.5f - fx2) * (1.5f - fx2);
            wcc1 = 0.75f - (fx2 - 1.0f) * (fx2 - 1.0f);
            wcc2 = 0.5f * (fx2 - 0.5f) * (fx2 - 0.5f);
        }
        const float WA[3] = { wa0, wa1, wa2 };
        const float WB[3] = { wb0, wb1, wb2 };
        const float WC[3] = { wcc0, wcc1, wcc2 };

        if (fast) {
            // ======== scatter into grown tile, no bbox sync needed ========
            if (act) {
                #pragma unroll
                for (int t = 0; t < 7; ++t) {
                    const int c = sub + 4 * t;
                    if (c >= 27) break;
                    const int oi = c / 9;
                    const int rem = c - 9 * oi;
                    const int oj = rem / 3;
                    const int ok = rem - 3 * oj;
                    const int li  = clampi(sb0 + oi) - tmn0;
                    const int lj2 = clampi(sb1 + oj) - tmn1;
                    const int lk  = clampi(sb2 + ok) - tmn2;
                    const float dpx = ((float)oi - fx0) * DXc;
                    const float dpy = ((float)oj - fx1) * DXc;
                    const float dpz = ((float)ok - fx2) * DXc;
                    const float w = WA[oi] * WB[oj] * WC[ok];
                    const int c4 = 4 * ((li * tD1 + lj2) * tD2 + lk);
                    atomicAdd(&tileOut[c4 + 0], w * (mvx + A00 * dpx + A01 * dpy + A02 * dpz));
                    atomicAdd(&tileOut[c4 + 1], w * (mvy + A10 * dpx + A11 * dpy + A12 * dpz));
                    atomicAdd(&tileOut[c4 + 2], w * (mvz + A20 * dpx + A21 * dpy + A22 * dpz));
                    atomicAdd(&tileOut[c4 + 3], w * P_MASS);
                }
            }
            __syncthreads();   // S3
            // flush grown tile -> grid (agent atomics), skip empty cells
            for (int c = threadIdx.x; c < tvol; c += NTHR) {
                const float m = tileOut[4 * c + 3];
                if (m != 0.f) {
                    const int k = c % tD2;
                    const int t = c / tD2;
                    const int j = t % tD1;
                    const int i = t / tD1;
                    const int gidx = ((tmn0 + i) * G + (tmn1 + j)) * G + (tmn2 + k);
                    float* gp = reinterpret_cast<float*>(gS4 + gidx);
                    unsafeAtomicAdd(gp + 0, tileOut[4 * c + 0]);
                    unsafeAtomicAdd(gp + 1, tileOut[4 * c + 1]);
                    unsafeAtomicAdd(gp + 2, tileOut[4 * c + 2]);
                    unsafeAtomicAdd(gp + 3, m);
                    if (outF) unsafeAtomicAdd(&outF[gidx], m);
                }
            }
        } else {
            // ======== fallback: bbox-sync path (p==0 or oversized tile) ========
            __syncthreads();   // S2: bbox ready
            const int mn0 = sred[0], mn1 = sred[1], mn2 = sred[2];
            const int mx0 = sred[3], mx1 = sred[4], mx2 = sred[5];
            const bool anyAct = (mx0 >= mn0);
            const int D1 = mx1 - mn1 + 1, D2 = mx2 - mn2 + 1;
            const int vol = anyAct ? (mx0 - mn0 + 1) * D1 * D2 : 0;
            const bool useLDS = anyAct && (vol <= TCOUT);
            if (useLDS) {
                if (act) {
                    #pragma unroll
                    for (int t = 0; t < 7; ++t) {
                        const int c = sub + 4 * t;
                        if (c >= 27) break;
                        const int oi = c / 9;
                        const int rem = c - 9 * oi;
                        const int oj = rem / 3;
                        const int ok = rem - 3 * oj;
                        const int li  = clampi(sb0 + oi) - mn0;
                        const int lj2 = clampi(sb1 + oj) - mn1;
                        const int lk  = clampi(sb2 + ok) - mn2;
                        const float dpx = ((float)oi - fx0) * DXc;
                        const float dpy = ((float)oj - fx1) * DXc;
                        const float dpz = ((float)ok - fx2) * DXc;
                        const float w = WA[oi] * WB[oj] * WC[ok];
                        const int c4 = 4 * ((li * D1 + lj2) * D2 + lk);
                        atomicAdd(&tileOut[c4 + 0], w * (mvx + A00 * dpx + A01 * dpy + A02 * dpz));
                        atomicAdd(&tileOut[c4 + 1], w * (mvy + A10 * dpx + A11 * dpy + A12 * dpz));
                        atomicAdd(&tileOut[c4 + 2], w * (mvz + A20 * dpx + A21 * dpy + A22 * dpz));
                        atomicAdd(&tileOut[c4 + 3], w * P_MASS);
                    }
                }
                __syncthreads();   // S3
                for (int c = threadIdx.x; c < vol; c += NTHR) {
                    const float m = tileOut[4 * c + 3];
                    if (m != 0.f) {
                        const int k = c % D2;
                        const int t = c / D2;
                        const int j = t % D1;
                        const int i = t / D1;
                        const int gidx = ((mn0 + i) * G + (mn1 + j)) * G + (mn2 + k);
                        float* gp = reinterpret_cast<float*>(gS4 + gidx);
                        unsafeAtomicAdd(gp + 0, tileOut[4 * c + 0]);
                        unsafeAtomicAdd(gp + 1, tileOut[4 * c + 1]);
                        unsafeAtomicAdd(gp + 2, tileOut[4 * c + 2]);
                        unsafeAtomicAdd(gp + 3, m);
                        if (outF) unsafeAtomicAdd(&outF[gidx], m);
                    }
                }
            } else {
                if (anyAct && act) {
                    #pragma unroll
                    for (int t = 0; t < 7; ++t) {
                        const int c = sub + 4 * t;
                        if (c >= 27) break;
                        const int oi = c / 9;
                        const int rem = c - 9 * oi;
                        const int oj = rem / 3;
                        const int ok = rem - 3 * oj;
                        const int nx = clampi(sb0 + oi);
                        const int ny = clampi(sb1 + oj);
                        const int nz = clampi(sb2 + ok);
                        const float dpx = ((float)oi - fx0) * DXc;
                        const float dpy = ((float)oj - fx1) * DXc;
                        const float dpz = ((float)ok - fx2) * DXc;
                        const float w = WA[oi] * WB[oj] * WC[ok];
                        const int gidx = (nx * G + ny) * G + nz;
                        float* gp = reinterpret_cast<float*>(gS4 + gidx);
                        unsafeAtomicAdd(gp + 0, w * (mvx + A00 * dpx + A01 * dpy + A02 * dpz));
                        unsafeAtomicAdd(gp + 1, w * (mvy + A10 * dpx + A11 * dpy + A12 * dpz));
                        unsafeAtomicAdd(gp + 2, w * (mvz + A20 * dpx + A21 * dpy + A22 * dpz));
                        unsafeAtomicAdd(gp + 3, w * P_MASS);
                        if (outF) unsafeAtomicAdd(&outF[gidx], w * P_MASS);
                    }
                }
                __syncthreads();   // S3 (uniform)
            }
        }

        // shift TRUE bbox history (sred result valid after S3)
        zmn0 = pmn0; zmn1 = pmn1; zmn2 = pmn2;
        zmx0 = pmx0; zmx1 = pmx1; zmx2 = pmx2; zvalid = pvalid;
        pmn0 = sred[0]; pmn1 = sred[1]; pmn2 = sred[2];
        pmx0 = sred[3]; pmx1 = sred[4]; pmx2 = sred[5]; pvalid = (pmx0 >= pmn0);

        if (p < NSUB - 1) gridbar(barcnt, barflag, ++gen);
        // last phase: kernel-end implicit release publishes the final out adds
    }
}

extern "C" void kernel_launch(void* const* d_in, const int* in_sizes, int n_in,
                              void* d_out, int out_size, void* d_ws, size_t ws_size,
                              hipStream_t stream) {
    const float* v  = (const float*)d_in[0];
    const float* q  = (const float*)d_in[1];
    const float* qd = (const float*)d_in[2];
    float* out = (float*)d_out;
    float* ws  = (float*)d_ws;
    // barrier lines at the tail of the workspace, separate 256B lines so the
    // poll stream never contests ownership of the arrival line
    char* tail = (char*)d_ws + (ws_size & ~(size_t)255);
    unsigned* barcnt  = reinterpret_cast<unsigned*>(tail - 256);
    unsigned* barflag = reinterpret_cast<unsigned*>(tail - 512);
    void* args[] = { (void*)&v, (void*)&q, (void*)&qd, (void*)&out, (void*)&ws,
                     (void*)&barcnt, (void*)&barflag };
    hipLaunchCooperativeKernel(reinterpret_cast<void*>(mpm_sim),
                               dim3(NBLK), dim3(NTHR), args, 0, stream);
}